// Round 11
// baseline (237.311 us; speedup 1.0000x reference)
//
#include <hip/hip_runtime.h>
#include <hip/hip_bf16.h>
#include <math.h>

#define CCLS 16
#define BB   2048

using bf16x8 = __attribute__((ext_vector_type(8))) short;
using short8 = __attribute__((ext_vector_type(8))) short;
using f32x4  = __attribute__((ext_vector_type(4))) float;

// fp32 -> (hi, lo) bf16 split (RNE; hi+lo reproduces ~24 mantissa bits)
__device__ __forceinline__ void split2(float e, short& hi, short& lo) {
    __hip_bfloat16 h = __float2bfloat16(e);
    hi = __builtin_bit_cast(short, h);
    lo = __builtin_bit_cast(short, __float2bfloat16(e - __bfloat162float(h)));
}

// LDS-visibility barrier that does NOT drain vmcnt.
__device__ __forceinline__ void soft_barrier() {
    asm volatile("s_waitcnt lgkmcnt(0)" ::: "memory");
    __builtin_amdgcn_s_barrier();
    asm volatile("" ::: "memory");
}

// global -> LDS direct copy, 16B/lane; lds dest is wave-uniform base
__device__ __forceinline__ void gll16(const void* g, void* l) {
    __builtin_amdgcn_global_load_lds(
        (const __attribute__((address_space(1))) unsigned*)g,
        (__attribute__((address_space(3))) unsigned*)l, 16, 0, 0);
}

// Fragment-major layout for a 128-row x 32-k bf16 tile (8 KB/plane):
//   L(row, kchunk) = (row>>4)<<10 | kchunk<<8 | (row&15)<<4   (kchunk = k/8)

// ---------------------------------------------------------------------------
// One-time pack: x and W1..W5 -> [hi 8KB][lo 8KB] fragment-major 128x32 tiles.
// ---------------------------------------------------------------------------
struct PackDesc {
    const float* src[6];
    int nrt[6];
    int ksn[6];
    int kreal[6];
    int beg[7];
};

__global__ __launch_bounds__(256)
void pack_kernel(PackDesc d, char* __restrict__ base)
{
    const int bid = blockIdx.x;
    int s = 0;
    #pragma unroll
    for (int i = 0; i < 5; ++i) s += (bid >= d.beg[i + 1]);
    const int t    = bid - d.beg[s];
    const int ksn  = d.ksn[s], nrt = d.nrt[s], kreal = d.kreal[s];
    const int perc = nrt * ksn;
    const int c  = t / perc;
    const int r  = t - c * perc;
    const int rt = r / ksn;
    const int ks = r - rt * ksn;
    const float* src = d.src[s] + ((size_t)(c * nrt + rt) * 128) * kreal;
    char* dst = base + (size_t)bid * 16384;
    const int tid = threadIdx.x;

    #pragma unroll
    for (int it = 0; it < 2; ++it) {
        const int row = (tid >> 2) + (it << 6);
        const int cc  = tid & 3;
        const int q   = ((row >> 4) << 10) | (cc << 8) | ((row & 15) << 4);
        const int k0  = ks * 32 + cc * 8;
        const float* sp = src + (size_t)row * kreal + k0;
        float e[8];
        if (k0 + 8 <= kreal) {
            float4 v0 = *(const float4*)sp;
            float4 v1 = *(const float4*)(sp + 4);
            e[0]=v0.x; e[1]=v0.y; e[2]=v0.z; e[3]=v0.w;
            e[4]=v1.x; e[5]=v1.y; e[6]=v1.z; e[7]=v1.w;
        } else {
            #pragma unroll
            for (int j = 0; j < 8; ++j) e[j] = (k0 + j < kreal) ? sp[j] : 0.f;
        }
        short hv[8], lv[8];
        #pragma unroll
        for (int j = 0; j < 8; ++j) split2(e[j], hv[j], lv[j]);
        *(short8*)(dst + q)        = (short8){hv[0],hv[1],hv[2],hv[3],hv[4],hv[5],hv[6],hv[7]};
        *(short8*)(dst + 8192 + q) = (short8){lv[0],lv[1],lv[2],lv[3],lv[4],lv[5],lv[6],lv[7]};
    }
}

// ---------------------------------------------------------------------------
// 4-wave kernel (R8 structure): PREPACK path for G1, reg-staged path for G3.
// ---------------------------------------------------------------------------
template<int BM, int K, bool PREPACK, bool FUSE_BN, bool WRITE_STATS>
__global__ __launch_bounds__(256, 2)
void gemm4w_kernel(const float* __restrict__ A, const char* __restrict__ Apk,
                   const char* __restrict__ Wpk, const float* __restrict__ bias,
                   const float* __restrict__ psumIn, const float* __restrict__ psqIn,
                   const float* __restrict__ gIn, const float* __restrict__ beIn,
                   float* __restrict__ Out,
                   float* __restrict__ psumOut, float* __restrict__ psqOut,
                   const int Fout, const int nbtIn)
{
    constexpr int KS    = (K + 31) / 32;
    constexpr int PLANE = BM * 64;
    constexpr int BUFSZ = PREPACK ? 32768 : 2 * PLANE;
    static_assert(PREPACK || (K % 32 == 0), "");
    static_assert(PREPACK || (KS % 2 == 0) || (KS == 1), "");

    __shared__ __align__(16) char sm[2 * BUFSZ + (FUSE_BN ? 8 * K : 16)];
    float* scs = (float*)(sm + 2 * BUFSZ);
    float* shs = scs + (FUSE_BN ? K : 0);

    const int tid   = threadIdx.x;
    const int btile = blockIdx.x, otile = blockIdx.y, c = blockIdx.z;

    if (FUSE_BN) {
        for (int f = tid; f < K; f += 256) {
            const float* ps = psumIn + ((size_t)c * K + f) * nbtIn;
            const float* pq = psqIn  + ((size_t)c * K + f) * nbtIn;
            float s = 0.f, q = 0.f;
            for (int t = 0; t < nbtIn; t += 4) {
                float4 a4 = *(const float4*)(ps + t);
                float4 b4 = *(const float4*)(pq + t);
                s += (a4.x + a4.y) + (a4.z + a4.w);
                q += (b4.x + b4.y) + (b4.z + b4.w);
            }
            const float mean = s * (1.f / BB);
            const float var  = q * (1.f / BB) - mean * mean;
            const float rstd = rsqrtf(var + 1e-5f);
            const float scv  = gIn[(size_t)c * K + f] * rstd;
            scs[f] = scv;
            shs[f] = fmaf(-mean, scv, beIn[(size_t)c * K + f]);
        }
        __syncthreads();
    }

    const int b0 = btile * BM, o0 = otile * 128;
    const int OT = Fout >> 7;
    const char* wbase = Wpk + (size_t)((c * OT + otile) * KS) * 16384;
    const char* abase = PREPACK ? (Apk + (size_t)((c * gridDim.x + btile) * KS) * 16384) : nullptr;

    const int lane = tid & 63, wv = tid >> 6;
    const int fr = lane & 15, fkc = lane >> 4;
    const int wrow = (BM == 128) ? ((wv >> 1) << 6) : ((wv >> 1) << 5);
    const int wcol = (wv & 1) << 6;
    const int wrg = wrow >> 4, wcg = wcol >> 4;
    constexpr int MI = BM / 32;

    f32x4 acc[MI][4];
    #pragma unroll
    for (int mi = 0; mi < MI; ++mi)
        #pragma unroll
        for (int ni = 0; ni < 4; ++ni)
            acc[mi][ni] = (f32x4){0.f, 0.f, 0.f, 0.f};

    if constexpr (PREPACK) {
        auto stageTile = [&](int nb, int ks) {
            const char* at = abase + (size_t)ks * 16384;
            const char* wt = wbase + (size_t)ks * 16384;
            char* dst = sm + nb;
            #pragma unroll
            for (int i = 0; i < 4; ++i) {
                const int rg = ((wv << 2) + i) << 10;
                gll16(at + rg + (lane << 4), dst + rg);
                gll16(wt + rg + (lane << 4), dst + 16384 + rg);
            }
        };
        stageTile(0, 0);
        __syncthreads();
        for (int ks = 0; ks < KS; ++ks) {
            const int cb = (ks & 1) ? BUFSZ : 0;
            if (ks + 1 < KS) stageTile(cb ^ BUFSZ, ks + 1);
            bf16x8 ah[MI], al[MI], wh[4], wl[4];
            #pragma unroll
            for (int i = 0; i < 4; ++i) {
                const int wo = ((wcg + i) << 10) | (fkc << 8) | (fr << 4);
                wh[i] = *(const bf16x8*)(sm + cb + 16384 + wo);
                wl[i] = *(const bf16x8*)(sm + cb + 24576 + wo);
            }
            #pragma unroll
            for (int i = 0; i < MI; ++i) {
                const int ao = ((wrg + i) << 10) | (fkc << 8) | (fr << 4);
                ah[i] = *(const bf16x8*)(sm + cb + ao);
                al[i] = *(const bf16x8*)(sm + cb + 8192 + ao);
            }
            #pragma unroll
            for (int mi = 0; mi < MI; ++mi)
                #pragma unroll
                for (int ni = 0; ni < 4; ++ni) {
                    acc[mi][ni] = __builtin_amdgcn_mfma_f32_16x16x32_bf16(ah[mi], wh[ni], acc[mi][ni], 0, 0, 0);
                    acc[mi][ni] = __builtin_amdgcn_mfma_f32_16x16x32_bf16(ah[mi], wl[ni], acc[mi][ni], 0, 0, 0);
                    acc[mi][ni] = __builtin_amdgcn_mfma_f32_16x16x32_bf16(al[mi], wh[ni], acc[mi][ni], 0, 0, 0);
                }
            __syncthreads();
        }
    } else {
        constexpr int NV = BM / 32;
        const int arow = (BM == 128) ? (tid >> 1) : (tid >> 2);
        const int asub = (BM == 128) ? (tid & 1)  : (tid & 3);
        const int ak0  = (BM == 128) ? (asub << 4) : (asub << 3);
        const int kch  = (BM == 128) ? (asub << 1) : asub;
        const int awr  = ((arow >> 4) << 10) | (kch << 8) | ((arow & 15) << 4);
        const float* Arow = A + ((size_t)c * BB + b0 + arow) * K;

        auto loadA = [&](float4 (&av)[NV], int gk0) {
            #pragma unroll
            for (int i = 0; i < NV; ++i)
                av[i] = *(const float4*)(Arow + gk0 + (i << 2));
        };
        auto loadW = [&](bf16x8 (&w)[8], int ks) {
            const char* wt = wbase + (size_t)ks * 16384;
            #pragma unroll
            for (int i = 0; i < 4; ++i) {
                const int wo = ((wcg + i) << 10) | (fkc << 8) | (fr << 4);
                w[i]     = *(const bf16x8*)(wt + wo);
                w[4 + i] = *(const bf16x8*)(wt + 8192 + wo);
            }
        };
        auto cvtStore = [&](char* dstbase, const float4 (&a)[NV], int gk0) {
            float e[NV * 4];
            #pragma unroll
            for (int i = 0; i < NV; ++i) {
                e[i*4+0] = a[i].x; e[i*4+1] = a[i].y; e[i*4+2] = a[i].z; e[i*4+3] = a[i].w;
            }
            if constexpr (FUSE_BN) {
                #pragma unroll
                for (int i = 0; i < NV; ++i) {
                    const float4 sc = *(const float4*)(scs + gk0 + (i << 2));
                    const float4 sh = *(const float4*)(shs + gk0 + (i << 2));
                    e[i*4+0] = fmaxf(0.f, fmaf(e[i*4+0], sc.x, sh.x));
                    e[i*4+1] = fmaxf(0.f, fmaf(e[i*4+1], sc.y, sh.y));
                    e[i*4+2] = fmaxf(0.f, fmaf(e[i*4+2], sc.z, sh.z));
                    e[i*4+3] = fmaxf(0.f, fmaf(e[i*4+3], sc.w, sh.w));
                }
            }
            short h[NV*4], l[NV*4];
            #pragma unroll
            for (int j = 0; j < NV*4; ++j) split2(e[j], h[j], l[j]);
            *(short8*)(dstbase + awr)         = (short8){h[0],h[1],h[2],h[3],h[4],h[5],h[6],h[7]};
            *(short8*)(dstbase + PLANE + awr) = (short8){l[0],l[1],l[2],l[3],l[4],l[5],l[6],l[7]};
            if constexpr (NV == 4) {
                *(short8*)(dstbase + awr + 256)         = (short8){h[8],h[9],h[10],h[11],h[12],h[13],h[14],h[15]};
                *(short8*)(dstbase + PLANE + awr + 256) = (short8){l[8],l[9],l[10],l[11],l[12],l[13],l[14],l[15]};
            }
        };

        bf16x8 wcA[8], wcB[8];
        float4 avP[NV], avQ[NV];

        auto step = [&](int ks, char* cbp, char* nbp,
                        float4 (&avUse)[NV], float4 (&avLoad)[NV],
                        bf16x8 (&wUse)[8], bf16x8 (&wLoad)[8]) {
            const bool hn  = (ks + 1) < KS;
            const bool hn2 = (ks + 2) < KS;
            if (hn2) loadA(avLoad, ((ks + 2) << 5) + ak0);
            if (hn)  loadW(wLoad, ks + 1);
            bf16x8 ah[MI], al[MI];
            #pragma unroll
            for (int i = 0; i < MI; ++i) {
                const int ao = ((wrg + i) << 10) | (fkc << 8) | (fr << 4);
                ah[i] = *(const bf16x8*)(cbp + ao);
                al[i] = *(const bf16x8*)(cbp + PLANE + ao);
            }
            #pragma unroll
            for (int mi = 0; mi < MI; ++mi)
                #pragma unroll
                for (int ni = 0; ni < 4; ++ni) {
                    acc[mi][ni] = __builtin_amdgcn_mfma_f32_16x16x32_bf16(ah[mi], wUse[ni],     acc[mi][ni], 0, 0, 0);
                    acc[mi][ni] = __builtin_amdgcn_mfma_f32_16x16x32_bf16(ah[mi], wUse[4 + ni], acc[mi][ni], 0, 0, 0);
                    acc[mi][ni] = __builtin_amdgcn_mfma_f32_16x16x32_bf16(al[mi], wUse[ni],     acc[mi][ni], 0, 0, 0);
                }
            if (hn) cvtStore(nbp, avUse, ((ks + 1) << 5) + ak0);
            soft_barrier();
        };

        {
            float4 av0[NV];
            loadA(av0, ak0);
            loadW(wcA, 0);
            if (KS > 1) loadA(avP, 32 + ak0);
            cvtStore(sm, av0, ak0);
        }
        soft_barrier();

        for (int ks = 0; ks < KS; ks += 2) {
            step(ks,     sm,         sm + BUFSZ, avP, avQ, wcA, wcB);
            step(ks + 1, sm + BUFSZ, sm,         avQ, avP, wcB, wcA);
        }
    }

    // ---- epilogue ----
    float bv[4];
    #pragma unroll
    for (int ni = 0; ni < 4; ++ni)
        bv[ni] = bias[(size_t)c * Fout + o0 + wcol + (ni << 4) + fr];

    float p[4] = {}, q[4] = {};
    const int rsub = (lane >> 4) << 2;
    #pragma unroll
    for (int mi = 0; mi < MI; ++mi) {
        #pragma unroll
        for (int j = 0; j < 4; ++j) {
            const int row = b0 + wrow + (mi << 4) + rsub + j;
            float* op = Out + ((size_t)c * BB + row) * Fout + o0 + wcol;
            #pragma unroll
            for (int ni = 0; ni < 4; ++ni) {
                const float v = acc[mi][ni][j] + bv[ni];
                op[(ni << 4) + fr] = v;
                if (WRITE_STATS) { p[ni] += v; q[ni] += v * v; }
            }
        }
    }

    if (WRITE_STATS) {
        #pragma unroll
        for (int ni = 0; ni < 4; ++ni) {
            p[ni] += __shfl_xor(p[ni], 16); p[ni] += __shfl_xor(p[ni], 32);
            q[ni] += __shfl_xor(q[ni], 16); q[ni] += __shfl_xor(q[ni], 32);
        }
        __syncthreads();
        float* redp = (float*)sm;
        float* redq = (float*)(sm + 1024);
        if (lane < 16) {
            const int base = (wv >> 1) * 128 + wcol;
            #pragma unroll
            for (int ni = 0; ni < 4; ++ni) {
                redp[base + (ni << 4) + fr] = p[ni];
                redq[base + (ni << 4) + fr] = q[ni];
            }
        }
        __syncthreads();
        if (tid < 128) {
            const float sp = redp[tid] + redp[128 + tid];
            const float sq = redq[tid] + redq[128 + tid];
            const size_t o = ((size_t)c * Fout + o0 + tid) * gridDim.x + btile;
            psumOut[o] = sp;
            psqOut[o]  = sq;
        }
    }
}

// ---------------------------------------------------------------------------
// 4-wave 64x256 tile kernel (waves 1M x 4N, each 64x64, MI=4 -> 48 MFMA/step).
// Full-N cvt-dedup like the 8w kernel, but 2x the blocks (>=2-4/CU) so
// independent blocks' barrier stalls interleave. Always FUSE_BN.
// ---------------------------------------------------------------------------
template<int K, bool WRITE_STATS>
__global__ __launch_bounds__(256, 4)
void gemm4n_kernel(const float* __restrict__ A, const char* __restrict__ Wpk,
                   const float* __restrict__ bias,
                   const float* __restrict__ psumIn, const float* __restrict__ psqIn,
                   const float* __restrict__ gIn, const float* __restrict__ beIn,
                   float* __restrict__ Out,
                   float* __restrict__ psumOut, float* __restrict__ psqOut,
                   const int Fout, const int nbtIn)
{
    constexpr int KS    = K / 32;
    constexpr int PLANE = 4096;     // 64x32 bf16 plane
    constexpr int BUFSZ = 8192;     // hi+lo
    static_assert(K % 32 == 0 && (KS % 2 == 0), "");

    __shared__ __align__(16) char sm[2 * BUFSZ + 8 * K];
    float* scs = (float*)(sm + 2 * BUFSZ);
    float* shs = scs + K;

    const int tid   = threadIdx.x;
    const int btile = blockIdx.x, otile = blockIdx.y, c = blockIdx.z;

    // folded combine: BN scale/shift for INPUT features
    for (int f = tid; f < K; f += 256) {
        const float* ps = psumIn + ((size_t)c * K + f) * nbtIn;
        const float* pq = psqIn  + ((size_t)c * K + f) * nbtIn;
        float s = 0.f, q = 0.f;
        for (int t = 0; t < nbtIn; t += 4) {
            float4 a4 = *(const float4*)(ps + t);
            float4 b4 = *(const float4*)(pq + t);
            s += (a4.x + a4.y) + (a4.z + a4.w);
            q += (b4.x + b4.y) + (b4.z + b4.w);
        }
        const float mean = s * (1.f / BB);
        const float var  = q * (1.f / BB) - mean * mean;
        const float rstd = rsqrtf(var + 1e-5f);
        const float scv  = gIn[(size_t)c * K + f] * rstd;
        scs[f] = scv;
        shs[f] = fmaf(-mean, scv, beIn[(size_t)c * K + f]);
    }
    __syncthreads();

    const int b0 = btile * 64, o0 = otile * 256;
    const int OT128 = Fout >> 7;

    // A staging: 256 threads x 8 floats (one 16B frag slot each)
    const int arow = tid >> 2, asub = tid & 3;
    const int ak0  = asub << 3;
    const int awr  = ((arow >> 4) << 10) | (asub << 8) | ((arow & 15) << 4);
    const float* Arow = A + ((size_t)c * BB + b0 + arow) * K;

    // wave map: 4 waves across N, each 64(M) x 64(N)
    const int lane = tid & 63, wv = tid >> 6;
    const int wcol = wv << 6;
    const int fr = lane & 15, fkc = lane >> 4;
    const int wtile = wv >> 1;              // which packed 128-col tile
    const int wcg = (wv & 1) << 2;          // 16-col group within it
    const char* wbase = Wpk + (size_t)((c * OT128 + otile * 2 + wtile) * KS) * 16384;

    auto loadA = [&](float4 (&av)[2], int gk0) {
        av[0] = *(const float4*)(Arow + gk0);
        av[1] = *(const float4*)(Arow + gk0 + 4);
    };
    auto loadW = [&](bf16x8 (&w)[8], int ks) {
        const char* wt = wbase + (size_t)ks * 16384;
        #pragma unroll
        for (int i = 0; i < 4; ++i) {
            const int wo = ((wcg + i) << 10) | (fkc << 8) | (fr << 4);
            w[i]     = *(const bf16x8*)(wt + wo);
            w[4 + i] = *(const bf16x8*)(wt + 8192 + wo);
        }
    };
    auto cvtStore = [&](char* dstbase, const float4 (&a)[2], int gk0) {
        float e[8] = {a[0].x, a[0].y, a[0].z, a[0].w, a[1].x, a[1].y, a[1].z, a[1].w};
        const float4 sc0 = *(const float4*)(scs + gk0);
        const float4 sc1 = *(const float4*)(scs + gk0 + 4);
        const float4 sh0 = *(const float4*)(shs + gk0);
        const float4 sh1 = *(const float4*)(shs + gk0 + 4);
        e[0] = fmaxf(0.f, fmaf(e[0], sc0.x, sh0.x));
        e[1] = fmaxf(0.f, fmaf(e[1], sc0.y, sh0.y));
        e[2] = fmaxf(0.f, fmaf(e[2], sc0.z, sh0.z));
        e[3] = fmaxf(0.f, fmaf(e[3], sc0.w, sh0.w));
        e[4] = fmaxf(0.f, fmaf(e[4], sc1.x, sh1.x));
        e[5] = fmaxf(0.f, fmaf(e[5], sc1.y, sh1.y));
        e[6] = fmaxf(0.f, fmaf(e[6], sc1.z, sh1.z));
        e[7] = fmaxf(0.f, fmaf(e[7], sc1.w, sh1.w));
        short h[8], l[8];
        #pragma unroll
        for (int j = 0; j < 8; ++j) split2(e[j], h[j], l[j]);
        *(short8*)(dstbase + awr)         = (short8){h[0],h[1],h[2],h[3],h[4],h[5],h[6],h[7]};
        *(short8*)(dstbase + PLANE + awr) = (short8){l[0],l[1],l[2],l[3],l[4],l[5],l[6],l[7]};
    };

    f32x4 acc[4][4];
    #pragma unroll
    for (int mi = 0; mi < 4; ++mi)
        #pragma unroll
        for (int ni = 0; ni < 4; ++ni)
            acc[mi][ni] = (f32x4){0.f, 0.f, 0.f, 0.f};

    bf16x8 wcA[8], wcB[8];
    float4 avP[2], avQ[2];

    auto step = [&](int ks, char* cbp, char* nbp,
                    float4 (&avUse)[2], float4 (&avLoad)[2],
                    bf16x8 (&wUse)[8], bf16x8 (&wLoad)[8]) {
        const bool hn  = (ks + 1) < KS;
        const bool hn2 = (ks + 2) < KS;
        if (hn2) loadA(avLoad, ((ks + 2) << 5) + ak0);
        if (hn)  loadW(wLoad, ks + 1);
        bf16x8 ah[4], al[4];
        #pragma unroll
        for (int i = 0; i < 4; ++i) {
            const int ao = (i << 10) | (fkc << 8) | (fr << 4);
            ah[i] = *(const bf16x8*)(cbp + ao);
            al[i] = *(const bf16x8*)(cbp + PLANE + ao);
        }
        #pragma unroll
        for (int mi = 0; mi < 4; ++mi)
            #pragma unroll
            for (int ni = 0; ni < 4; ++ni) {
                acc[mi][ni] = __builtin_amdgcn_mfma_f32_16x16x32_bf16(ah[mi], wUse[ni],     acc[mi][ni], 0, 0, 0);
                acc[mi][ni] = __builtin_amdgcn_mfma_f32_16x16x32_bf16(ah[mi], wUse[4 + ni], acc[mi][ni], 0, 0, 0);
                acc[mi][ni] = __builtin_amdgcn_mfma_f32_16x16x32_bf16(al[mi], wUse[ni],     acc[mi][ni], 0, 0, 0);
            }
        if (hn) cvtStore(nbp, avUse, ((ks + 1) << 5) + ak0);
        soft_barrier();
    };

    {
        float4 av0[2];
        loadA(av0, ak0);
        loadW(wcA, 0);
        loadA(avP, 32 + ak0);
        cvtStore(sm, av0, ak0);
    }
    soft_barrier();

    for (int ks = 0; ks < KS; ks += 2) {
        step(ks,     sm,         sm + BUFSZ, avP, avQ, wcA, wcB);
        step(ks + 1, sm + BUFSZ, sm,         avQ, avP, wcB, wcA);
    }

    // ---- epilogue: bias, store, deterministic partial BN stats ----
    // C/D layout: col = lane&15, row = (lane>>4)*4 + reg
    float bv[4];
    #pragma unroll
    for (int ni = 0; ni < 4; ++ni)
        bv[ni] = bias[(size_t)c * Fout + o0 + wcol + (ni << 4) + fr];

    float p[4] = {}, q[4] = {};
    const int rsub = (lane >> 4) << 2;
    #pragma unroll
    for (int mi = 0; mi < 4; ++mi) {
        #pragma unroll
        for (int j = 0; j < 4; ++j) {
            const int row = b0 + (mi << 4) + rsub + j;
            float* op = Out + ((size_t)c * BB + row) * Fout + o0 + wcol;
            #pragma unroll
            for (int ni = 0; ni < 4; ++ni) {
                const float v = acc[mi][ni][j] + bv[ni];
                op[(ni << 4) + fr] = v;
                if (WRITE_STATS) { p[ni] += v; q[ni] += v * v; }
            }
        }
    }

    if (WRITE_STATS) {
        #pragma unroll
        for (int ni = 0; ni < 4; ++ni) {   // fold the 4 row-subgroups per column
            p[ni] += __shfl_xor(p[ni], 16); p[ni] += __shfl_xor(p[ni], 32);
            q[ni] += __shfl_xor(q[ni], 16); q[ni] += __shfl_xor(q[ni], 32);
        }
        __syncthreads();                    // loop done; reuse sm as scratch
        float* redp = (float*)sm;           // [256]
        float* redq = (float*)(sm + 1024);
        if (lane < 16) {
            #pragma unroll
            for (int ni = 0; ni < 4; ++ni) {
                redp[wcol + (ni << 4) + fr] = p[ni];
                redq[wcol + (ni << 4) + fr] = q[ni];
            }
        }
        __syncthreads();
        if (tid < 256) {
            const size_t o = ((size_t)c * Fout + o0 + tid) * gridDim.x + btile;
            psumOut[o] = redp[tid];
            psqOut[o]  = redq[tid];
        }
    }
}

__global__ __launch_bounds__(256)
void label_kernel(float* __restrict__ out)
{
    const int i = blockIdx.x * 256 + threadIdx.x;
    out[i] = (float)(i >> 11);   // i / 2048
}

// ---------------------------------------------------------------------------
extern "C" void kernel_launch(void* const* d_in, const int* in_sizes, int n_in,
                              void* d_out, int out_size, void* d_ws, size_t ws_size,
                              hipStream_t stream)
{
    const float* x = (const float*)d_in[0];
    const float* W[5];  const float* bs[5];
    for (int l = 0; l < 5; ++l) { W[l] = (const float*)d_in[1 + 2 * l]; bs[l] = (const float*)d_in[2 + 2 * l]; }
    const float* g[4];  const float* be[4];
    for (int l = 0; l < 4; ++l) { g[l] = (const float*)d_in[11 + 2 * l]; be[l] = (const float*)d_in[12 + 2 * l]; }

    float* out     = (float*)d_out;
    float* gendata = out;                              // [C*BB, 512] — doubles as h1
    float* label   = out + (size_t)CCLS * BB * 512;

    float* ws  = (float*)d_ws;
    float* h2  = ws;                                   // 32MB
    float* h3  = h2 + 8388608;                         // 16MB
    float* h4  = h2;                                   // alias: h2 dead after G3
    float* ps1 = h3 + 4194304;                         // 16*512*16
    float* pq1 = ps1 + 131072;
    float* ps2 = pq1 + 131072;                         // 16*256*32
    float* pq2 = ps2 + 131072;
    float* ps3 = pq2 + 131072;                         // 16*128*32
    float* pq3 = ps3 + 65536;
    float* ps4 = pq3 + 65536;                          // 16*256*32
    float* pq4 = ps4 + 131072;
    char*  pack = (char*)(pq4 + 131072);               // 2560 x 16KB = 40MB

    const char* xpk  = pack;
    const char* wpk1 = pack + (size_t)1024 * 16384;
    const char* wpk2 = pack + (size_t)1280 * 16384;
    const char* wpk3 = pack + (size_t)1792 * 16384;
    const char* wpk4 = pack + (size_t)1920 * 16384;
    const char* wpk5 = pack + (size_t)2048 * 16384;

    const dim3 blk(256);

    PackDesc pd;
    pd.src[0] = x;    pd.src[1] = W[0]; pd.src[2] = W[1];
    pd.src[3] = W[2]; pd.src[4] = W[3]; pd.src[5] = W[4];
    const int nrt[6]   = {16, 4, 2, 1, 2, 4};
    const int ksn[6]   = {4, 4, 16, 8, 4, 8};
    const int kreal[6] = {100, 100, 512, 256, 128, 256};
    const int beg[7]   = {0, 1024, 1280, 1792, 1920, 2048, 2560};
    for (int i = 0; i < 6; ++i) { pd.nrt[i] = nrt[i]; pd.ksn[i] = ksn[i]; pd.kreal[i] = kreal[i]; }
    for (int i = 0; i < 7; ++i) pd.beg[i] = beg[i];
    pack_kernel<<<dim3(2560), blk, 0, stream>>>(pd, pack);

    // G1: x[K=100->128] -> h1(=gendata)[512], stats -> ps1 (nbt=16)
    gemm4w_kernel<128, 128, true, false, true><<<dim3(16, 4, CCLS), blk, 0, stream>>>(
        nullptr, xpk, wpk1, bs[0], nullptr, nullptr, nullptr, nullptr,
        gendata, ps1, pq1, 512, 0);

    // G2: bn1(h1)->relu -> h2[256], stats -> ps2 (nbt=32). 64x256 tile, 512 blocks.
    gemm4n_kernel<512, true><<<dim3(32, 1, CCLS), blk, 0, stream>>>(
        gendata, wpk2, bs[1], ps1, pq1, g[0], be[0],
        h2, ps2, pq2, 256, 16);

    // G3: bn2(h2)->relu -> h3[128], stats -> ps3 (BM=64, nbt=32)
    gemm4w_kernel<64, 256, false, true, true><<<dim3(32, 1, CCLS), blk, 0, stream>>>(
        h2, nullptr, wpk3, bs[2], ps2, pq2, g[1], be[1],
        h3, ps3, pq3, 128, 32);

    // G4: bn3(h3)->relu -> h4[256] (aliases h2), stats -> ps4 (nbt=32). 512 blocks.
    gemm4n_kernel<128, true><<<dim3(32, 1, CCLS), blk, 0, stream>>>(
        h3, wpk4, bs[3], ps3, pq3, g[2], be[2],
        h4, ps4, pq4, 256, 32);

    // G5: bn4(h4)->relu -> gendata[512] (no stats). 1024 blocks.
    gemm4n_kernel<256, false><<<dim3(32, 2, CCLS), blk, 0, stream>>>(
        h4, wpk5, bs[4], ps4, pq4, g[3], be[3],
        gendata, nullptr, nullptr, 512, 32);

    label_kernel<<<dim3(CCLS * BB / 256), blk, 0, stream>>>(label);
}

// Round 12
// 211.496 us; speedup vs baseline: 1.1221x; 1.1221x over previous
//
#include <hip/hip_runtime.h>
#include <hip/hip_bf16.h>
#include <math.h>

#define CCLS 16
#define BB   2048

using bf16x8 = __attribute__((ext_vector_type(8))) short;
using short8 = __attribute__((ext_vector_type(8))) short;
using f32x4  = __attribute__((ext_vector_type(4))) float;

// fp32 -> (hi, lo) bf16 split (RNE; hi+lo reproduces ~24 mantissa bits)
__device__ __forceinline__ void split2(float e, short& hi, short& lo) {
    __hip_bfloat16 h = __float2bfloat16(e);
    hi = __builtin_bit_cast(short, h);
    lo = __builtin_bit_cast(short, __float2bfloat16(e - __bfloat162float(h)));
}

// LDS-visibility barrier that does NOT drain vmcnt.
__device__ __forceinline__ void soft_barrier() {
    asm volatile("s_waitcnt lgkmcnt(0)" ::: "memory");
    __builtin_amdgcn_s_barrier();
    asm volatile("" ::: "memory");
}

// global -> LDS direct copy, 16B/lane; lds dest is wave-uniform base
__device__ __forceinline__ void gll16(const void* g, void* l) {
    __builtin_amdgcn_global_load_lds(
        (const __attribute__((address_space(1))) unsigned*)g,
        (__attribute__((address_space(3))) unsigned*)l, 16, 0, 0);
}

// XCD class-clustering remap (perf-only, bijective): default dispatch is
// round-robin by linear wg id mod 8 XCDs; this remap gives XCD k the two
// classes {2k, 2k+1} so each XCD's W-panel working set fits its 4MB L2.
// Valid whenever gridDim.z == CCLS and total blocks is a multiple of 16.
#define XCD_REMAP(btile, otile, c)                                             \
    int btile, otile, c;                                                       \
    {                                                                          \
        const int bpcls = gridDim.x * gridDim.y;                               \
        const int id = blockIdx.x + gridDim.x * (blockIdx.y + gridDim.y * blockIdx.z); \
        const int j = id >> 3;                                                 \
        c = 2 * (id & 7) + j / bpcls;                                          \
        const int r = j % bpcls;                                               \
        btile = r % gridDim.x;                                                 \
        otile = r / gridDim.x;                                                 \
    }

// Fragment-major layout for a 128-row x 32-k bf16 tile (8 KB/plane):
//   L(row, kchunk) = (row>>4)<<10 | kchunk<<8 | (row&15)<<4   (kchunk = k/8)

// ---------------------------------------------------------------------------
// One-time pack: x and W1..W5 -> [hi 8KB][lo 8KB] fragment-major 128x32 tiles.
// ---------------------------------------------------------------------------
struct PackDesc {
    const float* src[6];
    int nrt[6];
    int ksn[6];
    int kreal[6];
    int beg[7];
};

__global__ __launch_bounds__(256)
void pack_kernel(PackDesc d, char* __restrict__ base)
{
    const int bid = blockIdx.x;
    int s = 0;
    #pragma unroll
    for (int i = 0; i < 5; ++i) s += (bid >= d.beg[i + 1]);
    const int t    = bid - d.beg[s];
    const int ksn  = d.ksn[s], nrt = d.nrt[s], kreal = d.kreal[s];
    const int perc = nrt * ksn;
    const int c  = t / perc;
    const int r  = t - c * perc;
    const int rt = r / ksn;
    const int ks = r - rt * ksn;
    const float* src = d.src[s] + ((size_t)(c * nrt + rt) * 128) * kreal;
    char* dst = base + (size_t)bid * 16384;
    const int tid = threadIdx.x;

    #pragma unroll
    for (int it = 0; it < 2; ++it) {
        const int row = (tid >> 2) + (it << 6);
        const int cc  = tid & 3;
        const int q   = ((row >> 4) << 10) | (cc << 8) | ((row & 15) << 4);
        const int k0  = ks * 32 + cc * 8;
        const float* sp = src + (size_t)row * kreal + k0;
        float e[8];
        if (k0 + 8 <= kreal) {
            float4 v0 = *(const float4*)sp;
            float4 v1 = *(const float4*)(sp + 4);
            e[0]=v0.x; e[1]=v0.y; e[2]=v0.z; e[3]=v0.w;
            e[4]=v1.x; e[5]=v1.y; e[6]=v1.z; e[7]=v1.w;
        } else {
            #pragma unroll
            for (int j = 0; j < 8; ++j) e[j] = (k0 + j < kreal) ? sp[j] : 0.f;
        }
        short hv[8], lv[8];
        #pragma unroll
        for (int j = 0; j < 8; ++j) split2(e[j], hv[j], lv[j]);
        *(short8*)(dst + q)        = (short8){hv[0],hv[1],hv[2],hv[3],hv[4],hv[5],hv[6],hv[7]};
        *(short8*)(dst + 8192 + q) = (short8){lv[0],lv[1],lv[2],lv[3],lv[4],lv[5],lv[6],lv[7]};
    }
}

// ---------------------------------------------------------------------------
// 4-wave kernel (R8 structure): PREPACK path for G1, reg-staged path for G3.
// ---------------------------------------------------------------------------
template<int BM, int K, bool PREPACK, bool FUSE_BN, bool WRITE_STATS>
__global__ __launch_bounds__(256, 2)
void gemm4w_kernel(const float* __restrict__ A, const char* __restrict__ Apk,
                   const char* __restrict__ Wpk, const float* __restrict__ bias,
                   const float* __restrict__ psumIn, const float* __restrict__ psqIn,
                   const float* __restrict__ gIn, const float* __restrict__ beIn,
                   float* __restrict__ Out,
                   float* __restrict__ psumOut, float* __restrict__ psqOut,
                   const int Fout, const int nbtIn)
{
    constexpr int KS    = (K + 31) / 32;
    constexpr int PLANE = BM * 64;
    constexpr int BUFSZ = PREPACK ? 32768 : 2 * PLANE;
    static_assert(PREPACK || (K % 32 == 0), "");
    static_assert(PREPACK || (KS % 2 == 0) || (KS == 1), "");

    __shared__ __align__(16) char sm[2 * BUFSZ + (FUSE_BN ? 8 * K : 16)];
    float* scs = (float*)(sm + 2 * BUFSZ);
    float* shs = scs + (FUSE_BN ? K : 0);

    const int tid = threadIdx.x;
    XCD_REMAP(btile, otile, c)

    if (FUSE_BN) {
        for (int f = tid; f < K; f += 256) {
            const float* ps = psumIn + ((size_t)c * K + f) * nbtIn;
            const float* pq = psqIn  + ((size_t)c * K + f) * nbtIn;
            float s = 0.f, q = 0.f;
            for (int t = 0; t < nbtIn; t += 4) {
                float4 a4 = *(const float4*)(ps + t);
                float4 b4 = *(const float4*)(pq + t);
                s += (a4.x + a4.y) + (a4.z + a4.w);
                q += (b4.x + b4.y) + (b4.z + b4.w);
            }
            const float mean = s * (1.f / BB);
            const float var  = q * (1.f / BB) - mean * mean;
            const float rstd = rsqrtf(var + 1e-5f);
            const float scv  = gIn[(size_t)c * K + f] * rstd;
            scs[f] = scv;
            shs[f] = fmaf(-mean, scv, beIn[(size_t)c * K + f]);
        }
        __syncthreads();
    }

    const int b0 = btile * BM, o0 = otile * 128;
    const int OT = Fout >> 7;
    const char* wbase = Wpk + (size_t)((c * OT + otile) * KS) * 16384;
    const char* abase = PREPACK ? (Apk + (size_t)((c * gridDim.x + btile) * KS) * 16384) : nullptr;

    const int lane = tid & 63, wv = tid >> 6;
    const int fr = lane & 15, fkc = lane >> 4;
    const int wrow = (BM == 128) ? ((wv >> 1) << 6) : ((wv >> 1) << 5);
    const int wcol = (wv & 1) << 6;
    const int wrg = wrow >> 4, wcg = wcol >> 4;
    constexpr int MI = BM / 32;

    f32x4 acc[MI][4];
    #pragma unroll
    for (int mi = 0; mi < MI; ++mi)
        #pragma unroll
        for (int ni = 0; ni < 4; ++ni)
            acc[mi][ni] = (f32x4){0.f, 0.f, 0.f, 0.f};

    if constexpr (PREPACK) {
        auto stageTile = [&](int nb, int ks) {
            const char* at = abase + (size_t)ks * 16384;
            const char* wt = wbase + (size_t)ks * 16384;
            char* dst = sm + nb;
            #pragma unroll
            for (int i = 0; i < 4; ++i) {
                const int rg = ((wv << 2) + i) << 10;
                gll16(at + rg + (lane << 4), dst + rg);
                gll16(wt + rg + (lane << 4), dst + 16384 + rg);
            }
        };
        stageTile(0, 0);
        __syncthreads();
        for (int ks = 0; ks < KS; ++ks) {
            const int cb = (ks & 1) ? BUFSZ : 0;
            if (ks + 1 < KS) stageTile(cb ^ BUFSZ, ks + 1);
            bf16x8 ah[MI], al[MI], wh[4], wl[4];
            #pragma unroll
            for (int i = 0; i < 4; ++i) {
                const int wo = ((wcg + i) << 10) | (fkc << 8) | (fr << 4);
                wh[i] = *(const bf16x8*)(sm + cb + 16384 + wo);
                wl[i] = *(const bf16x8*)(sm + cb + 24576 + wo);
            }
            #pragma unroll
            for (int i = 0; i < MI; ++i) {
                const int ao = ((wrg + i) << 10) | (fkc << 8) | (fr << 4);
                ah[i] = *(const bf16x8*)(sm + cb + ao);
                al[i] = *(const bf16x8*)(sm + cb + 8192 + ao);
            }
            #pragma unroll
            for (int mi = 0; mi < MI; ++mi)
                #pragma unroll
                for (int ni = 0; ni < 4; ++ni) {
                    acc[mi][ni] = __builtin_amdgcn_mfma_f32_16x16x32_bf16(ah[mi], wh[ni], acc[mi][ni], 0, 0, 0);
                    acc[mi][ni] = __builtin_amdgcn_mfma_f32_16x16x32_bf16(ah[mi], wl[ni], acc[mi][ni], 0, 0, 0);
                    acc[mi][ni] = __builtin_amdgcn_mfma_f32_16x16x32_bf16(al[mi], wh[ni], acc[mi][ni], 0, 0, 0);
                }
            __syncthreads();
        }
    } else {
        constexpr int NV = BM / 32;
        const int arow = (BM == 128) ? (tid >> 1) : (tid >> 2);
        const int asub = (BM == 128) ? (tid & 1)  : (tid & 3);
        const int ak0  = (BM == 128) ? (asub << 4) : (asub << 3);
        const int kch  = (BM == 128) ? (asub << 1) : asub;
        const int awr  = ((arow >> 4) << 10) | (kch << 8) | ((arow & 15) << 4);
        const float* Arow = A + ((size_t)c * BB + b0 + arow) * K;

        auto loadA = [&](float4 (&av)[NV], int gk0) {
            #pragma unroll
            for (int i = 0; i < NV; ++i)
                av[i] = *(const float4*)(Arow + gk0 + (i << 2));
        };
        auto loadW = [&](bf16x8 (&w)[8], int ks) {
            const char* wt = wbase + (size_t)ks * 16384;
            #pragma unroll
            for (int i = 0; i < 4; ++i) {
                const int wo = ((wcg + i) << 10) | (fkc << 8) | (fr << 4);
                w[i]     = *(const bf16x8*)(wt + wo);
                w[4 + i] = *(const bf16x8*)(wt + 8192 + wo);
            }
        };
        auto cvtStore = [&](char* dstbase, const float4 (&a)[NV], int gk0) {
            float e[NV * 4];
            #pragma unroll
            for (int i = 0; i < NV; ++i) {
                e[i*4+0] = a[i].x; e[i*4+1] = a[i].y; e[i*4+2] = a[i].z; e[i*4+3] = a[i].w;
            }
            if constexpr (FUSE_BN) {
                #pragma unroll
                for (int i = 0; i < NV; ++i) {
                    const float4 sc = *(const float4*)(scs + gk0 + (i << 2));
                    const float4 sh = *(const float4*)(shs + gk0 + (i << 2));
                    e[i*4+0] = fmaxf(0.f, fmaf(e[i*4+0], sc.x, sh.x));
                    e[i*4+1] = fmaxf(0.f, fmaf(e[i*4+1], sc.y, sh.y));
                    e[i*4+2] = fmaxf(0.f, fmaf(e[i*4+2], sc.z, sh.z));
                    e[i*4+3] = fmaxf(0.f, fmaf(e[i*4+3], sc.w, sh.w));
                }
            }
            short h[NV*4], l[NV*4];
            #pragma unroll
            for (int j = 0; j < NV*4; ++j) split2(e[j], h[j], l[j]);
            *(short8*)(dstbase + awr)         = (short8){h[0],h[1],h[2],h[3],h[4],h[5],h[6],h[7]};
            *(short8*)(dstbase + PLANE + awr) = (short8){l[0],l[1],l[2],l[3],l[4],l[5],l[6],l[7]};
            if constexpr (NV == 4) {
                *(short8*)(dstbase + awr + 256)         = (short8){h[8],h[9],h[10],h[11],h[12],h[13],h[14],h[15]};
                *(short8*)(dstbase + PLANE + awr + 256) = (short8){l[8],l[9],l[10],l[11],l[12],l[13],l[14],l[15]};
            }
        };

        bf16x8 wcA[8], wcB[8];
        float4 avP[NV], avQ[NV];

        auto step = [&](int ks, char* cbp, char* nbp,
                        float4 (&avUse)[NV], float4 (&avLoad)[NV],
                        bf16x8 (&wUse)[8], bf16x8 (&wLoad)[8]) {
            const bool hn  = (ks + 1) < KS;
            const bool hn2 = (ks + 2) < KS;
            if (hn2) loadA(avLoad, ((ks + 2) << 5) + ak0);
            if (hn)  loadW(wLoad, ks + 1);
            bf16x8 ah[MI], al[MI];
            #pragma unroll
            for (int i = 0; i < MI; ++i) {
                const int ao = ((wrg + i) << 10) | (fkc << 8) | (fr << 4);
                ah[i] = *(const bf16x8*)(cbp + ao);
                al[i] = *(const bf16x8*)(cbp + PLANE + ao);
            }
            #pragma unroll
            for (int mi = 0; mi < MI; ++mi)
                #pragma unroll
                for (int ni = 0; ni < 4; ++ni) {
                    acc[mi][ni] = __builtin_amdgcn_mfma_f32_16x16x32_bf16(ah[mi], wUse[ni],     acc[mi][ni], 0, 0, 0);
                    acc[mi][ni] = __builtin_amdgcn_mfma_f32_16x16x32_bf16(ah[mi], wUse[4 + ni], acc[mi][ni], 0, 0, 0);
                    acc[mi][ni] = __builtin_amdgcn_mfma_f32_16x16x32_bf16(al[mi], wUse[ni],     acc[mi][ni], 0, 0, 0);
                }
            if (hn) cvtStore(nbp, avUse, ((ks + 1) << 5) + ak0);
            soft_barrier();
        };

        {
            float4 av0[NV];
            loadA(av0, ak0);
            loadW(wcA, 0);
            if (KS > 1) loadA(avP, 32 + ak0);
            cvtStore(sm, av0, ak0);
        }
        soft_barrier();

        for (int ks = 0; ks < KS; ks += 2) {
            step(ks,     sm,         sm + BUFSZ, avP, avQ, wcA, wcB);
            step(ks + 1, sm + BUFSZ, sm,         avQ, avP, wcB, wcA);
        }
    }

    // ---- epilogue ----
    float bv[4];
    #pragma unroll
    for (int ni = 0; ni < 4; ++ni)
        bv[ni] = bias[(size_t)c * Fout + o0 + wcol + (ni << 4) + fr];

    float p[4] = {}, q[4] = {};
    const int rsub = (lane >> 4) << 2;
    #pragma unroll
    for (int mi = 0; mi < MI; ++mi) {
        #pragma unroll
        for (int j = 0; j < 4; ++j) {
            const int row = b0 + wrow + (mi << 4) + rsub + j;
            float* op = Out + ((size_t)c * BB + row) * Fout + o0 + wcol;
            #pragma unroll
            for (int ni = 0; ni < 4; ++ni) {
                const float v = acc[mi][ni][j] + bv[ni];
                op[(ni << 4) + fr] = v;
                if (WRITE_STATS) { p[ni] += v; q[ni] += v * v; }
            }
        }
    }

    if (WRITE_STATS) {
        #pragma unroll
        for (int ni = 0; ni < 4; ++ni) {
            p[ni] += __shfl_xor(p[ni], 16); p[ni] += __shfl_xor(p[ni], 32);
            q[ni] += __shfl_xor(q[ni], 16); q[ni] += __shfl_xor(q[ni], 32);
        }
        __syncthreads();
        float* redp = (float*)sm;
        float* redq = (float*)(sm + 1024);
        if (lane < 16) {
            const int base = (wv >> 1) * 128 + wcol;
            #pragma unroll
            for (int ni = 0; ni < 4; ++ni) {
                redp[base + (ni << 4) + fr] = p[ni];
                redq[base + (ni << 4) + fr] = q[ni];
            }
        }
        __syncthreads();
        if (tid < 128) {
            const float sp = redp[tid] + redp[128 + tid];
            const float sq = redq[tid] + redq[128 + tid];
            const size_t o = ((size_t)c * Fout + o0 + tid) * gridDim.x + btile;
            psumOut[o] = sp;
            psqOut[o]  = sq;
        }
    }
}

// ---------------------------------------------------------------------------
// 8-wave (512-thread) 128x256 tile kernel: per-wave 64x64 (48 MFMA/step),
// full-N cvt-dedup (each A element converted once per block). Waves 2Mx4N.
// launch_bounds(512,4): allows 2 blocks/CU where the grid supplies them (G5).
// ---------------------------------------------------------------------------
template<int K, bool WRITE_STATS>
__global__ __launch_bounds__(512, 4)
void gemm8w_kernel(const float* __restrict__ A, const char* __restrict__ Wpk,
                   const float* __restrict__ bias,
                   const float* __restrict__ psumIn, const float* __restrict__ psqIn,
                   const float* __restrict__ gIn, const float* __restrict__ beIn,
                   float* __restrict__ Out,
                   float* __restrict__ psumOut, float* __restrict__ psqOut,
                   const int Fout, const int nbtIn)
{
    constexpr int KS    = K / 32;
    constexpr int PLANE = 8192;     // 128x32 bf16 plane
    constexpr int BUFSZ = 16384;    // hi+lo
    static_assert(K % 32 == 0 && (KS % 2 == 0), "");

    __shared__ __align__(16) char sm[2 * BUFSZ + 8 * K];
    float* scs = (float*)(sm + 2 * BUFSZ);
    float* shs = scs + K;

    const int tid = threadIdx.x;
    XCD_REMAP(btile, otile, c)

    // folded combine: BN scale/shift for INPUT features
    for (int f = tid; f < K; f += 512) {
        const float* ps = psumIn + ((size_t)c * K + f) * nbtIn;
        const float* pq = psqIn  + ((size_t)c * K + f) * nbtIn;
        float s = 0.f, q = 0.f;
        for (int t = 0; t < nbtIn; t += 4) {
            float4 a4 = *(const float4*)(ps + t);
            float4 b4 = *(const float4*)(pq + t);
            s += (a4.x + a4.y) + (a4.z + a4.w);
            q += (b4.x + b4.y) + (b4.z + b4.w);
        }
        const float mean = s * (1.f / BB);
        const float var  = q * (1.f / BB) - mean * mean;
        const float rstd = rsqrtf(var + 1e-5f);
        const float scv  = gIn[(size_t)c * K + f] * rstd;
        scs[f] = scv;
        shs[f] = fmaf(-mean, scv, beIn[(size_t)c * K + f]);
    }
    __syncthreads();

    const int b0 = btile * 128, o0 = otile * 256;
    const int OT128 = Fout >> 7;

    // A staging map: 512 threads, 8 floats each (one 16B frag slot)
    const int arow = tid >> 2, asub = tid & 3;
    const int ak0  = asub << 3;
    const int awr  = ((arow >> 4) << 10) | (asub << 8) | ((arow & 15) << 4);
    const float* Arow = A + ((size_t)c * BB + b0 + arow) * K;

    // wave map: 2(M) x 4(N), each wave 64x64
    const int lane = tid & 63, wv = tid >> 6;
    const int wr = wv >> 2, nc = wv & 3;
    const int wrow = wr << 6, wcol = nc << 6;
    const int fr = lane & 15, fkc = lane >> 4;
    const int wrg = wrow >> 4;
    const int wtile = wcol >> 7;            // which packed 128-col tile (0/1)
    const int wcg = (wcol >> 4) & 7;        // 16-col group within that tile
    const char* wbase = Wpk + (size_t)((c * OT128 + otile * 2 + wtile) * KS) * 16384;

    auto loadA = [&](float4 (&av)[2], int gk0) {
        av[0] = *(const float4*)(Arow + gk0);
        av[1] = *(const float4*)(Arow + gk0 + 4);
    };
    auto loadW = [&](bf16x8 (&w)[8], int ks) {
        const char* wt = wbase + (size_t)ks * 16384;
        #pragma unroll
        for (int i = 0; i < 4; ++i) {
            const int wo = ((wcg + i) << 10) | (fkc << 8) | (fr << 4);
            w[i]     = *(const bf16x8*)(wt + wo);
            w[4 + i] = *(const bf16x8*)(wt + 8192 + wo);
        }
    };
    auto cvtStore = [&](char* dstbase, const float4 (&a)[2], int gk0) {
        float e[8] = {a[0].x, a[0].y, a[0].z, a[0].w, a[1].x, a[1].y, a[1].z, a[1].w};
        const float4 sc0 = *(const float4*)(scs + gk0);
        const float4 sc1 = *(const float4*)(scs + gk0 + 4);
        const float4 sh0 = *(const float4*)(shs + gk0);
        const float4 sh1 = *(const float4*)(shs + gk0 + 4);
        e[0] = fmaxf(0.f, fmaf(e[0], sc0.x, sh0.x));
        e[1] = fmaxf(0.f, fmaf(e[1], sc0.y, sh0.y));
        e[2] = fmaxf(0.f, fmaf(e[2], sc0.z, sh0.z));
        e[3] = fmaxf(0.f, fmaf(e[3], sc0.w, sh0.w));
        e[4] = fmaxf(0.f, fmaf(e[4], sc1.x, sh1.x));
        e[5] = fmaxf(0.f, fmaf(e[5], sc1.y, sh1.y));
        e[6] = fmaxf(0.f, fmaf(e[6], sc1.z, sh1.z));
        e[7] = fmaxf(0.f, fmaf(e[7], sc1.w, sh1.w));
        short h[8], l[8];
        #pragma unroll
        for (int j = 0; j < 8; ++j) split2(e[j], h[j], l[j]);
        *(short8*)(dstbase + awr)         = (short8){h[0],h[1],h[2],h[3],h[4],h[5],h[6],h[7]};
        *(short8*)(dstbase + PLANE + awr) = (short8){l[0],l[1],l[2],l[3],l[4],l[5],l[6],l[7]};
    };

    f32x4 acc[4][4];
    #pragma unroll
    for (int mi = 0; mi < 4; ++mi)
        #pragma unroll
        for (int ni = 0; ni < 4; ++ni)
            acc[mi][ni] = (f32x4){0.f, 0.f, 0.f, 0.f};

    bf16x8 wcA[8], wcB[8];
    float4 avP[2], avQ[2];

    auto step = [&](int ks, char* cbp, char* nbp,
                    float4 (&avUse)[2], float4 (&avLoad)[2],
                    bf16x8 (&wUse)[8], bf16x8 (&wLoad)[8]) {
        const bool hn  = (ks + 1) < KS;
        const bool hn2 = (ks + 2) < KS;
        if (hn2) loadA(avLoad, ((ks + 2) << 5) + ak0);
        if (hn)  loadW(wLoad, ks + 1);
        bf16x8 ah[4], al[4];
        #pragma unroll
        for (int i = 0; i < 4; ++i) {
            const int ao = ((wrg + i) << 10) | (fkc << 8) | (fr << 4);
            ah[i] = *(const bf16x8*)(cbp + ao);
            al[i] = *(const bf16x8*)(cbp + PLANE + ao);
        }
        #pragma unroll
        for (int mi = 0; mi < 4; ++mi)
            #pragma unroll
            for (int ni = 0; ni < 4; ++ni) {
                acc[mi][ni] = __builtin_amdgcn_mfma_f32_16x16x32_bf16(ah[mi], wUse[ni],     acc[mi][ni], 0, 0, 0);
                acc[mi][ni] = __builtin_amdgcn_mfma_f32_16x16x32_bf16(ah[mi], wUse[4 + ni], acc[mi][ni], 0, 0, 0);
                acc[mi][ni] = __builtin_amdgcn_mfma_f32_16x16x32_bf16(al[mi], wUse[ni],     acc[mi][ni], 0, 0, 0);
            }
        if (hn) cvtStore(nbp, avUse, ((ks + 1) << 5) + ak0);
        soft_barrier();
    };

    {
        float4 av0[2];
        loadA(av0, ak0);
        loadW(wcA, 0);
        loadA(avP, 32 + ak0);
        cvtStore(sm, av0, ak0);
    }
    soft_barrier();

    for (int ks = 0; ks < KS; ks += 2) {
        step(ks,     sm,         sm + BUFSZ, avP, avQ, wcA, wcB);
        step(ks + 1, sm + BUFSZ, sm,         avQ, avP, wcB, wcA);
    }

    // ---- epilogue: bias, store, deterministic partial BN stats ----
    // C/D layout: col = lane&15, row = (lane>>4)*4 + reg
    float bv[4];
    #pragma unroll
    for (int ni = 0; ni < 4; ++ni)
        bv[ni] = bias[(size_t)c * Fout + o0 + wcol + (ni << 4) + fr];

    float p[4] = {}, q[4] = {};
    const int rsub = (lane >> 4) << 2;
    #pragma unroll
    for (int mi = 0; mi < 4; ++mi) {
        #pragma unroll
        for (int j = 0; j < 4; ++j) {
            const int row = b0 + wrow + (mi << 4) + rsub + j;
            float* op = Out + ((size_t)c * BB + row) * Fout + o0 + wcol;
            #pragma unroll
            for (int ni = 0; ni < 4; ++ni) {
                const float v = acc[mi][ni][j] + bv[ni];
                op[(ni << 4) + fr] = v;
                if (WRITE_STATS) { p[ni] += v; q[ni] += v * v; }
            }
        }
    }

    if (WRITE_STATS) {
        #pragma unroll
        for (int ni = 0; ni < 4; ++ni) {
            p[ni] += __shfl_xor(p[ni], 16); p[ni] += __shfl_xor(p[ni], 32);
            q[ni] += __shfl_xor(q[ni], 16); q[ni] += __shfl_xor(q[ni], 32);
        }
        __syncthreads();                    // loop done; reuse sm as scratch
        float* redp = (float*)sm;           // [2][256]
        float* redq = (float*)(sm + 2048);
        if (lane < 16) {
            const int base = wr * 256 + wcol;
            #pragma unroll
            for (int ni = 0; ni < 4; ++ni) {
                redp[base + (ni << 4) + fr] = p[ni];
                redq[base + (ni << 4) + fr] = q[ni];
            }
        }
        __syncthreads();
        if (tid < 256) {
            const float sp = redp[tid] + redp[256 + tid];
            const float sq = redq[tid] + redq[256 + tid];
            const size_t o = ((size_t)c * Fout + o0 + tid) * gridDim.x + btile;
            psumOut[o] = sp;
            psqOut[o]  = sq;
        }
    }
}

__global__ __launch_bounds__(256)
void label_kernel(float* __restrict__ out)
{
    const int i = blockIdx.x * 256 + threadIdx.x;
    out[i] = (float)(i >> 11);   // i / 2048
}

// ---------------------------------------------------------------------------
extern "C" void kernel_launch(void* const* d_in, const int* in_sizes, int n_in,
                              void* d_out, int out_size, void* d_ws, size_t ws_size,
                              hipStream_t stream)
{
    const float* x = (const float*)d_in[0];
    const float* W[5];  const float* bs[5];
    for (int l = 0; l < 5; ++l) { W[l] = (const float*)d_in[1 + 2 * l]; bs[l] = (const float*)d_in[2 + 2 * l]; }
    const float* g[4];  const float* be[4];
    for (int l = 0; l < 4; ++l) { g[l] = (const float*)d_in[11 + 2 * l]; be[l] = (const float*)d_in[12 + 2 * l]; }

    float* out     = (float*)d_out;
    float* gendata = out;                              // [C*BB, 512] — doubles as h1
    float* label   = out + (size_t)CCLS * BB * 512;

    float* ws  = (float*)d_ws;
    float* h2  = ws;                                   // 32MB
    float* h3  = h2 + 8388608;                         // 16MB
    float* h4  = h2;                                   // alias: h2 dead after G3
    float* ps1 = h3 + 4194304;
    float* pq1 = ps1 + 131072;
    float* ps2 = pq1 + 131072;
    float* pq2 = ps2 + 65536;
    float* ps3 = pq2 + 65536;
    float* pq3 = ps3 + 65536;
    float* ps4 = pq3 + 65536;
    float* pq4 = ps4 + 65536;
    char*  pack = (char*)(pq4 + 65536);                // 2560 x 16KB = 40MB

    const char* xpk  = pack;
    const char* wpk1 = pack + (size_t)1024 * 16384;
    const char* wpk2 = pack + (size_t)1280 * 16384;
    const char* wpk3 = pack + (size_t)1792 * 16384;
    const char* wpk4 = pack + (size_t)1920 * 16384;
    const char* wpk5 = pack + (size_t)2048 * 16384;

    const dim3 blk(256);

    PackDesc pd;
    pd.src[0] = x;    pd.src[1] = W[0]; pd.src[2] = W[1];
    pd.src[3] = W[2]; pd.src[4] = W[3]; pd.src[5] = W[4];
    const int nrt[6]   = {16, 4, 2, 1, 2, 4};
    const int ksn[6]   = {4, 4, 16, 8, 4, 8};
    const int kreal[6] = {100, 100, 512, 256, 128, 256};
    const int beg[7]   = {0, 1024, 1280, 1792, 1920, 2048, 2560};
    for (int i = 0; i < 6; ++i) { pd.nrt[i] = nrt[i]; pd.ksn[i] = ksn[i]; pd.kreal[i] = kreal[i]; }
    for (int i = 0; i < 7; ++i) pd.beg[i] = beg[i];
    pack_kernel<<<dim3(2560), blk, 0, stream>>>(pd, pack);

    // G1: x[K=100->128] -> h1(=gendata)[512], stats -> ps1 (nbt=16)
    gemm4w_kernel<128, 128, true, false, true><<<dim3(16, 4, CCLS), blk, 0, stream>>>(
        nullptr, xpk, wpk1, bs[0], nullptr, nullptr, nullptr, nullptr,
        gendata, ps1, pq1, 512, 0);

    // G2: bn1(h1)->relu -> h2[256], stats -> ps2 (nbt=16). 8-wave, OT=1.
    gemm8w_kernel<512, true><<<dim3(16, 1, CCLS), dim3(512), 0, stream>>>(
        gendata, wpk2, bs[1], ps1, pq1, g[0], be[0],
        h2, ps2, pq2, 256, 16);

    // G3: bn2(h2)->relu -> h3[128], stats -> ps3 (BM=64, nbt=32)
    gemm4w_kernel<64, 256, false, true, true><<<dim3(32, 1, CCLS), blk, 0, stream>>>(
        h2, nullptr, wpk3, bs[2], ps2, pq2, g[1], be[1],
        h3, ps3, pq3, 128, 16);

    // G4: bn3(h3)->relu -> h4[256] (aliases h2), stats -> ps4 (nbt=16). 8-wave.
    gemm8w_kernel<128, true><<<dim3(16, 1, CCLS), dim3(512), 0, stream>>>(
        h3, wpk4, bs[3], ps3, pq3, g[2], be[2],
        h4, ps4, pq4, 256, 32);

    // G5: bn4(h4)->relu -> gendata[512] (no stats). 8-wave, OT=2, 512 blocks.
    gemm8w_kernel<256, false><<<dim3(16, 2, CCLS), dim3(512), 0, stream>>>(
        h4, wpk5, bs[4], ps4, pq4, g[3], be[3],
        gendata, nullptr, nullptr, 512, 16);

    label_kernel<<<dim3(CCLS * BB / 256), blk, 0, stream>>>(label);
}

// Round 13
// 167.168 us; speedup vs baseline: 1.4196x; 1.2652x over previous
//
#include <hip/hip_runtime.h>
#include <hip/hip_bf16.h>
#include <math.h>

#define CCLS 16
#define BB   2048

using bf16x8 = __attribute__((ext_vector_type(8))) short;
using short8 = __attribute__((ext_vector_type(8))) short;
using f32x4  = __attribute__((ext_vector_type(4))) float;

// fp32 -> (hi, lo) bf16 split (RNE; hi+lo reproduces ~24 mantissa bits)
__device__ __forceinline__ void split2(float e, short& hi, short& lo) {
    __hip_bfloat16 h = __float2bfloat16(e);
    hi = __builtin_bit_cast(short, h);
    lo = __builtin_bit_cast(short, __float2bfloat16(e - __bfloat162float(h)));
}

// LDS-visibility barrier that does NOT drain vmcnt.
__device__ __forceinline__ void soft_barrier() {
    asm volatile("s_waitcnt lgkmcnt(0)" ::: "memory");
    __builtin_amdgcn_s_barrier();
    asm volatile("" ::: "memory");
}

// global -> LDS direct copy, 16B/lane; lds dest is wave-uniform base
__device__ __forceinline__ void gll16(const void* g, void* l) {
    __builtin_amdgcn_global_load_lds(
        (const __attribute__((address_space(1))) unsigned*)g,
        (__attribute__((address_space(3))) unsigned*)l, 16, 0, 0);
}

// L2-warm prefetch of a 16KB W tile: 64 lanes x 2 x 128B lines. Results kept
// live via empty asm (rule #17) so the loads aren't DCE'd. Perf-only.
__device__ __forceinline__ void prefetchW(const char* wt2, int lane) {
    unsigned p0 = *(const unsigned*)(wt2 + (lane << 8));
    unsigned p1 = *(const unsigned*)(wt2 + (lane << 8) + 128);
    asm volatile("" :: "v"(p0), "v"(p1));
}

// Fragment-major layout for a 128-row x 32-k bf16 tile (8 KB/plane):
//   L(row, kchunk) = (row>>4)<<10 | kchunk<<8 | (row&15)<<4   (kchunk = k/8)

// ---------------------------------------------------------------------------
// One-time pack: x and W1..W5 -> [hi 8KB][lo 8KB] fragment-major 128x32 tiles.
// ---------------------------------------------------------------------------
struct PackDesc {
    const float* src[6];
    int nrt[6];
    int ksn[6];
    int kreal[6];
    int beg[7];
};

__global__ __launch_bounds__(256)
void pack_kernel(PackDesc d, char* __restrict__ base)
{
    const int bid = blockIdx.x;
    int s = 0;
    #pragma unroll
    for (int i = 0; i < 5; ++i) s += (bid >= d.beg[i + 1]);
    const int t    = bid - d.beg[s];
    const int ksn  = d.ksn[s], nrt = d.nrt[s], kreal = d.kreal[s];
    const int perc = nrt * ksn;
    const int c  = t / perc;
    const int r  = t - c * perc;
    const int rt = r / ksn;
    const int ks = r - rt * ksn;
    const float* src = d.src[s] + ((size_t)(c * nrt + rt) * 128) * kreal;
    char* dst = base + (size_t)bid * 16384;
    const int tid = threadIdx.x;

    #pragma unroll
    for (int it = 0; it < 2; ++it) {
        const int row = (tid >> 2) + (it << 6);
        const int cc  = tid & 3;
        const int q   = ((row >> 4) << 10) | (cc << 8) | ((row & 15) << 4);
        const int k0  = ks * 32 + cc * 8;
        const float* sp = src + (size_t)row * kreal + k0;
        float e[8];
        if (k0 + 8 <= kreal) {
            float4 v0 = *(const float4*)sp;
            float4 v1 = *(const float4*)(sp + 4);
            e[0]=v0.x; e[1]=v0.y; e[2]=v0.z; e[3]=v0.w;
            e[4]=v1.x; e[5]=v1.y; e[6]=v1.z; e[7]=v1.w;
        } else {
            #pragma unroll
            for (int j = 0; j < 8; ++j) e[j] = (k0 + j < kreal) ? sp[j] : 0.f;
        }
        short hv[8], lv[8];
        #pragma unroll
        for (int j = 0; j < 8; ++j) split2(e[j], hv[j], lv[j]);
        *(short8*)(dst + q)        = (short8){hv[0],hv[1],hv[2],hv[3],hv[4],hv[5],hv[6],hv[7]};
        *(short8*)(dst + 8192 + q) = (short8){lv[0],lv[1],lv[2],lv[3],lv[4],lv[5],lv[6],lv[7]};
    }
}

// ---------------------------------------------------------------------------
// 4-wave kernel (R8 structure): PREPACK path for G1, reg-staged path for G3.
// ---------------------------------------------------------------------------
template<int BM, int K, bool PREPACK, bool FUSE_BN, bool WRITE_STATS>
__global__ __launch_bounds__(256, 2)
void gemm4w_kernel(const float* __restrict__ A, const char* __restrict__ Apk,
                   const char* __restrict__ Wpk, const float* __restrict__ bias,
                   const float* __restrict__ psumIn, const float* __restrict__ psqIn,
                   const float* __restrict__ gIn, const float* __restrict__ beIn,
                   float* __restrict__ Out,
                   float* __restrict__ psumOut, float* __restrict__ psqOut,
                   const int Fout, const int nbtIn)
{
    constexpr int KS    = (K + 31) / 32;
    constexpr int PLANE = BM * 64;
    constexpr int BUFSZ = PREPACK ? 32768 : 2 * PLANE;
    static_assert(PREPACK || (K % 32 == 0), "");
    static_assert(PREPACK || (KS % 2 == 0) || (KS == 1), "");

    __shared__ __align__(16) char sm[2 * BUFSZ + (FUSE_BN ? 8 * K : 16)];
    float* scs = (float*)(sm + 2 * BUFSZ);
    float* shs = scs + (FUSE_BN ? K : 0);

    const int tid   = threadIdx.x;
    const int btile = blockIdx.x, otile = blockIdx.y, c = blockIdx.z;

    if (FUSE_BN) {
        for (int f = tid; f < K; f += 256) {
            const float* ps = psumIn + ((size_t)c * K + f) * nbtIn;
            const float* pq = psqIn  + ((size_t)c * K + f) * nbtIn;
            float s = 0.f, q = 0.f;
            for (int t = 0; t < nbtIn; t += 4) {
                float4 a4 = *(const float4*)(ps + t);
                float4 b4 = *(const float4*)(pq + t);
                s += (a4.x + a4.y) + (a4.z + a4.w);
                q += (b4.x + b4.y) + (b4.z + b4.w);
            }
            const float mean = s * (1.f / BB);
            const float var  = q * (1.f / BB) - mean * mean;
            const float rstd = rsqrtf(var + 1e-5f);
            const float scv  = gIn[(size_t)c * K + f] * rstd;
            scs[f] = scv;
            shs[f] = fmaf(-mean, scv, beIn[(size_t)c * K + f]);
        }
        __syncthreads();
    }

    const int b0 = btile * BM, o0 = otile * 128;
    const int OT = Fout >> 7;
    const char* wbase = Wpk + (size_t)((c * OT + otile) * KS) * 16384;
    const char* abase = PREPACK ? (Apk + (size_t)((c * gridDim.x + btile) * KS) * 16384) : nullptr;

    const int lane = tid & 63, wv = tid >> 6;
    const int fr = lane & 15, fkc = lane >> 4;
    const int wrow = (BM == 128) ? ((wv >> 1) << 6) : ((wv >> 1) << 5);
    const int wcol = (wv & 1) << 6;
    const int wrg = wrow >> 4, wcg = wcol >> 4;
    constexpr int MI = BM / 32;

    f32x4 acc[MI][4];
    #pragma unroll
    for (int mi = 0; mi < MI; ++mi)
        #pragma unroll
        for (int ni = 0; ni < 4; ++ni)
            acc[mi][ni] = (f32x4){0.f, 0.f, 0.f, 0.f};

    if constexpr (PREPACK) {
        auto stageTile = [&](int nb, int ks) {
            const char* at = abase + (size_t)ks * 16384;
            const char* wt = wbase + (size_t)ks * 16384;
            char* dst = sm + nb;
            #pragma unroll
            for (int i = 0; i < 4; ++i) {
                const int rg = ((wv << 2) + i) << 10;
                gll16(at + rg + (lane << 4), dst + rg);
                gll16(wt + rg + (lane << 4), dst + 16384 + rg);
            }
        };
        stageTile(0, 0);
        __syncthreads();
        for (int ks = 0; ks < KS; ++ks) {
            const int cb = (ks & 1) ? BUFSZ : 0;
            if (ks + 1 < KS) stageTile(cb ^ BUFSZ, ks + 1);
            bf16x8 ah[MI], al[MI], wh[4], wl[4];
            #pragma unroll
            for (int i = 0; i < 4; ++i) {
                const int wo = ((wcg + i) << 10) | (fkc << 8) | (fr << 4);
                wh[i] = *(const bf16x8*)(sm + cb + 16384 + wo);
                wl[i] = *(const bf16x8*)(sm + cb + 24576 + wo);
            }
            #pragma unroll
            for (int i = 0; i < MI; ++i) {
                const int ao = ((wrg + i) << 10) | (fkc << 8) | (fr << 4);
                ah[i] = *(const bf16x8*)(sm + cb + ao);
                al[i] = *(const bf16x8*)(sm + cb + 8192 + ao);
            }
            #pragma unroll
            for (int mi = 0; mi < MI; ++mi)
                #pragma unroll
                for (int ni = 0; ni < 4; ++ni) {
                    acc[mi][ni] = __builtin_amdgcn_mfma_f32_16x16x32_bf16(ah[mi], wh[ni], acc[mi][ni], 0, 0, 0);
                    acc[mi][ni] = __builtin_amdgcn_mfma_f32_16x16x32_bf16(ah[mi], wl[ni], acc[mi][ni], 0, 0, 0);
                    acc[mi][ni] = __builtin_amdgcn_mfma_f32_16x16x32_bf16(al[mi], wh[ni], acc[mi][ni], 0, 0, 0);
                }
            __syncthreads();
        }
    } else {
        constexpr int NV = BM / 32;
        const int arow = (BM == 128) ? (tid >> 1) : (tid >> 2);
        const int asub = (BM == 128) ? (tid & 1)  : (tid & 3);
        const int ak0  = (BM == 128) ? (asub << 4) : (asub << 3);
        const int kch  = (BM == 128) ? (asub << 1) : asub;
        const int awr  = ((arow >> 4) << 10) | (kch << 8) | ((arow & 15) << 4);
        const float* Arow = A + ((size_t)c * BB + b0 + arow) * K;

        auto loadA = [&](float4 (&av)[NV], int gk0) {
            #pragma unroll
            for (int i = 0; i < NV; ++i)
                av[i] = *(const float4*)(Arow + gk0 + (i << 2));
        };
        auto loadW = [&](bf16x8 (&w)[8], int ks) {
            const char* wt = wbase + (size_t)ks * 16384;
            #pragma unroll
            for (int i = 0; i < 4; ++i) {
                const int wo = ((wcg + i) << 10) | (fkc << 8) | (fr << 4);
                w[i]     = *(const bf16x8*)(wt + wo);
                w[4 + i] = *(const bf16x8*)(wt + 8192 + wo);
            }
        };
        auto cvtStore = [&](char* dstbase, const float4 (&a)[NV], int gk0) {
            float e[NV * 4];
            #pragma unroll
            for (int i = 0; i < NV; ++i) {
                e[i*4+0] = a[i].x; e[i*4+1] = a[i].y; e[i*4+2] = a[i].z; e[i*4+3] = a[i].w;
            }
            if constexpr (FUSE_BN) {
                #pragma unroll
                for (int i = 0; i < NV; ++i) {
                    const float4 sc = *(const float4*)(scs + gk0 + (i << 2));
                    const float4 sh = *(const float4*)(shs + gk0 + (i << 2));
                    e[i*4+0] = fmaxf(0.f, fmaf(e[i*4+0], sc.x, sh.x));
                    e[i*4+1] = fmaxf(0.f, fmaf(e[i*4+1], sc.y, sh.y));
                    e[i*4+2] = fmaxf(0.f, fmaf(e[i*4+2], sc.z, sh.z));
                    e[i*4+3] = fmaxf(0.f, fmaf(e[i*4+3], sc.w, sh.w));
                }
            }
            short h[NV*4], l[NV*4];
            #pragma unroll
            for (int j = 0; j < NV*4; ++j) split2(e[j], h[j], l[j]);
            *(short8*)(dstbase + awr)         = (short8){h[0],h[1],h[2],h[3],h[4],h[5],h[6],h[7]};
            *(short8*)(dstbase + PLANE + awr) = (short8){l[0],l[1],l[2],l[3],l[4],l[5],l[6],l[7]};
            if constexpr (NV == 4) {
                *(short8*)(dstbase + awr + 256)         = (short8){h[8],h[9],h[10],h[11],h[12],h[13],h[14],h[15]};
                *(short8*)(dstbase + PLANE + awr + 256) = (short8){l[8],l[9],l[10],l[11],l[12],l[13],l[14],l[15]};
            }
        };

        bf16x8 wcA[8], wcB[8];
        float4 avP[NV], avQ[NV];

        auto step = [&](int ks, char* cbp, char* nbp,
                        float4 (&avUse)[NV], float4 (&avLoad)[NV],
                        bf16x8 (&wUse)[8], bf16x8 (&wLoad)[8]) {
            const bool hn  = (ks + 1) < KS;
            const bool hn2 = (ks + 2) < KS;
            if (hn2) loadA(avLoad, ((ks + 2) << 5) + ak0);
            if (hn)  loadW(wLoad, ks + 1);
            if (hn2) prefetchW(wbase + (size_t)(ks + 2) * 16384, lane);  // L2-warm
            bf16x8 ah[MI], al[MI];
            #pragma unroll
            for (int i = 0; i < MI; ++i) {
                const int ao = ((wrg + i) << 10) | (fkc << 8) | (fr << 4);
                ah[i] = *(const bf16x8*)(cbp + ao);
                al[i] = *(const bf16x8*)(cbp + PLANE + ao);
            }
            #pragma unroll
            for (int mi = 0; mi < MI; ++mi)
                #pragma unroll
                for (int ni = 0; ni < 4; ++ni) {
                    acc[mi][ni] = __builtin_amdgcn_mfma_f32_16x16x32_bf16(ah[mi], wUse[ni],     acc[mi][ni], 0, 0, 0);
                    acc[mi][ni] = __builtin_amdgcn_mfma_f32_16x16x32_bf16(ah[mi], wUse[4 + ni], acc[mi][ni], 0, 0, 0);
                    acc[mi][ni] = __builtin_amdgcn_mfma_f32_16x16x32_bf16(al[mi], wUse[ni],     acc[mi][ni], 0, 0, 0);
                }
            if (hn) cvtStore(nbp, avUse, ((ks + 1) << 5) + ak0);
            soft_barrier();
        };

        {
            float4 av0[NV];
            loadA(av0, ak0);
            loadW(wcA, 0);
            if (KS > 1) loadA(avP, 32 + ak0);
            cvtStore(sm, av0, ak0);
        }
        soft_barrier();

        for (int ks = 0; ks < KS; ks += 2) {
            step(ks,     sm,         sm + BUFSZ, avP, avQ, wcA, wcB);
            step(ks + 1, sm + BUFSZ, sm,         avQ, avP, wcB, wcA);
        }
    }

    // ---- epilogue ----
    float bv[4];
    #pragma unroll
    for (int ni = 0; ni < 4; ++ni)
        bv[ni] = bias[(size_t)c * Fout + o0 + wcol + (ni << 4) + fr];

    float p[4] = {}, q[4] = {};
    const int rsub = (lane >> 4) << 2;
    #pragma unroll
    for (int mi = 0; mi < MI; ++mi) {
        #pragma unroll
        for (int j = 0; j < 4; ++j) {
            const int row = b0 + wrow + (mi << 4) + rsub + j;
            float* op = Out + ((size_t)c * BB + row) * Fout + o0 + wcol;
            #pragma unroll
            for (int ni = 0; ni < 4; ++ni) {
                const float v = acc[mi][ni][j] + bv[ni];
                op[(ni << 4) + fr] = v;
                if (WRITE_STATS) { p[ni] += v; q[ni] += v * v; }
            }
        }
    }

    if (WRITE_STATS) {
        #pragma unroll
        for (int ni = 0; ni < 4; ++ni) {
            p[ni] += __shfl_xor(p[ni], 16); p[ni] += __shfl_xor(p[ni], 32);
            q[ni] += __shfl_xor(q[ni], 16); q[ni] += __shfl_xor(q[ni], 32);
        }
        __syncthreads();
        float* redp = (float*)sm;
        float* redq = (float*)(sm + 1024);
        if (lane < 16) {
            const int base = (wv >> 1) * 128 + wcol;
            #pragma unroll
            for (int ni = 0; ni < 4; ++ni) {
                redp[base + (ni << 4) + fr] = p[ni];
                redq[base + (ni << 4) + fr] = q[ni];
            }
        }
        __syncthreads();
        if (tid < 128) {
            const float sp = redp[tid] + redp[128 + tid];
            const float sq = redq[tid] + redq[128 + tid];
            const size_t o = ((size_t)c * Fout + o0 + tid) * gridDim.x + btile;
            psumOut[o] = sp;
            psqOut[o]  = sq;
        }
    }
}

// ---------------------------------------------------------------------------
// 8-wave (512-thread) 128x256 tile kernel: per-wave 64x64 (48 MFMA/step),
// full-N cvt-dedup (each A element converted once per block). Waves 2Mx4N.
// launch_bounds(512,2): VGPR budget 128 (measured 80+prefetch, no spill).
// ---------------------------------------------------------------------------
template<int K, bool WRITE_STATS>
__global__ __launch_bounds__(512, 2)
void gemm8w_kernel(const float* __restrict__ A, const char* __restrict__ Wpk,
                   const float* __restrict__ bias,
                   const float* __restrict__ psumIn, const float* __restrict__ psqIn,
                   const float* __restrict__ gIn, const float* __restrict__ beIn,
                   float* __restrict__ Out,
                   float* __restrict__ psumOut, float* __restrict__ psqOut,
                   const int Fout, const int nbtIn)
{
    constexpr int KS    = K / 32;
    constexpr int PLANE = 8192;     // 128x32 bf16 plane
    constexpr int BUFSZ = 16384;    // hi+lo
    static_assert(K % 32 == 0 && (KS % 2 == 0), "");

    __shared__ __align__(16) char sm[2 * BUFSZ + 8 * K];
    float* scs = (float*)(sm + 2 * BUFSZ);
    float* shs = scs + K;

    const int tid   = threadIdx.x;
    const int btile = blockIdx.x, otile = blockIdx.y, c = blockIdx.z;

    // folded combine: BN scale/shift for INPUT features
    for (int f = tid; f < K; f += 512) {
        const float* ps = psumIn + ((size_t)c * K + f) * nbtIn;
        const float* pq = psqIn  + ((size_t)c * K + f) * nbtIn;
        float s = 0.f, q = 0.f;
        for (int t = 0; t < nbtIn; t += 4) {
            float4 a4 = *(const float4*)(ps + t);
            float4 b4 = *(const float4*)(pq + t);
            s += (a4.x + a4.y) + (a4.z + a4.w);
            q += (b4.x + b4.y) + (b4.z + b4.w);
        }
        const float mean = s * (1.f / BB);
        const float var  = q * (1.f / BB) - mean * mean;
        const float rstd = rsqrtf(var + 1e-5f);
        const float scv  = gIn[(size_t)c * K + f] * rstd;
        scs[f] = scv;
        shs[f] = fmaf(-mean, scv, beIn[(size_t)c * K + f]);
    }
    __syncthreads();

    const int b0 = btile * 128, o0 = otile * 256;
    const int OT128 = Fout >> 7;

    // A staging map: 512 threads, 8 floats each (one 16B frag slot)
    const int arow = tid >> 2, asub = tid & 3;
    const int ak0  = asub << 3;
    const int awr  = ((arow >> 4) << 10) | (asub << 8) | ((arow & 15) << 4);
    const float* Arow = A + ((size_t)c * BB + b0 + arow) * K;

    // wave map: 2(M) x 4(N), each wave 64x64
    const int lane = tid & 63, wv = tid >> 6;
    const int wr = wv >> 2, nc = wv & 3;
    const int wrow = wr << 6, wcol = nc << 6;
    const int fr = lane & 15, fkc = lane >> 4;
    const int wrg = wrow >> 4;
    const int wtile = wcol >> 7;            // which packed 128-col tile (0/1)
    const int wcg = (wcol >> 4) & 7;        // 16-col group within that tile
    const char* wbase = Wpk + (size_t)((c * OT128 + otile * 2 + wtile) * KS) * 16384;

    auto loadA = [&](float4 (&av)[2], int gk0) {
        av[0] = *(const float4*)(Arow + gk0);
        av[1] = *(const float4*)(Arow + gk0 + 4);
    };
    auto loadW = [&](bf16x8 (&w)[8], int ks) {
        const char* wt = wbase + (size_t)ks * 16384;
        #pragma unroll
        for (int i = 0; i < 4; ++i) {
            const int wo = ((wcg + i) << 10) | (fkc << 8) | (fr << 4);
            w[i]     = *(const bf16x8*)(wt + wo);
            w[4 + i] = *(const bf16x8*)(wt + 8192 + wo);
        }
    };
    auto cvtStore = [&](char* dstbase, const float4 (&a)[2], int gk0) {
        float e[8] = {a[0].x, a[0].y, a[0].z, a[0].w, a[1].x, a[1].y, a[1].z, a[1].w};
        const float4 sc0 = *(const float4*)(scs + gk0);
        const float4 sc1 = *(const float4*)(scs + gk0 + 4);
        const float4 sh0 = *(const float4*)(shs + gk0);
        const float4 sh1 = *(const float4*)(shs + gk0 + 4);
        e[0] = fmaxf(0.f, fmaf(e[0], sc0.x, sh0.x));
        e[1] = fmaxf(0.f, fmaf(e[1], sc0.y, sh0.y));
        e[2] = fmaxf(0.f, fmaf(e[2], sc0.z, sh0.z));
        e[3] = fmaxf(0.f, fmaf(e[3], sc0.w, sh0.w));
        e[4] = fmaxf(0.f, fmaf(e[4], sc1.x, sh1.x));
        e[5] = fmaxf(0.f, fmaf(e[5], sc1.y, sh1.y));
        e[6] = fmaxf(0.f, fmaf(e[6], sc1.z, sh1.z));
        e[7] = fmaxf(0.f, fmaf(e[7], sc1.w, sh1.w));
        short h[8], l[8];
        #pragma unroll
        for (int j = 0; j < 8; ++j) split2(e[j], h[j], l[j]);
        *(short8*)(dstbase + awr)         = (short8){h[0],h[1],h[2],h[3],h[4],h[5],h[6],h[7]};
        *(short8*)(dstbase + PLANE + awr) = (short8){l[0],l[1],l[2],l[3],l[4],l[5],l[6],l[7]};
    };

    f32x4 acc[4][4];
    #pragma unroll
    for (int mi = 0; mi < 4; ++mi)
        #pragma unroll
        for (int ni = 0; ni < 4; ++ni)
            acc[mi][ni] = (f32x4){0.f, 0.f, 0.f, 0.f};

    bf16x8 wcA[8], wcB[8];
    float4 avP[2], avQ[2];

    auto step = [&](int ks, char* cbp, char* nbp,
                    float4 (&avUse)[2], float4 (&avLoad)[2],
                    bf16x8 (&wUse)[8], bf16x8 (&wLoad)[8]) {
        const bool hn  = (ks + 1) < KS;
        const bool hn2 = (ks + 2) < KS;
        if (hn2) loadA(avLoad, ((ks + 2) << 5) + ak0);
        if (hn)  loadW(wLoad, ks + 1);
        if (hn2) prefetchW(wbase + (size_t)(ks + 2) * 16384, lane);   // L2-warm
        bf16x8 ah[4], al[4];
        #pragma unroll
        for (int i = 0; i < 4; ++i) {
            const int ao = ((wrg + i) << 10) | (fkc << 8) | (fr << 4);
            ah[i] = *(const bf16x8*)(cbp + ao);
            al[i] = *(const bf16x8*)(cbp + PLANE + ao);
        }
        #pragma unroll
        for (int mi = 0; mi < 4; ++mi)
            #pragma unroll
            for (int ni = 0; ni < 4; ++ni) {
                acc[mi][ni] = __builtin_amdgcn_mfma_f32_16x16x32_bf16(ah[mi], wUse[ni],     acc[mi][ni], 0, 0, 0);
                acc[mi][ni] = __builtin_amdgcn_mfma_f32_16x16x32_bf16(ah[mi], wUse[4 + ni], acc[mi][ni], 0, 0, 0);
                acc[mi][ni] = __builtin_amdgcn_mfma_f32_16x16x32_bf16(al[mi], wUse[ni],     acc[mi][ni], 0, 0, 0);
            }
        if (hn) cvtStore(nbp, avUse, ((ks + 1) << 5) + ak0);
        soft_barrier();
    };

    {
        float4 av0[2];
        loadA(av0, ak0);
        loadW(wcA, 0);
        loadA(avP, 32 + ak0);
        cvtStore(sm, av0, ak0);
    }
    soft_barrier();

    for (int ks = 0; ks < KS; ks += 2) {
        step(ks,     sm,         sm + BUFSZ, avP, avQ, wcA, wcB);
        step(ks + 1, sm + BUFSZ, sm,         avQ, avP, wcB, wcA);
    }

    // ---- epilogue: bias, store, deterministic partial BN stats ----
    // C/D layout: col = lane&15, row = (lane>>4)*4 + reg
    float bv[4];
    #pragma unroll
    for (int ni = 0; ni < 4; ++ni)
        bv[ni] = bias[(size_t)c * Fout + o0 + wcol + (ni << 4) + fr];

    float p[4] = {}, q[4] = {};
    const int rsub = (lane >> 4) << 2;
    #pragma unroll
    for (int mi = 0; mi < 4; ++mi) {
        #pragma unroll
        for (int j = 0; j < 4; ++j) {
            const int row = b0 + wrow + (mi << 4) + rsub + j;
            float* op = Out + ((size_t)c * BB + row) * Fout + o0 + wcol;
            #pragma unroll
            for (int ni = 0; ni < 4; ++ni) {
                const float v = acc[mi][ni][j] + bv[ni];
                op[(ni << 4) + fr] = v;
                if (WRITE_STATS) { p[ni] += v; q[ni] += v * v; }
            }
        }
    }

    if (WRITE_STATS) {
        #pragma unroll
        for (int ni = 0; ni < 4; ++ni) {
            p[ni] += __shfl_xor(p[ni], 16); p[ni] += __shfl_xor(p[ni], 32);
            q[ni] += __shfl_xor(q[ni], 16); q[ni] += __shfl_xor(q[ni], 32);
        }
        __syncthreads();                    // loop done; reuse sm as scratch
        float* redp = (float*)sm;           // [2][256]
        float* redq = (float*)(sm + 2048);
        if (lane < 16) {
            const int base = wr * 256 + wcol;
            #pragma unroll
            for (int ni = 0; ni < 4; ++ni) {
                redp[base + (ni << 4) + fr] = p[ni];
                redq[base + (ni << 4) + fr] = q[ni];
            }
        }
        __syncthreads();
        if (tid < 256) {
            const float sp = redp[tid] + redp[256 + tid];
            const float sq = redq[tid] + redq[256 + tid];
            const size_t o = ((size_t)c * Fout + o0 + tid) * gridDim.x + btile;
            psumOut[o] = sp;
            psqOut[o]  = sq;
        }
    }
}

__global__ __launch_bounds__(256)
void label_kernel(float* __restrict__ out)
{
    const int i = blockIdx.x * 256 + threadIdx.x;
    out[i] = (float)(i >> 11);   // i / 2048
}

// ---------------------------------------------------------------------------
extern "C" void kernel_launch(void* const* d_in, const int* in_sizes, int n_in,
                              void* d_out, int out_size, void* d_ws, size_t ws_size,
                              hipStream_t stream)
{
    const float* x = (const float*)d_in[0];
    const float* W[5];  const float* bs[5];
    for (int l = 0; l < 5; ++l) { W[l] = (const float*)d_in[1 + 2 * l]; bs[l] = (const float*)d_in[2 + 2 * l]; }
    const float* g[4];  const float* be[4];
    for (int l = 0; l < 4; ++l) { g[l] = (const float*)d_in[11 + 2 * l]; be[l] = (const float*)d_in[12 + 2 * l]; }

    float* out     = (float*)d_out;
    float* gendata = out;                              // [C*BB, 512] — doubles as h1
    float* label   = out + (size_t)CCLS * BB * 512;

    float* ws  = (float*)d_ws;
    float* h2  = ws;                                   // 32MB
    float* h3  = h2 + 8388608;                         // 16MB
    float* h4  = h2;                                   // alias: h2 dead after G3
    float* ps1 = h3 + 4194304;
    float* pq1 = ps1 + 131072;
    float* ps2 = pq1 + 131072;
    float* pq2 = ps2 + 65536;
    float* ps3 = pq2 + 65536;
    float* pq3 = ps3 + 65536;
    float* ps4 = pq3 + 65536;
    float* pq4 = ps4 + 65536;
    char*  pack = (char*)(pq4 + 65536);                // 2560 x 16KB = 40MB

    const char* xpk  = pack;
    const char* wpk1 = pack + (size_t)1024 * 16384;
    const char* wpk2 = pack + (size_t)1280 * 16384;
    const char* wpk3 = pack + (size_t)1792 * 16384;
    const char* wpk4 = pack + (size_t)1920 * 16384;
    const char* wpk5 = pack + (size_t)2048 * 16384;

    const dim3 blk(256);

    PackDesc pd;
    pd.src[0] = x;    pd.src[1] = W[0]; pd.src[2] = W[1];
    pd.src[3] = W[2]; pd.src[4] = W[3]; pd.src[5] = W[4];
    const int nrt[6]   = {16, 4, 2, 1, 2, 4};
    const int ksn[6]   = {4, 4, 16, 8, 4, 8};
    const int kreal[6] = {100, 100, 512, 256, 128, 256};
    const int beg[7]   = {0, 1024, 1280, 1792, 1920, 2048, 2560};
    for (int i = 0; i < 6; ++i) { pd.nrt[i] = nrt[i]; pd.ksn[i] = ksn[i]; pd.kreal[i] = kreal[i]; }
    for (int i = 0; i < 7; ++i) pd.beg[i] = beg[i];
    pack_kernel<<<dim3(2560), blk, 0, stream>>>(pd, pack);

    // G1: x[K=100->128] -> h1(=gendata)[512], stats -> ps1 (nbt=16)
    gemm4w_kernel<128, 128, true, false, true><<<dim3(16, 4, CCLS), blk, 0, stream>>>(
        nullptr, xpk, wpk1, bs[0], nullptr, nullptr, nullptr, nullptr,
        gendata, ps1, pq1, 512, 0);

    // G2: bn1(h1)->relu -> h2[256], stats -> ps2 (nbt=16). 8-wave, OT=1.
    gemm8w_kernel<512, true><<<dim3(16, 1, CCLS), dim3(512), 0, stream>>>(
        gendata, wpk2, bs[1], ps1, pq1, g[0], be[0],
        h2, ps2, pq2, 256, 16);

    // G3: bn2(h2)->relu -> h3[128], stats -> ps3 (BM=64, nbt=32)
    gemm4w_kernel<64, 256, false, true, true><<<dim3(32, 1, CCLS), blk, 0, stream>>>(
        h2, nullptr, wpk3, bs[2], ps2, pq2, g[1], be[1],
        h3, ps3, pq3, 128, 16);

    // G4: bn3(h3)->relu -> h4[256] (aliases h2), stats -> ps4 (nbt=16). 8-wave.
    gemm8w_kernel<128, true><<<dim3(16, 1, CCLS), dim3(512), 0, stream>>>(
        h3, wpk4, bs[3], ps3, pq3, g[2], be[2],
        h4, ps4, pq4, 256, 32);

    // G5: bn4(h4)->relu -> gendata[512] (no stats). 8-wave, OT=2, 512 blocks.
    gemm8w_kernel<256, false><<<dim3(16, 2, CCLS), dim3(512), 0, stream>>>(
        h4, wpk5, bs[4], ps4, pq4, g[3], be[3],
        gendata, nullptr, nullptr, 512, 16);

    label_kernel<<<dim3(CCLS * BB / 256), blk, 0, stream>>>(label);
}

// Round 14
// 148.266 us; speedup vs baseline: 1.6006x; 1.1275x over previous
//
#include <hip/hip_runtime.h>
#include <hip/hip_bf16.h>
#include <math.h>

#define CCLS 16
#define BB   2048

using bf16x8 = __attribute__((ext_vector_type(8))) short;
using short8 = __attribute__((ext_vector_type(8))) short;
using f32x4  = __attribute__((ext_vector_type(4))) float;

// fp32 -> (hi, lo) bf16 split (RNE; hi+lo reproduces ~24 mantissa bits)
__device__ __forceinline__ void split2(float e, short& hi, short& lo) {
    __hip_bfloat16 h = __float2bfloat16(e);
    hi = __builtin_bit_cast(short, h);
    lo = __builtin_bit_cast(short, __float2bfloat16(e - __bfloat162float(h)));
}

// LDS-visibility barrier that does NOT drain vmcnt.
__device__ __forceinline__ void soft_barrier() {
    asm volatile("s_waitcnt lgkmcnt(0)" ::: "memory");
    __builtin_amdgcn_s_barrier();
    asm volatile("" ::: "memory");
}

// global -> LDS direct copy, 16B/lane; lds dest is wave-uniform base
__device__ __forceinline__ void gll16(const void* g, void* l) {
    __builtin_amdgcn_global_load_lds(
        (const __attribute__((address_space(1))) unsigned*)g,
        (__attribute__((address_space(3))) unsigned*)l, 16, 0, 0);
}

// XCD class-clustering remap (perf-only, bijective): XCD k gets classes
// {2k, 2k+1} so its W-panel working set fits the 4MB per-XCD L2.
// Valid when gridDim.z == CCLS and total blocks % 16 == 0.
#define XCD_REMAP(btile, otile, c)                                             \
    int btile, otile, c;                                                       \
    {                                                                          \
        const int bpcls = gridDim.x * gridDim.y;                               \
        const int id = blockIdx.x + gridDim.x * (blockIdx.y + gridDim.y * blockIdx.z); \
        const int j = id >> 3;                                                 \
        c = 2 * (id & 7) + j / bpcls;                                          \
        const int r = j % bpcls;                                               \
        btile = r % gridDim.x;                                                 \
        otile = r / gridDim.x;                                                 \
    }

// Fragment-major layout for a 128-row x 32-k bf16 tile (8 KB/plane):
//   L(row, kchunk) = (row>>4)<<10 | kchunk<<8 | (row&15)<<4   (kchunk = k/8)

// ---------------------------------------------------------------------------
// One-time pack: x and W1..W5 -> [hi 8KB][lo 8KB] fragment-major 128x32 tiles.
// ---------------------------------------------------------------------------
struct PackDesc {
    const float* src[6];
    int nrt[6];
    int ksn[6];
    int kreal[6];
    int beg[7];
};

__global__ __launch_bounds__(256)
void pack_kernel(PackDesc d, char* __restrict__ base)
{
    const int bid = blockIdx.x;
    int s = 0;
    #pragma unroll
    for (int i = 0; i < 5; ++i) s += (bid >= d.beg[i + 1]);
    const int t    = bid - d.beg[s];
    const int ksn  = d.ksn[s], nrt = d.nrt[s], kreal = d.kreal[s];
    const int perc = nrt * ksn;
    const int c  = t / perc;
    const int r  = t - c * perc;
    const int rt = r / ksn;
    const int ks = r - rt * ksn;
    const float* src = d.src[s] + ((size_t)(c * nrt + rt) * 128) * kreal;
    char* dst = base + (size_t)bid * 16384;
    const int tid = threadIdx.x;

    #pragma unroll
    for (int it = 0; it < 2; ++it) {
        const int row = (tid >> 2) + (it << 6);
        const int cc  = tid & 3;
        const int q   = ((row >> 4) << 10) | (cc << 8) | ((row & 15) << 4);
        const int k0  = ks * 32 + cc * 8;
        const float* sp = src + (size_t)row * kreal + k0;
        float e[8];
        if (k0 + 8 <= kreal) {
            float4 v0 = *(const float4*)sp;
            float4 v1 = *(const float4*)(sp + 4);
            e[0]=v0.x; e[1]=v0.y; e[2]=v0.z; e[3]=v0.w;
            e[4]=v1.x; e[5]=v1.y; e[6]=v1.z; e[7]=v1.w;
        } else {
            #pragma unroll
            for (int j = 0; j < 8; ++j) e[j] = (k0 + j < kreal) ? sp[j] : 0.f;
        }
        short hv[8], lv[8];
        #pragma unroll
        for (int j = 0; j < 8; ++j) split2(e[j], hv[j], lv[j]);
        *(short8*)(dst + q)        = (short8){hv[0],hv[1],hv[2],hv[3],hv[4],hv[5],hv[6],hv[7]};
        *(short8*)(dst + 8192 + q) = (short8){lv[0],lv[1],lv[2],lv[3],lv[4],lv[5],lv[6],lv[7]};
    }
}

// ---------------------------------------------------------------------------
// 4-wave kernel (R8/R10 structure, unchanged): PREPACK path for G1,
// reg-staged path for G3.
// ---------------------------------------------------------------------------
template<int BM, int K, bool PREPACK, bool FUSE_BN, bool WRITE_STATS>
__global__ __launch_bounds__(256, 2)
void gemm4w_kernel(const float* __restrict__ A, const char* __restrict__ Apk,
                   const char* __restrict__ Wpk, const float* __restrict__ bias,
                   const float* __restrict__ psumIn, const float* __restrict__ psqIn,
                   const float* __restrict__ gIn, const float* __restrict__ beIn,
                   float* __restrict__ Out,
                   float* __restrict__ psumOut, float* __restrict__ psqOut,
                   const int Fout, const int nbtIn)
{
    constexpr int KS    = (K + 31) / 32;
    constexpr int PLANE = BM * 64;
    constexpr int BUFSZ = PREPACK ? 32768 : 2 * PLANE;
    static_assert(PREPACK || (K % 32 == 0), "");
    static_assert(PREPACK || (KS % 2 == 0) || (KS == 1), "");

    __shared__ __align__(16) char sm[2 * BUFSZ + (FUSE_BN ? 8 * K : 16)];
    float* scs = (float*)(sm + 2 * BUFSZ);
    float* shs = scs + (FUSE_BN ? K : 0);

    const int tid   = threadIdx.x;
    const int btile = blockIdx.x, otile = blockIdx.y, c = blockIdx.z;

    if (FUSE_BN) {
        for (int f = tid; f < K; f += 256) {
            const float* ps = psumIn + ((size_t)c * K + f) * nbtIn;
            const float* pq = psqIn  + ((size_t)c * K + f) * nbtIn;
            float s = 0.f, q = 0.f;
            for (int t = 0; t < nbtIn; t += 4) {
                float4 a4 = *(const float4*)(ps + t);
                float4 b4 = *(const float4*)(pq + t);
                s += (a4.x + a4.y) + (a4.z + a4.w);
                q += (b4.x + b4.y) + (b4.z + b4.w);
            }
            const float mean = s * (1.f / BB);
            const float var  = q * (1.f / BB) - mean * mean;
            const float rstd = rsqrtf(var + 1e-5f);
            const float scv  = gIn[(size_t)c * K + f] * rstd;
            scs[f] = scv;
            shs[f] = fmaf(-mean, scv, beIn[(size_t)c * K + f]);
        }
        __syncthreads();
    }

    const int b0 = btile * BM, o0 = otile * 128;
    const int OT = Fout >> 7;
    const char* wbase = Wpk + (size_t)((c * OT + otile) * KS) * 16384;
    const char* abase = PREPACK ? (Apk + (size_t)((c * gridDim.x + btile) * KS) * 16384) : nullptr;

    const int lane = tid & 63, wv = tid >> 6;
    const int fr = lane & 15, fkc = lane >> 4;
    const int wrow = (BM == 128) ? ((wv >> 1) << 6) : ((wv >> 1) << 5);
    const int wcol = (wv & 1) << 6;
    const int wrg = wrow >> 4, wcg = wcol >> 4;
    constexpr int MI = BM / 32;

    f32x4 acc[MI][4];
    #pragma unroll
    for (int mi = 0; mi < MI; ++mi)
        #pragma unroll
        for (int ni = 0; ni < 4; ++ni)
            acc[mi][ni] = (f32x4){0.f, 0.f, 0.f, 0.f};

    if constexpr (PREPACK) {
        auto stageTile = [&](int nb, int ks) {
            const char* at = abase + (size_t)ks * 16384;
            const char* wt = wbase + (size_t)ks * 16384;
            char* dst = sm + nb;
            #pragma unroll
            for (int i = 0; i < 4; ++i) {
                const int rg = ((wv << 2) + i) << 10;
                gll16(at + rg + (lane << 4), dst + rg);
                gll16(wt + rg + (lane << 4), dst + 16384 + rg);
            }
        };
        stageTile(0, 0);
        __syncthreads();
        for (int ks = 0; ks < KS; ++ks) {
            const int cb = (ks & 1) ? BUFSZ : 0;
            if (ks + 1 < KS) stageTile(cb ^ BUFSZ, ks + 1);
            bf16x8 ah[MI], al[MI], wh[4], wl[4];
            #pragma unroll
            for (int i = 0; i < 4; ++i) {
                const int wo = ((wcg + i) << 10) | (fkc << 8) | (fr << 4);
                wh[i] = *(const bf16x8*)(sm + cb + 16384 + wo);
                wl[i] = *(const bf16x8*)(sm + cb + 24576 + wo);
            }
            #pragma unroll
            for (int i = 0; i < MI; ++i) {
                const int ao = ((wrg + i) << 10) | (fkc << 8) | (fr << 4);
                ah[i] = *(const bf16x8*)(sm + cb + ao);
                al[i] = *(const bf16x8*)(sm + cb + 8192 + ao);
            }
            #pragma unroll
            for (int mi = 0; mi < MI; ++mi)
                #pragma unroll
                for (int ni = 0; ni < 4; ++ni) {
                    acc[mi][ni] = __builtin_amdgcn_mfma_f32_16x16x32_bf16(ah[mi], wh[ni], acc[mi][ni], 0, 0, 0);
                    acc[mi][ni] = __builtin_amdgcn_mfma_f32_16x16x32_bf16(ah[mi], wl[ni], acc[mi][ni], 0, 0, 0);
                    acc[mi][ni] = __builtin_amdgcn_mfma_f32_16x16x32_bf16(al[mi], wh[ni], acc[mi][ni], 0, 0, 0);
                }
            __syncthreads();
        }
    } else {
        constexpr int NV = BM / 32;
        const int arow = (BM == 128) ? (tid >> 1) : (tid >> 2);
        const int asub = (BM == 128) ? (tid & 1)  : (tid & 3);
        const int ak0  = (BM == 128) ? (asub << 4) : (asub << 3);
        const int kch  = (BM == 128) ? (asub << 1) : asub;
        const int awr  = ((arow >> 4) << 10) | (kch << 8) | ((arow & 15) << 4);
        const float* Arow = A + ((size_t)c * BB + b0 + arow) * K;

        auto loadA = [&](float4 (&av)[NV], int gk0) {
            #pragma unroll
            for (int i = 0; i < NV; ++i)
                av[i] = *(const float4*)(Arow + gk0 + (i << 2));
        };
        auto loadW = [&](bf16x8 (&w)[8], int ks) {
            const char* wt = wbase + (size_t)ks * 16384;
            #pragma unroll
            for (int i = 0; i < 4; ++i) {
                const int wo = ((wcg + i) << 10) | (fkc << 8) | (fr << 4);
                w[i]     = *(const bf16x8*)(wt + wo);
                w[4 + i] = *(const bf16x8*)(wt + 8192 + wo);
            }
        };
        auto cvtStore = [&](char* dstbase, const float4 (&a)[NV], int gk0) {
            float e[NV * 4];
            #pragma unroll
            for (int i = 0; i < NV; ++i) {
                e[i*4+0] = a[i].x; e[i*4+1] = a[i].y; e[i*4+2] = a[i].z; e[i*4+3] = a[i].w;
            }
            if constexpr (FUSE_BN) {
                #pragma unroll
                for (int i = 0; i < NV; ++i) {
                    const float4 sc = *(const float4*)(scs + gk0 + (i << 2));
                    const float4 sh = *(const float4*)(shs + gk0 + (i << 2));
                    e[i*4+0] = fmaxf(0.f, fmaf(e[i*4+0], sc.x, sh.x));
                    e[i*4+1] = fmaxf(0.f, fmaf(e[i*4+1], sc.y, sh.y));
                    e[i*4+2] = fmaxf(0.f, fmaf(e[i*4+2], sc.z, sh.z));
                    e[i*4+3] = fmaxf(0.f, fmaf(e[i*4+3], sc.w, sh.w));
                }
            }
            short h[NV*4], l[NV*4];
            #pragma unroll
            for (int j = 0; j < NV*4; ++j) split2(e[j], h[j], l[j]);
            *(short8*)(dstbase + awr)         = (short8){h[0],h[1],h[2],h[3],h[4],h[5],h[6],h[7]};
            *(short8*)(dstbase + PLANE + awr) = (short8){l[0],l[1],l[2],l[3],l[4],l[5],l[6],l[7]};
            if constexpr (NV == 4) {
                *(short8*)(dstbase + awr + 256)         = (short8){h[8],h[9],h[10],h[11],h[12],h[13],h[14],h[15]};
                *(short8*)(dstbase + PLANE + awr + 256) = (short8){l[8],l[9],l[10],l[11],l[12],l[13],l[14],l[15]};
            }
        };

        bf16x8 wcA[8], wcB[8];
        float4 avP[NV], avQ[NV];

        auto step = [&](int ks, char* cbp, char* nbp,
                        float4 (&avUse)[NV], float4 (&avLoad)[NV],
                        bf16x8 (&wUse)[8], bf16x8 (&wLoad)[8]) {
            const bool hn  = (ks + 1) < KS;
            const bool hn2 = (ks + 2) < KS;
            if (hn2) loadA(avLoad, ((ks + 2) << 5) + ak0);
            if (hn)  loadW(wLoad, ks + 1);
            bf16x8 ah[MI], al[MI];
            #pragma unroll
            for (int i = 0; i < MI; ++i) {
                const int ao = ((wrg + i) << 10) | (fkc << 8) | (fr << 4);
                ah[i] = *(const bf16x8*)(cbp + ao);
                al[i] = *(const bf16x8*)(cbp + PLANE + ao);
            }
            #pragma unroll
            for (int mi = 0; mi < MI; ++mi)
                #pragma unroll
                for (int ni = 0; ni < 4; ++ni) {
                    acc[mi][ni] = __builtin_amdgcn_mfma_f32_16x16x32_bf16(ah[mi], wUse[ni],     acc[mi][ni], 0, 0, 0);
                    acc[mi][ni] = __builtin_amdgcn_mfma_f32_16x16x32_bf16(ah[mi], wUse[4 + ni], acc[mi][ni], 0, 0, 0);
                    acc[mi][ni] = __builtin_amdgcn_mfma_f32_16x16x32_bf16(al[mi], wUse[ni],     acc[mi][ni], 0, 0, 0);
                }
            if (hn) cvtStore(nbp, avUse, ((ks + 1) << 5) + ak0);
            soft_barrier();
        };

        {
            float4 av0[NV];
            loadA(av0, ak0);
            loadW(wcA, 0);
            if (KS > 1) loadA(avP, 32 + ak0);
            cvtStore(sm, av0, ak0);
        }
        soft_barrier();

        for (int ks = 0; ks < KS; ks += 2) {
            step(ks,     sm,         sm + BUFSZ, avP, avQ, wcA, wcB);
            step(ks + 1, sm + BUFSZ, sm,         avQ, avP, wcB, wcA);
        }
    }

    // ---- epilogue ----
    float bv[4];
    #pragma unroll
    for (int ni = 0; ni < 4; ++ni)
        bv[ni] = bias[(size_t)c * Fout + o0 + wcol + (ni << 4) + fr];

    float p[4] = {}, q[4] = {};
    const int rsub = (lane >> 4) << 2;
    #pragma unroll
    for (int mi = 0; mi < MI; ++mi) {
        #pragma unroll
        for (int j = 0; j < 4; ++j) {
            const int row = b0 + wrow + (mi << 4) + rsub + j;
            float* op = Out + ((size_t)c * BB + row) * Fout + o0 + wcol;
            #pragma unroll
            for (int ni = 0; ni < 4; ++ni) {
                const float v = acc[mi][ni][j] + bv[ni];
                op[(ni << 4) + fr] = v;
                if (WRITE_STATS) { p[ni] += v; q[ni] += v * v; }
            }
        }
    }

    if (WRITE_STATS) {
        #pragma unroll
        for (int ni = 0; ni < 4; ++ni) {
            p[ni] += __shfl_xor(p[ni], 16); p[ni] += __shfl_xor(p[ni], 32);
            q[ni] += __shfl_xor(q[ni], 16); q[ni] += __shfl_xor(q[ni], 32);
        }
        __syncthreads();
        float* redp = (float*)sm;
        float* redq = (float*)(sm + 1024);
        if (lane < 16) {
            const int base = (wv >> 1) * 128 + wcol;
            #pragma unroll
            for (int ni = 0; ni < 4; ++ni) {
                redp[base + (ni << 4) + fr] = p[ni];
                redq[base + (ni << 4) + fr] = q[ni];
            }
        }
        __syncthreads();
        if (tid < 128) {
            const float sp = redp[tid] + redp[128 + tid];
            const float sq = redq[tid] + redq[128 + tid];
            const size_t o = ((size_t)c * Fout + o0 + tid) * gridDim.x + btile;
            psumOut[o] = sp;
            psqOut[o]  = sq;
        }
    }
}

// ---------------------------------------------------------------------------
// 8-wave (512-thread) 128x256 tile kernel, TWO K-steps per barrier:
// 4 LDS A-buffers (steps mod 4); within a barrier-free group, step ks reads
// buf[ks%4] and produces buf[(ks+2)%4] (disjoint sets -> no WAR). cvt data
// loaded a full group (2 steps) ahead. W reg ping-pong self-restores per
// group. Barriers per tile: KS/2. XCD class-cluster remap for W L2 locality.
// ---------------------------------------------------------------------------
template<int K, bool WRITE_STATS>
__global__ __launch_bounds__(512, 2)
void gemm8w_kernel(const float* __restrict__ A, const char* __restrict__ Wpk,
                   const float* __restrict__ bias,
                   const float* __restrict__ psumIn, const float* __restrict__ psqIn,
                   const float* __restrict__ gIn, const float* __restrict__ beIn,
                   float* __restrict__ Out,
                   float* __restrict__ psumOut, float* __restrict__ psqOut,
                   const int Fout, const int nbtIn)
{
    constexpr int KS    = K / 32;
    constexpr int PLANE = 8192;     // 128x32 bf16 plane
    constexpr int BUFSZ = 16384;    // hi+lo
    static_assert(K % 128 == 0, "need KS % 4 == 0 for the paired schedule");

    __shared__ __align__(16) char sm[4 * BUFSZ + 8 * K];
    float* scs = (float*)(sm + 4 * BUFSZ);
    float* shs = scs + K;

    const int tid = threadIdx.x;
    XCD_REMAP(btile, otile, c)

    // folded combine: BN scale/shift for INPUT features
    for (int f = tid; f < K; f += 512) {
        const float* ps = psumIn + ((size_t)c * K + f) * nbtIn;
        const float* pq = psqIn  + ((size_t)c * K + f) * nbtIn;
        float s = 0.f, q = 0.f;
        for (int t = 0; t < nbtIn; t += 4) {
            float4 a4 = *(const float4*)(ps + t);
            float4 b4 = *(const float4*)(pq + t);
            s += (a4.x + a4.y) + (a4.z + a4.w);
            q += (b4.x + b4.y) + (b4.z + b4.w);
        }
        const float mean = s * (1.f / BB);
        const float var  = q * (1.f / BB) - mean * mean;
        const float rstd = rsqrtf(var + 1e-5f);
        const float scv  = gIn[(size_t)c * K + f] * rstd;
        scs[f] = scv;
        shs[f] = fmaf(-mean, scv, beIn[(size_t)c * K + f]);
    }
    __syncthreads();

    const int b0 = btile * 128, o0 = otile * 256;
    const int OT128 = Fout >> 7;

    // A staging map: 512 threads, 8 floats each (one 16B frag slot)
    const int arow = tid >> 2, asub = tid & 3;
    const int ak0  = asub << 3;
    const int awr  = ((arow >> 4) << 10) | (asub << 8) | ((arow & 15) << 4);
    const float* Arow = A + ((size_t)c * BB + b0 + arow) * K;

    // wave map: 2(M) x 4(N), each wave 64x64
    const int lane = tid & 63, wv = tid >> 6;
    const int wr = wv >> 2, nc = wv & 3;
    const int wrow = wr << 6, wcol = nc << 6;
    const int fr = lane & 15, fkc = lane >> 4;
    const int wrg = wrow >> 4;
    const int wtile = wcol >> 7;            // which packed 128-col tile (0/1)
    const int wcg = (wcol >> 4) & 7;        // 16-col group within that tile
    const char* wbase = Wpk + (size_t)((c * OT128 + otile * 2 + wtile) * KS) * 16384;

    auto loadA = [&](float4 (&av)[2], int gk0) {
        av[0] = *(const float4*)(Arow + gk0);
        av[1] = *(const float4*)(Arow + gk0 + 4);
    };
    auto loadW = [&](bf16x8 (&w)[8], int ks) {
        const char* wt = wbase + (size_t)ks * 16384;
        #pragma unroll
        for (int i = 0; i < 4; ++i) {
            const int wo = ((wcg + i) << 10) | (fkc << 8) | (fr << 4);
            w[i]     = *(const bf16x8*)(wt + wo);
            w[4 + i] = *(const bf16x8*)(wt + 8192 + wo);
        }
    };
    auto cvtStore = [&](char* dstbase, const float4 (&a)[2], int gk0) {
        float e[8] = {a[0].x, a[0].y, a[0].z, a[0].w, a[1].x, a[1].y, a[1].z, a[1].w};
        const float4 sc0 = *(const float4*)(scs + gk0);
        const float4 sc1 = *(const float4*)(scs + gk0 + 4);
        const float4 sh0 = *(const float4*)(shs + gk0);
        const float4 sh1 = *(const float4*)(shs + gk0 + 4);
        e[0] = fmaxf(0.f, fmaf(e[0], sc0.x, sh0.x));
        e[1] = fmaxf(0.f, fmaf(e[1], sc0.y, sh0.y));
        e[2] = fmaxf(0.f, fmaf(e[2], sc0.z, sh0.z));
        e[3] = fmaxf(0.f, fmaf(e[3], sc0.w, sh0.w));
        e[4] = fmaxf(0.f, fmaf(e[4], sc1.x, sh1.x));
        e[5] = fmaxf(0.f, fmaf(e[5], sc1.y, sh1.y));
        e[6] = fmaxf(0.f, fmaf(e[6], sc1.z, sh1.z));
        e[7] = fmaxf(0.f, fmaf(e[7], sc1.w, sh1.w));
        short h[8], l[8];
        #pragma unroll
        for (int j = 0; j < 8; ++j) split2(e[j], h[j], l[j]);
        *(short8*)(dstbase + awr)         = (short8){h[0],h[1],h[2],h[3],h[4],h[5],h[6],h[7]};
        *(short8*)(dstbase + PLANE + awr) = (short8){l[0],l[1],l[2],l[3],l[4],l[5],l[6],l[7]};
    };

    f32x4 acc[4][4];
    #pragma unroll
    for (int mi = 0; mi < 4; ++mi)
        #pragma unroll
        for (int ni = 0; ni < 4; ++ni)
            acc[mi][ni] = (f32x4){0.f, 0.f, 0.f, 0.f};

    bf16x8 wc[8], wn[8];
    float4 avA[2], avB[2], avC[2], avD[2];  // A(2t+2), A(2t+3), A(2t+4), A(2t+5)

    auto mfmaStep = [&](char* cbp, bf16x8 (&wUse)[8]) {
        bf16x8 ah[4], al[4];
        #pragma unroll
        for (int i = 0; i < 4; ++i) {
            const int ao = ((wrg + i) << 10) | (fkc << 8) | (fr << 4);
            ah[i] = *(const bf16x8*)(cbp + ao);
            al[i] = *(const bf16x8*)(cbp + PLANE + ao);
        }
        #pragma unroll
        for (int mi = 0; mi < 4; ++mi)
            #pragma unroll
            for (int ni = 0; ni < 4; ++ni) {
                acc[mi][ni] = __builtin_amdgcn_mfma_f32_16x16x32_bf16(ah[mi], wUse[ni],     acc[mi][ni], 0, 0, 0);
                acc[mi][ni] = __builtin_amdgcn_mfma_f32_16x16x32_bf16(ah[mi], wUse[4 + ni], acc[mi][ni], 0, 0, 0);
                acc[mi][ni] = __builtin_amdgcn_mfma_f32_16x16x32_bf16(al[mi], wUse[ni],     acc[mi][ni], 0, 0, 0);
            }
    };

    // group of 2 K-steps, ONE barrier. Reads buf ks%4, ks+1%4 (ready since
    // last barrier); writes buf ks+2%4, ks+3%4 (consumed after this barrier).
    auto group = [&](int ks, char* bR0, char* bR1, char* bW0, char* bW1,
                     float4 (&aU0)[2], float4 (&aU1)[2],
                     float4 (&aL0)[2], float4 (&aL1)[2]) {
        // step ks (consumes wc)
        if (ks + 4 < KS) loadA(aL0, ((ks + 4) << 5) + ak0);
        if (ks + 1 < KS) loadW(wn, ks + 1);
        mfmaStep(bR0, wc);
        if (ks + 2 < KS) cvtStore(bW0, aU0, ((ks + 2) << 5) + ak0);
        // step ks+1 (consumes wn)
        if (ks + 5 < KS) loadA(aL1, ((ks + 5) << 5) + ak0);
        if (ks + 2 < KS) loadW(wc, ks + 2);
        mfmaStep(bR1, wn);
        if (ks + 3 < KS) cvtStore(bW1, aU1, ((ks + 3) << 5) + ak0);
        soft_barrier();
    };

    // prologue: A(0),A(1) -> bufs 0,1; A(2),A(3) -> regs; W(0) -> wc
    {
        float4 a0[2], a1[2];
        loadA(a0, ak0);
        loadA(a1, 32 + ak0);
        loadW(wc, 0);
        loadA(avA, 64 + ak0);        // A(2)  (KS >= 4 guaranteed)
        loadA(avB, 96 + ak0);        // A(3)
        cvtStore(sm,         a0, ak0);
        cvtStore(sm + BUFSZ, a1, 32 + ak0);
    }
    soft_barrier();

    for (int ks = 0; ks < KS; ks += 4) {
        group(ks,     sm,             sm + BUFSZ,     sm + 2 * BUFSZ, sm + 3 * BUFSZ,
              avA, avB, avC, avD);
        group(ks + 2, sm + 2 * BUFSZ, sm + 3 * BUFSZ, sm,             sm + BUFSZ,
              avC, avD, avA, avB);
    }

    // ---- epilogue: bias, store, deterministic partial BN stats ----
    // C/D layout: col = lane&15, row = (lane>>4)*4 + reg
    float bv[4];
    #pragma unroll
    for (int ni = 0; ni < 4; ++ni)
        bv[ni] = bias[(size_t)c * Fout + o0 + wcol + (ni << 4) + fr];

    float p[4] = {}, q[4] = {};
    const int rsub = (lane >> 4) << 2;
    #pragma unroll
    for (int mi = 0; mi < 4; ++mi) {
        #pragma unroll
        for (int j = 0; j < 4; ++j) {
            const int row = b0 + wrow + (mi << 4) + rsub + j;
            float* op = Out + ((size_t)c * BB + row) * Fout + o0 + wcol;
            #pragma unroll
            for (int ni = 0; ni < 4; ++ni) {
                const float v = acc[mi][ni][j] + bv[ni];
                op[(ni << 4) + fr] = v;
                if (WRITE_STATS) { p[ni] += v; q[ni] += v * v; }
            }
        }
    }

    if (WRITE_STATS) {
        #pragma unroll
        for (int ni = 0; ni < 4; ++ni) {
            p[ni] += __shfl_xor(p[ni], 16); p[ni] += __shfl_xor(p[ni], 32);
            q[ni] += __shfl_xor(q[ni], 16); q[ni] += __shfl_xor(q[ni], 32);
        }
        __syncthreads();                    // loop done; reuse sm as scratch
        float* redp = (float*)sm;           // [2][256]
        float* redq = (float*)(sm + 2048);
        if (lane < 16) {
            const int base = wr * 256 + wcol;
            #pragma unroll
            for (int ni = 0; ni < 4; ++ni) {
                redp[base + (ni << 4) + fr] = p[ni];
                redq[base + (ni << 4) + fr] = q[ni];
            }
        }
        __syncthreads();
        if (tid < 256) {
            const float sp = redp[tid] + redp[256 + tid];
            const float sq = redq[tid] + redq[256 + tid];
            const size_t o = ((size_t)c * Fout + o0 + tid) * gridDim.x + btile;
            psumOut[o] = sp;
            psqOut[o]  = sq;
        }
    }
}

__global__ __launch_bounds__(256)
void label_kernel(float* __restrict__ out)
{
    const int i = blockIdx.x * 256 + threadIdx.x;
    out[i] = (float)(i >> 11);   // i / 2048
}

// ---------------------------------------------------------------------------
extern "C" void kernel_launch(void* const* d_in, const int* in_sizes, int n_in,
                              void* d_out, int out_size, void* d_ws, size_t ws_size,
                              hipStream_t stream)
{
    const float* x = (const float*)d_in[0];
    const float* W[5];  const float* bs[5];
    for (int l = 0; l < 5; ++l) { W[l] = (const float*)d_in[1 + 2 * l]; bs[l] = (const float*)d_in[2 + 2 * l]; }
    const float* g[4];  const float* be[4];
    for (int l = 0; l < 4; ++l) { g[l] = (const float*)d_in[11 + 2 * l]; be[l] = (const float*)d_in[12 + 2 * l]; }

    float* out     = (float*)d_out;
    float* gendata = out;                              // [C*BB, 512] — doubles as h1
    float* label   = out + (size_t)CCLS * BB * 512;

    float* ws  = (float*)d_ws;
    float* h2  = ws;                                   // 32MB
    float* h3  = h2 + 8388608;                         // 16MB
    float* h4  = h2;                                   // alias: h2 dead after G3
    float* ps1 = h3 + 4194304;
    float* pq1 = ps1 + 131072;
    float* ps2 = pq1 + 131072;
    float* pq2 = ps2 + 65536;
    float* ps3 = pq2 + 65536;
    float* pq3 = ps3 + 65536;
    float* ps4 = pq3 + 65536;
    float* pq4 = ps4 + 65536;
    char*  pack = (char*)(pq4 + 65536);                // 2560 x 16KB = 40MB

    const char* xpk  = pack;
    const char* wpk1 = pack + (size_t)1024 * 16384;
    const char* wpk2 = pack + (size_t)1280 * 16384;
    const char* wpk3 = pack + (size_t)1792 * 16384;
    const char* wpk4 = pack + (size_t)1920 * 16384;
    const char* wpk5 = pack + (size_t)2048 * 16384;

    const dim3 blk(256);

    PackDesc pd;
    pd.src[0] = x;    pd.src[1] = W[0]; pd.src[2] = W[1];
    pd.src[3] = W[2]; pd.src[4] = W[3]; pd.src[5] = W[4];
    const int nrt[6]   = {16, 4, 2, 1, 2, 4};
    const int ksn[6]   = {4, 4, 16, 8, 4, 8};
    const int kreal[6] = {100, 100, 512, 256, 128, 256};
    const int beg[7]   = {0, 1024, 1280, 1792, 1920, 2048, 2560};
    for (int i = 0; i < 6; ++i) { pd.nrt[i] = nrt[i]; pd.ksn[i] = ksn[i]; pd.kreal[i] = kreal[i]; }
    for (int i = 0; i < 7; ++i) pd.beg[i] = beg[i];
    pack_kernel<<<dim3(2560), blk, 0, stream>>>(pd, pack);

    // G1: x[K=100->128] -> h1(=gendata)[512], stats -> ps1 (nbt=16)
    gemm4w_kernel<128, 128, true, false, true><<<dim3(16, 4, CCLS), blk, 0, stream>>>(
        nullptr, xpk, wpk1, bs[0], nullptr, nullptr, nullptr, nullptr,
        gendata, ps1, pq1, 512, 0);

    // G2: bn1(h1)->relu -> h2[256], stats -> ps2 (nbt=16). 8-wave paired.
    gemm8w_kernel<512, true><<<dim3(16, 1, CCLS), dim3(512), 0, stream>>>(
        gendata, wpk2, bs[1], ps1, pq1, g[0], be[0],
        h2, ps2, pq2, 256, 16);

    // G3: bn2(h2)->relu -> h3[128], stats -> ps3 (BM=64, nbt=32)
    gemm4w_kernel<64, 256, false, true, true><<<dim3(32, 1, CCLS), blk, 0, stream>>>(
        h2, nullptr, wpk3, bs[2], ps2, pq2, g[1], be[1],
        h3, ps3, pq3, 128, 16);

    // G4: bn3(h3)->relu -> h4[256] (aliases h2), stats -> ps4 (nbt=16). Paired.
    gemm8w_kernel<128, true><<<dim3(16, 1, CCLS), dim3(512), 0, stream>>>(
        h3, wpk4, bs[3], ps3, pq3, g[2], be[2],
        h4, ps4, pq4, 256, 32);

    // G5: bn4(h4)->relu -> gendata[512] (no stats). Paired, 512 blocks.
    gemm8w_kernel<256, false><<<dim3(16, 2, CCLS), dim3(512), 0, stream>>>(
        h4, wpk5, bs[4], ps4, pq4, g[3], be[3],
        gendata, nullptr, nullptr, 512, 16);

    label_kernel<<<dim3(CCLS * BB / 256), blk, 0, stream>>>(label);
}

// Round 15
// 142.316 us; speedup vs baseline: 1.6675x; 1.0418x over previous
//
#include <hip/hip_runtime.h>
#include <hip/hip_bf16.h>
#include <math.h>

#define CCLS 16
#define BB   2048

using bf16x8 = __attribute__((ext_vector_type(8))) short;
using short8 = __attribute__((ext_vector_type(8))) short;
using f32x4  = __attribute__((ext_vector_type(4))) float;

// fp32 -> (hi, lo) bf16 split (RNE; hi+lo reproduces ~24 mantissa bits)
__device__ __forceinline__ void split2(float e, short& hi, short& lo) {
    __hip_bfloat16 h = __float2bfloat16(e);
    hi = __builtin_bit_cast(short, h);
    lo = __builtin_bit_cast(short, __float2bfloat16(e - __bfloat162float(h)));
}
__device__ __forceinline__ short f2b(float e) {
    return __builtin_bit_cast(short, __float2bfloat16(e));
}

// LDS-visibility barrier that does NOT drain vmcnt.
__device__ __forceinline__ void soft_barrier() {
    asm volatile("s_waitcnt lgkmcnt(0)" ::: "memory");
    __builtin_amdgcn_s_barrier();
    asm volatile("" ::: "memory");
}

// global -> LDS direct copy, 16B/lane; lds dest is wave-uniform base
__device__ __forceinline__ void gll16(const void* g, void* l) {
    __builtin_amdgcn_global_load_lds(
        (const __attribute__((address_space(1))) unsigned*)g,
        (__attribute__((address_space(3))) unsigned*)l, 16, 0, 0);
}

// XCD class-clustering remap (perf-only, bijective): XCD k gets classes
// {2k, 2k+1} so its W-panel working set fits the 4MB per-XCD L2.
#define XCD_REMAP(btile, otile, c)                                             \
    int btile, otile, c;                                                       \
    {                                                                          \
        const int bpcls = gridDim.x * gridDim.y;                               \
        const int id = blockIdx.x + gridDim.x * (blockIdx.y + gridDim.y * blockIdx.z); \
        const int j = id >> 3;                                                 \
        c = 2 * (id & 7) + j / bpcls;                                          \
        const int r = j % bpcls;                                               \
        btile = r % gridDim.x;                                                 \
        otile = r / gridDim.x;                                                 \
    }

// Fragment-major layout for a 128-row x 32-k bf16 tile (8 KB/plane):
//   L(row, kchunk) = (row>>4)<<10 | kchunk<<8 | (row&15)<<4   (kchunk = k/8)

// ---------------------------------------------------------------------------
// One-time pack: x and W1..W5 -> [hi 8KB][lo 8KB] fragment-major 128x32 tiles.
// ---------------------------------------------------------------------------
struct PackDesc {
    const float* src[6];
    int nrt[6];
    int ksn[6];
    int kreal[6];
    int beg[7];
};

__global__ __launch_bounds__(256)
void pack_kernel(PackDesc d, char* __restrict__ base)
{
    const int bid = blockIdx.x;
    int s = 0;
    #pragma unroll
    for (int i = 0; i < 5; ++i) s += (bid >= d.beg[i + 1]);
    const int t    = bid - d.beg[s];
    const int ksn  = d.ksn[s], nrt = d.nrt[s], kreal = d.kreal[s];
    const int perc = nrt * ksn;
    const int c  = t / perc;
    const int r  = t - c * perc;
    const int rt = r / ksn;
    const int ks = r - rt * ksn;
    const float* src = d.src[s] + ((size_t)(c * nrt + rt) * 128) * kreal;
    char* dst = base + (size_t)bid * 16384;
    const int tid = threadIdx.x;

    #pragma unroll
    for (int it = 0; it < 2; ++it) {
        const int row = (tid >> 2) + (it << 6);
        const int cc  = tid & 3;
        const int q   = ((row >> 4) << 10) | (cc << 8) | ((row & 15) << 4);
        const int k0  = ks * 32 + cc * 8;
        const float* sp = src + (size_t)row * kreal + k0;
        float e[8];
        if (k0 + 8 <= kreal) {
            float4 v0 = *(const float4*)sp;
            float4 v1 = *(const float4*)(sp + 4);
            e[0]=v0.x; e[1]=v0.y; e[2]=v0.z; e[3]=v0.w;
            e[4]=v1.x; e[5]=v1.y; e[6]=v1.z; e[7]=v1.w;
        } else {
            #pragma unroll
            for (int j = 0; j < 8; ++j) e[j] = (k0 + j < kreal) ? sp[j] : 0.f;
        }
        short hv[8], lv[8];
        #pragma unroll
        for (int j = 0; j < 8; ++j) split2(e[j], hv[j], lv[j]);
        *(short8*)(dst + q)        = (short8){hv[0],hv[1],hv[2],hv[3],hv[4],hv[5],hv[6],hv[7]};
        *(short8*)(dst + 8192 + q) = (short8){lv[0],lv[1],lv[2],lv[3],lv[4],lv[5],lv[6],lv[7]};
    }
}

// ---------------------------------------------------------------------------
// 4-wave kernel: PREPACK path for G1 (3-product, packed A), reg-staged path
// for G3. AHL=false: A stored as SINGLE bf16 plane (no lo) -> 2-product
// d = a_bf*(wh+wl); error ~2^-9 relative, re-normalized by the next BN.
// ---------------------------------------------------------------------------
template<int BM, int K, bool PREPACK, bool AHL, bool FUSE_BN, bool WRITE_STATS>
__global__ __launch_bounds__(256, 2)
void gemm4w_kernel(const float* __restrict__ A, const char* __restrict__ Apk,
                   const char* __restrict__ Wpk, const float* __restrict__ bias,
                   const float* __restrict__ psumIn, const float* __restrict__ psqIn,
                   const float* __restrict__ gIn, const float* __restrict__ beIn,
                   float* __restrict__ Out,
                   float* __restrict__ psumOut, float* __restrict__ psqOut,
                   const int Fout, const int nbtIn)
{
    constexpr int KS    = (K + 31) / 32;
    constexpr int PLANE = BM * 64;
    constexpr int BUFSZ = PREPACK ? 32768 : (AHL ? 2 * PLANE : PLANE);
    static_assert(PREPACK || (K % 32 == 0), "");
    static_assert(PREPACK || (KS % 2 == 0) || (KS == 1), "");

    __shared__ __align__(16) char sm[2 * BUFSZ + (FUSE_BN ? 8 * K : 16)];
    float* scs = (float*)(sm + 2 * BUFSZ);
    float* shs = scs + (FUSE_BN ? K : 0);

    const int tid   = threadIdx.x;
    const int btile = blockIdx.x, otile = blockIdx.y, c = blockIdx.z;

    if (FUSE_BN) {
        for (int f = tid; f < K; f += 256) {
            const float* ps = psumIn + ((size_t)c * K + f) * nbtIn;
            const float* pq = psqIn  + ((size_t)c * K + f) * nbtIn;
            float s = 0.f, q = 0.f;
            for (int t = 0; t < nbtIn; t += 4) {
                float4 a4 = *(const float4*)(ps + t);
                float4 b4 = *(const float4*)(pq + t);
                s += (a4.x + a4.y) + (a4.z + a4.w);
                q += (b4.x + b4.y) + (b4.z + b4.w);
            }
            const float mean = s * (1.f / BB);
            const float var  = q * (1.f / BB) - mean * mean;
            const float rstd = rsqrtf(var + 1e-5f);
            const float scv  = gIn[(size_t)c * K + f] * rstd;
            scs[f] = scv;
            shs[f] = fmaf(-mean, scv, beIn[(size_t)c * K + f]);
        }
        __syncthreads();
    }

    const int b0 = btile * BM, o0 = otile * 128;
    const int OT = Fout >> 7;
    const char* wbase = Wpk + (size_t)((c * OT + otile) * KS) * 16384;
    const char* abase = PREPACK ? (Apk + (size_t)((c * gridDim.x + btile) * KS) * 16384) : nullptr;

    const int lane = tid & 63, wv = tid >> 6;
    const int fr = lane & 15, fkc = lane >> 4;
    const int wrow = (BM == 128) ? ((wv >> 1) << 6) : ((wv >> 1) << 5);
    const int wcol = (wv & 1) << 6;
    const int wrg = wrow >> 4, wcg = wcol >> 4;
    constexpr int MI = BM / 32;

    f32x4 acc[MI][4];
    #pragma unroll
    for (int mi = 0; mi < MI; ++mi)
        #pragma unroll
        for (int ni = 0; ni < 4; ++ni)
            acc[mi][ni] = (f32x4){0.f, 0.f, 0.f, 0.f};

    if constexpr (PREPACK) {
        auto stageTile = [&](int nb, int ks) {
            const char* at = abase + (size_t)ks * 16384;
            const char* wt = wbase + (size_t)ks * 16384;
            char* dst = sm + nb;
            #pragma unroll
            for (int i = 0; i < 4; ++i) {
                const int rg = ((wv << 2) + i) << 10;
                gll16(at + rg + (lane << 4), dst + rg);
                gll16(wt + rg + (lane << 4), dst + 16384 + rg);
            }
        };
        stageTile(0, 0);
        __syncthreads();
        for (int ks = 0; ks < KS; ++ks) {
            const int cb = (ks & 1) ? BUFSZ : 0;
            if (ks + 1 < KS) stageTile(cb ^ BUFSZ, ks + 1);
            bf16x8 ah[MI], al[MI], wh[4], wl[4];
            #pragma unroll
            for (int i = 0; i < 4; ++i) {
                const int wo = ((wcg + i) << 10) | (fkc << 8) | (fr << 4);
                wh[i] = *(const bf16x8*)(sm + cb + 16384 + wo);
                wl[i] = *(const bf16x8*)(sm + cb + 24576 + wo);
            }
            #pragma unroll
            for (int i = 0; i < MI; ++i) {
                const int ao = ((wrg + i) << 10) | (fkc << 8) | (fr << 4);
                ah[i] = *(const bf16x8*)(sm + cb + ao);
                al[i] = *(const bf16x8*)(sm + cb + 8192 + ao);
            }
            #pragma unroll
            for (int mi = 0; mi < MI; ++mi)
                #pragma unroll
                for (int ni = 0; ni < 4; ++ni) {
                    acc[mi][ni] = __builtin_amdgcn_mfma_f32_16x16x32_bf16(ah[mi], wh[ni], acc[mi][ni], 0, 0, 0);
                    acc[mi][ni] = __builtin_amdgcn_mfma_f32_16x16x32_bf16(ah[mi], wl[ni], acc[mi][ni], 0, 0, 0);
                    acc[mi][ni] = __builtin_amdgcn_mfma_f32_16x16x32_bf16(al[mi], wh[ni], acc[mi][ni], 0, 0, 0);
                }
            __syncthreads();
        }
    } else {
        constexpr int NV = BM / 32;
        const int arow = (BM == 128) ? (tid >> 1) : (tid >> 2);
        const int asub = (BM == 128) ? (tid & 1)  : (tid & 3);
        const int ak0  = (BM == 128) ? (asub << 4) : (asub << 3);
        const int kch  = (BM == 128) ? (asub << 1) : asub;
        const int awr  = ((arow >> 4) << 10) | (kch << 8) | ((arow & 15) << 4);
        const float* Arow = A + ((size_t)c * BB + b0 + arow) * K;

        auto loadA = [&](float4 (&av)[NV], int gk0) {
            #pragma unroll
            for (int i = 0; i < NV; ++i)
                av[i] = *(const float4*)(Arow + gk0 + (i << 2));
        };
        auto loadW = [&](bf16x8 (&w)[8], int ks) {
            const char* wt = wbase + (size_t)ks * 16384;
            #pragma unroll
            for (int i = 0; i < 4; ++i) {
                const int wo = ((wcg + i) << 10) | (fkc << 8) | (fr << 4);
                w[i]     = *(const bf16x8*)(wt + wo);
                w[4 + i] = *(const bf16x8*)(wt + 8192 + wo);
            }
        };
        auto cvtStore = [&](char* dstbase, const float4 (&a)[NV], int gk0) {
            float e[NV * 4];
            #pragma unroll
            for (int i = 0; i < NV; ++i) {
                e[i*4+0] = a[i].x; e[i*4+1] = a[i].y; e[i*4+2] = a[i].z; e[i*4+3] = a[i].w;
            }
            if constexpr (FUSE_BN) {
                #pragma unroll
                for (int i = 0; i < NV; ++i) {
                    const float4 sc = *(const float4*)(scs + gk0 + (i << 2));
                    const float4 sh = *(const float4*)(shs + gk0 + (i << 2));
                    e[i*4+0] = fmaxf(0.f, fmaf(e[i*4+0], sc.x, sh.x));
                    e[i*4+1] = fmaxf(0.f, fmaf(e[i*4+1], sc.y, sh.y));
                    e[i*4+2] = fmaxf(0.f, fmaf(e[i*4+2], sc.z, sh.z));
                    e[i*4+3] = fmaxf(0.f, fmaf(e[i*4+3], sc.w, sh.w));
                }
            }
            if constexpr (AHL) {
                short h[NV*4], l[NV*4];
                #pragma unroll
                for (int j = 0; j < NV*4; ++j) split2(e[j], h[j], l[j]);
                *(short8*)(dstbase + awr)         = (short8){h[0],h[1],h[2],h[3],h[4],h[5],h[6],h[7]};
                *(short8*)(dstbase + PLANE + awr) = (short8){l[0],l[1],l[2],l[3],l[4],l[5],l[6],l[7]};
                if constexpr (NV == 4) {
                    *(short8*)(dstbase + awr + 256)         = (short8){h[8],h[9],h[10],h[11],h[12],h[13],h[14],h[15]};
                    *(short8*)(dstbase + PLANE + awr + 256) = (short8){l[8],l[9],l[10],l[11],l[12],l[13],l[14],l[15]};
                }
            } else {
                short h[NV*4];
                #pragma unroll
                for (int j = 0; j < NV*4; ++j) h[j] = f2b(e[j]);
                *(short8*)(dstbase + awr) = (short8){h[0],h[1],h[2],h[3],h[4],h[5],h[6],h[7]};
                if constexpr (NV == 4)
                    *(short8*)(dstbase + awr + 256) = (short8){h[8],h[9],h[10],h[11],h[12],h[13],h[14],h[15]};
            }
        };

        bf16x8 wcA[8], wcB[8];
        float4 avP[NV], avQ[NV];

        auto step = [&](int ks, char* cbp, char* nbp,
                        float4 (&avUse)[NV], float4 (&avLoad)[NV],
                        bf16x8 (&wUse)[8], bf16x8 (&wLoad)[8]) {
            const bool hn  = (ks + 1) < KS;
            const bool hn2 = (ks + 2) < KS;
            if (hn2) loadA(avLoad, ((ks + 2) << 5) + ak0);
            if (hn)  loadW(wLoad, ks + 1);
            bf16x8 ah[MI], al[MI];
            #pragma unroll
            for (int i = 0; i < MI; ++i) {
                const int ao = ((wrg + i) << 10) | (fkc << 8) | (fr << 4);
                ah[i] = *(const bf16x8*)(cbp + ao);
                if constexpr (AHL) al[i] = *(const bf16x8*)(cbp + PLANE + ao);
            }
            #pragma unroll
            for (int mi = 0; mi < MI; ++mi)
                #pragma unroll
                for (int ni = 0; ni < 4; ++ni) {
                    acc[mi][ni] = __builtin_amdgcn_mfma_f32_16x16x32_bf16(ah[mi], wUse[ni],     acc[mi][ni], 0, 0, 0);
                    acc[mi][ni] = __builtin_amdgcn_mfma_f32_16x16x32_bf16(ah[mi], wUse[4 + ni], acc[mi][ni], 0, 0, 0);
                    if constexpr (AHL)
                        acc[mi][ni] = __builtin_amdgcn_mfma_f32_16x16x32_bf16(al[mi], wUse[ni], acc[mi][ni], 0, 0, 0);
                }
            if (hn) cvtStore(nbp, avUse, ((ks + 1) << 5) + ak0);
            soft_barrier();
        };

        {
            float4 av0[NV];
            loadA(av0, ak0);
            loadW(wcA, 0);
            if (KS > 1) loadA(avP, 32 + ak0);
            cvtStore(sm, av0, ak0);
        }
        soft_barrier();

        for (int ks = 0; ks < KS; ks += 2) {
            step(ks,     sm,         sm + BUFSZ, avP, avQ, wcA, wcB);
            step(ks + 1, sm + BUFSZ, sm,         avQ, avP, wcB, wcA);
        }
    }

    // ---- epilogue ----
    float bv[4];
    #pragma unroll
    for (int ni = 0; ni < 4; ++ni)
        bv[ni] = bias[(size_t)c * Fout + o0 + wcol + (ni << 4) + fr];

    float p[4] = {}, q[4] = {};
    const int rsub = (lane >> 4) << 2;
    #pragma unroll
    for (int mi = 0; mi < MI; ++mi) {
        #pragma unroll
        for (int j = 0; j < 4; ++j) {
            const int row = b0 + wrow + (mi << 4) + rsub + j;
            float* op = Out + ((size_t)c * BB + row) * Fout + o0 + wcol;
            #pragma unroll
            for (int ni = 0; ni < 4; ++ni) {
                const float v = acc[mi][ni][j] + bv[ni];
                op[(ni << 4) + fr] = v;
                if (WRITE_STATS) { p[ni] += v; q[ni] += v * v; }
            }
        }
    }

    if (WRITE_STATS) {
        #pragma unroll
        for (int ni = 0; ni < 4; ++ni) {
            p[ni] += __shfl_xor(p[ni], 16); p[ni] += __shfl_xor(p[ni], 32);
            q[ni] += __shfl_xor(q[ni], 16); q[ni] += __shfl_xor(q[ni], 32);
        }
        __syncthreads();
        float* redp = (float*)sm;
        float* redq = (float*)(sm + 1024);
        if (lane < 16) {
            const int base = (wv >> 1) * 128 + wcol;
            #pragma unroll
            for (int ni = 0; ni < 4; ++ni) {
                redp[base + (ni << 4) + fr] = p[ni];
                redq[base + (ni << 4) + fr] = q[ni];
            }
        }
        __syncthreads();
        if (tid < 128) {
            const float sp = redp[tid] + redp[128 + tid];
            const float sq = redq[tid] + redq[128 + tid];
            const size_t o = ((size_t)c * Fout + o0 + tid) * gridDim.x + btile;
            psumOut[o] = sp;
            psqOut[o]  = sq;
        }
    }
}

// ---------------------------------------------------------------------------
// 8-wave (512-thread) 128x256 tile kernel, TWO K-steps per barrier (4 LDS
// A-buffers, steps mod 4). AHL=false: single-plane A (2-product); true: full
// hi/lo (3-product). XCD class-cluster remap for W L2 locality.
// ---------------------------------------------------------------------------
template<int K, bool AHL, bool WRITE_STATS>
__global__ __launch_bounds__(512, 2)
void gemm8w_kernel(const float* __restrict__ A, const char* __restrict__ Wpk,
                   const float* __restrict__ bias,
                   const float* __restrict__ psumIn, const float* __restrict__ psqIn,
                   const float* __restrict__ gIn, const float* __restrict__ beIn,
                   float* __restrict__ Out,
                   float* __restrict__ psumOut, float* __restrict__ psqOut,
                   const int Fout, const int nbtIn)
{
    constexpr int KS    = K / 32;
    constexpr int PLANE = 8192;                      // 128x32 bf16 plane
    constexpr int BUFSZ = AHL ? 16384 : 8192;        // per-step A buffer
    static_assert(K % 128 == 0, "need KS % 4 == 0 for the paired schedule");

    __shared__ __align__(16) char sm[4 * BUFSZ + 8 * K];
    float* scs = (float*)(sm + 4 * BUFSZ);
    float* shs = scs + K;

    const int tid = threadIdx.x;
    XCD_REMAP(btile, otile, c)

    // folded combine: BN scale/shift for INPUT features
    for (int f = tid; f < K; f += 512) {
        const float* ps = psumIn + ((size_t)c * K + f) * nbtIn;
        const float* pq = psqIn  + ((size_t)c * K + f) * nbtIn;
        float s = 0.f, q = 0.f;
        for (int t = 0; t < nbtIn; t += 4) {
            float4 a4 = *(const float4*)(ps + t);
            float4 b4 = *(const float4*)(pq + t);
            s += (a4.x + a4.y) + (a4.z + a4.w);
            q += (b4.x + b4.y) + (b4.z + b4.w);
        }
        const float mean = s * (1.f / BB);
        const float var  = q * (1.f / BB) - mean * mean;
        const float rstd = rsqrtf(var + 1e-5f);
        const float scv  = gIn[(size_t)c * K + f] * rstd;
        scs[f] = scv;
        shs[f] = fmaf(-mean, scv, beIn[(size_t)c * K + f]);
    }
    __syncthreads();

    const int b0 = btile * 128, o0 = otile * 256;
    const int OT128 = Fout >> 7;

    // A staging map: 512 threads, 8 floats each (one 16B frag slot)
    const int arow = tid >> 2, asub = tid & 3;
    const int ak0  = asub << 3;
    const int awr  = ((arow >> 4) << 10) | (asub << 8) | ((arow & 15) << 4);
    const float* Arow = A + ((size_t)c * BB + b0 + arow) * K;

    // wave map: 2(M) x 4(N), each wave 64x64
    const int lane = tid & 63, wv = tid >> 6;
    const int wr = wv >> 2, nc = wv & 3;
    const int wrow = wr << 6, wcol = nc << 6;
    const int fr = lane & 15, fkc = lane >> 4;
    const int wrg = wrow >> 4;
    const int wtile = wcol >> 7;
    const int wcg = (wcol >> 4) & 7;
    const char* wbase = Wpk + (size_t)((c * OT128 + otile * 2 + wtile) * KS) * 16384;

    auto loadA = [&](float4 (&av)[2], int gk0) {
        av[0] = *(const float4*)(Arow + gk0);
        av[1] = *(const float4*)(Arow + gk0 + 4);
    };
    auto loadW = [&](bf16x8 (&w)[8], int ks) {
        const char* wt = wbase + (size_t)ks * 16384;
        #pragma unroll
        for (int i = 0; i < 4; ++i) {
            const int wo = ((wcg + i) << 10) | (fkc << 8) | (fr << 4);
            w[i]     = *(const bf16x8*)(wt + wo);
            w[4 + i] = *(const bf16x8*)(wt + 8192 + wo);
        }
    };
    auto cvtStore = [&](char* dstbase, const float4 (&a)[2], int gk0) {
        float e[8] = {a[0].x, a[0].y, a[0].z, a[0].w, a[1].x, a[1].y, a[1].z, a[1].w};
        const float4 sc0 = *(const float4*)(scs + gk0);
        const float4 sc1 = *(const float4*)(scs + gk0 + 4);
        const float4 sh0 = *(const float4*)(shs + gk0);
        const float4 sh1 = *(const float4*)(shs + gk0 + 4);
        e[0] = fmaxf(0.f, fmaf(e[0], sc0.x, sh0.x));
        e[1] = fmaxf(0.f, fmaf(e[1], sc0.y, sh0.y));
        e[2] = fmaxf(0.f, fmaf(e[2], sc0.z, sh0.z));
        e[3] = fmaxf(0.f, fmaf(e[3], sc0.w, sh0.w));
        e[4] = fmaxf(0.f, fmaf(e[4], sc1.x, sh1.x));
        e[5] = fmaxf(0.f, fmaf(e[5], sc1.y, sh1.y));
        e[6] = fmaxf(0.f, fmaf(e[6], sc1.z, sh1.z));
        e[7] = fmaxf(0.f, fmaf(e[7], sc1.w, sh1.w));
        if constexpr (AHL) {
            short h[8], l[8];
            #pragma unroll
            for (int j = 0; j < 8; ++j) split2(e[j], h[j], l[j]);
            *(short8*)(dstbase + awr)         = (short8){h[0],h[1],h[2],h[3],h[4],h[5],h[6],h[7]};
            *(short8*)(dstbase + PLANE + awr) = (short8){l[0],l[1],l[2],l[3],l[4],l[5],l[6],l[7]};
        } else {
            short h[8];
            #pragma unroll
            for (int j = 0; j < 8; ++j) h[j] = f2b(e[j]);
            *(short8*)(dstbase + awr) = (short8){h[0],h[1],h[2],h[3],h[4],h[5],h[6],h[7]};
        }
    };

    f32x4 acc[4][4];
    #pragma unroll
    for (int mi = 0; mi < 4; ++mi)
        #pragma unroll
        for (int ni = 0; ni < 4; ++ni)
            acc[mi][ni] = (f32x4){0.f, 0.f, 0.f, 0.f};

    bf16x8 wc[8], wn[8];
    float4 avA[2], avB[2], avC[2], avD[2];

    auto mfmaStep = [&](char* cbp, bf16x8 (&wUse)[8]) {
        bf16x8 ah[4], al[4];
        #pragma unroll
        for (int i = 0; i < 4; ++i) {
            const int ao = ((wrg + i) << 10) | (fkc << 8) | (fr << 4);
            ah[i] = *(const bf16x8*)(cbp + ao);
            if constexpr (AHL) al[i] = *(const bf16x8*)(cbp + PLANE + ao);
        }
        #pragma unroll
        for (int mi = 0; mi < 4; ++mi)
            #pragma unroll
            for (int ni = 0; ni < 4; ++ni) {
                acc[mi][ni] = __builtin_amdgcn_mfma_f32_16x16x32_bf16(ah[mi], wUse[ni],     acc[mi][ni], 0, 0, 0);
                acc[mi][ni] = __builtin_amdgcn_mfma_f32_16x16x32_bf16(ah[mi], wUse[4 + ni], acc[mi][ni], 0, 0, 0);
                if constexpr (AHL)
                    acc[mi][ni] = __builtin_amdgcn_mfma_f32_16x16x32_bf16(al[mi], wUse[ni], acc[mi][ni], 0, 0, 0);
            }
    };

    auto group = [&](int ks, char* bR0, char* bR1, char* bW0, char* bW1,
                     float4 (&aU0)[2], float4 (&aU1)[2],
                     float4 (&aL0)[2], float4 (&aL1)[2]) {
        if (ks + 4 < KS) loadA(aL0, ((ks + 4) << 5) + ak0);
        if (ks + 1 < KS) loadW(wn, ks + 1);
        mfmaStep(bR0, wc);
        if (ks + 2 < KS) cvtStore(bW0, aU0, ((ks + 2) << 5) + ak0);
        if (ks + 5 < KS) loadA(aL1, ((ks + 5) << 5) + ak0);
        if (ks + 2 < KS) loadW(wc, ks + 2);
        mfmaStep(bR1, wn);
        if (ks + 3 < KS) cvtStore(bW1, aU1, ((ks + 3) << 5) + ak0);
        soft_barrier();
    };

    {
        float4 a0[2], a1[2];
        loadA(a0, ak0);
        loadA(a1, 32 + ak0);
        loadW(wc, 0);
        loadA(avA, 64 + ak0);
        loadA(avB, 96 + ak0);
        cvtStore(sm,         a0, ak0);
        cvtStore(sm + BUFSZ, a1, 32 + ak0);
    }
    soft_barrier();

    for (int ks = 0; ks < KS; ks += 4) {
        group(ks,     sm,             sm + BUFSZ,     sm + 2 * BUFSZ, sm + 3 * BUFSZ,
              avA, avB, avC, avD);
        group(ks + 2, sm + 2 * BUFSZ, sm + 3 * BUFSZ, sm,             sm + BUFSZ,
              avC, avD, avA, avB);
    }

    // ---- epilogue: bias, store, deterministic partial BN stats ----
    float bv[4];
    #pragma unroll
    for (int ni = 0; ni < 4; ++ni)
        bv[ni] = bias[(size_t)c * Fout + o0 + wcol + (ni << 4) + fr];

    float p[4] = {}, q[4] = {};
    const int rsub = (lane >> 4) << 2;
    #pragma unroll
    for (int mi = 0; mi < 4; ++mi) {
        #pragma unroll
        for (int j = 0; j < 4; ++j) {
            const int row = b0 + wrow + (mi << 4) + rsub + j;
            float* op = Out + ((size_t)c * BB + row) * Fout + o0 + wcol;
            #pragma unroll
            for (int ni = 0; ni < 4; ++ni) {
                const float v = acc[mi][ni][j] + bv[ni];
                op[(ni << 4) + fr] = v;
                if (WRITE_STATS) { p[ni] += v; q[ni] += v * v; }
            }
        }
    }

    if (WRITE_STATS) {
        #pragma unroll
        for (int ni = 0; ni < 4; ++ni) {
            p[ni] += __shfl_xor(p[ni], 16); p[ni] += __shfl_xor(p[ni], 32);
            q[ni] += __shfl_xor(q[ni], 16); q[ni] += __shfl_xor(q[ni], 32);
        }
        __syncthreads();
        float* redp = (float*)sm;           // [2][256]
        float* redq = (float*)(sm + 2048);
        if (lane < 16) {
            const int base = wr * 256 + wcol;
            #pragma unroll
            for (int ni = 0; ni < 4; ++ni) {
                redp[base + (ni << 4) + fr] = p[ni];
                redq[base + (ni << 4) + fr] = q[ni];
            }
        }
        __syncthreads();
        if (tid < 256) {
            const float sp = redp[tid] + redp[256 + tid];
            const float sq = redq[tid] + redq[256 + tid];
            const size_t o = ((size_t)c * Fout + o0 + tid) * gridDim.x + btile;
            psumOut[o] = sp;
            psqOut[o]  = sq;
        }
    }
}

__global__ __launch_bounds__(256)
void label_kernel(float* __restrict__ out)
{
    const int i = blockIdx.x * 256 + threadIdx.x;
    out[i] = (float)(i >> 11);   // i / 2048
}

// ---------------------------------------------------------------------------
extern "C" void kernel_launch(void* const* d_in, const int* in_sizes, int n_in,
                              void* d_out, int out_size, void* d_ws, size_t ws_size,
                              hipStream_t stream)
{
    const float* x = (const float*)d_in[0];
    const float* W[5];  const float* bs[5];
    for (int l = 0; l < 5; ++l) { W[l] = (const float*)d_in[1 + 2 * l]; bs[l] = (const float*)d_in[2 + 2 * l]; }
    const float* g[4];  const float* be[4];
    for (int l = 0; l < 4; ++l) { g[l] = (const float*)d_in[11 + 2 * l]; be[l] = (const float*)d_in[12 + 2 * l]; }

    float* out     = (float*)d_out;
    float* gendata = out;                              // [C*BB, 512] — doubles as h1
    float* label   = out + (size_t)CCLS * BB * 512;

    float* ws  = (float*)d_ws;
    float* h2  = ws;                                   // 32MB
    float* h3  = h2 + 8388608;                         // 16MB
    float* h4  = h2;                                   // alias: h2 dead after G3
    float* ps1 = h3 + 4194304;
    float* pq1 = ps1 + 131072;
    float* ps2 = pq1 + 131072;
    float* pq2 = ps2 + 65536;
    float* ps3 = pq2 + 65536;
    float* pq3 = ps3 + 65536;
    float* ps4 = pq3 + 65536;
    float* pq4 = ps4 + 65536;
    char*  pack = (char*)(pq4 + 65536);                // 2560 x 16KB = 40MB

    const char* xpk  = pack;
    const char* wpk1 = pack + (size_t)1024 * 16384;
    const char* wpk2 = pack + (size_t)1280 * 16384;
    const char* wpk3 = pack + (size_t)1792 * 16384;
    const char* wpk4 = pack + (size_t)1920 * 16384;
    const char* wpk5 = pack + (size_t)2048 * 16384;

    const dim3 blk(256);

    PackDesc pd;
    pd.src[0] = x;    pd.src[1] = W[0]; pd.src[2] = W[1];
    pd.src[3] = W[2]; pd.src[4] = W[3]; pd.src[5] = W[4];
    const int nrt[6]   = {16, 4, 2, 1, 2, 4};
    const int ksn[6]   = {4, 4, 16, 8, 4, 8};
    const int kreal[6] = {100, 100, 512, 256, 128, 256};
    const int beg[7]   = {0, 1024, 1280, 1792, 1920, 2048, 2560};
    for (int i = 0; i < 6; ++i) { pd.nrt[i] = nrt[i]; pd.ksn[i] = ksn[i]; pd.kreal[i] = kreal[i]; }
    for (int i = 0; i < 7; ++i) pd.beg[i] = beg[i];
    pack_kernel<<<dim3(2560), blk, 0, stream>>>(pd, pack);

    // G1: x[K=100->128] -> h1(=gendata)[512], stats -> ps1 (PREPACK, 3-product)
    gemm4w_kernel<128, 128, true, true, false, true><<<dim3(16, 4, CCLS), blk, 0, stream>>>(
        nullptr, xpk, wpk1, bs[0], nullptr, nullptr, nullptr, nullptr,
        gendata, ps1, pq1, 512, 0);

    // G2: bn1(h1)->relu -> h2[256], stats (8w paired, A single-plane 2-product)
    gemm8w_kernel<512, false, true><<<dim3(16, 1, CCLS), dim3(512), 0, stream>>>(
        gendata, wpk2, bs[1], ps1, pq1, g[0], be[0],
        h2, ps2, pq2, 256, 16);

    // G3: bn2(h2)->relu -> h3[128], stats (4w BM=64, A single-plane 2-product)
    gemm4w_kernel<64, 256, false, false, true, true><<<dim3(32, 1, CCLS), blk, 0, stream>>>(
        h2, nullptr, wpk3, bs[2], ps2, pq2, g[1], be[1],
        h3, ps3, pq3, 128, 16);

    // G4: bn3(h3)->relu -> h4[256], stats (8w paired, 2-product)
    gemm8w_kernel<128, false, true><<<dim3(16, 1, CCLS), dim3(512), 0, stream>>>(
        h3, wpk4, bs[3], ps3, pq3, g[2], be[2],
        h4, ps4, pq4, 256, 32);

    // G5: bn4(h4)->relu -> gendata[512] (8w paired, FULL 3-product — final out)
    gemm8w_kernel<256, true, false><<<dim3(16, 2, CCLS), dim3(512), 0, stream>>>(
        h4, wpk5, bs[4], ps4, pq4, g[3], be[3],
        gendata, nullptr, nullptr, 512, 16);

    label_kernel<<<dim3(CCLS * BB / 256), blk, 0, stream>>>(label);
}

// Round 16
// 138.826 us; speedup vs baseline: 1.7094x; 1.0251x over previous
//
#include <hip/hip_runtime.h>
#include <hip/hip_bf16.h>
#include <math.h>

#define CCLS 16
#define BB   2048

using bf16x8 = __attribute__((ext_vector_type(8))) short;
using short8 = __attribute__((ext_vector_type(8))) short;
using f32x4  = __attribute__((ext_vector_type(4))) float;

// fp32 -> (hi, lo) bf16 split (RNE; hi+lo reproduces ~24 mantissa bits)
__device__ __forceinline__ void split2(float e, short& hi, short& lo) {
    __hip_bfloat16 h = __float2bfloat16(e);
    hi = __builtin_bit_cast(short, h);
    lo = __builtin_bit_cast(short, __float2bfloat16(e - __bfloat162float(h)));
}
__device__ __forceinline__ short f2b(float e) {
    return __builtin_bit_cast(short, __float2bfloat16(e));
}

// LDS-visibility barrier that does NOT drain vmcnt.
__device__ __forceinline__ void soft_barrier() {
    asm volatile("s_waitcnt lgkmcnt(0)" ::: "memory");
    __builtin_amdgcn_s_barrier();
    asm volatile("" ::: "memory");
}

// global -> LDS direct copy, 16B/lane; lds dest is wave-uniform base
__device__ __forceinline__ void gll16(const void* g, void* l) {
    __builtin_amdgcn_global_load_lds(
        (const __attribute__((address_space(1))) unsigned*)g,
        (__attribute__((address_space(3))) unsigned*)l, 16, 0, 0);
}

// XCD class-clustering remap (perf-only, bijective): XCD k gets classes
// {2k, 2k+1} so its W-panel working set fits the 4MB per-XCD L2.
#define XCD_REMAP(btile, otile, c)                                             \
    int btile, otile, c;                                                       \
    {                                                                          \
        const int bpcls = gridDim.x * gridDim.y;                               \
        const int id = blockIdx.x + gridDim.x * (blockIdx.y + gridDim.y * blockIdx.z); \
        const int j = id >> 3;                                                 \
        c = 2 * (id & 7) + j / bpcls;                                          \
        const int r = j % bpcls;                                               \
        btile = r % gridDim.x;                                                 \
        otile = r / gridDim.x;                                                 \
    }

// Fragment-major layout for a 128-row x 32-k bf16 tile (8 KB/plane):
//   L(row, kchunk) = (row>>4)<<10 | kchunk<<8 | (row&15)<<4   (kchunk = k/8)

// ---------------------------------------------------------------------------
// One-time pack: x and W1..W5 -> [hi 8KB][lo 8KB] fragment-major 128x32 tiles.
// ---------------------------------------------------------------------------
struct PackDesc {
    const float* src[6];
    int nrt[6];
    int ksn[6];
    int kreal[6];
    int beg[7];
};

__global__ __launch_bounds__(256)
void pack_kernel(PackDesc d, char* __restrict__ base)
{
    const int bid = blockIdx.x;
    int s = 0;
    #pragma unroll
    for (int i = 0; i < 5; ++i) s += (bid >= d.beg[i + 1]);
    const int t    = bid - d.beg[s];
    const int ksn  = d.ksn[s], nrt = d.nrt[s], kreal = d.kreal[s];
    const int perc = nrt * ksn;
    const int c  = t / perc;
    const int r  = t - c * perc;
    const int rt = r / ksn;
    const int ks = r - rt * ksn;
    const float* src = d.src[s] + ((size_t)(c * nrt + rt) * 128) * kreal;
    char* dst = base + (size_t)bid * 16384;
    const int tid = threadIdx.x;

    #pragma unroll
    for (int it = 0; it < 2; ++it) {
        const int row = (tid >> 2) + (it << 6);
        const int cc  = tid & 3;
        const int q   = ((row >> 4) << 10) | (cc << 8) | ((row & 15) << 4);
        const int k0  = ks * 32 + cc * 8;
        const float* sp = src + (size_t)row * kreal + k0;
        float e[8];
        if (k0 + 8 <= kreal) {
            float4 v0 = *(const float4*)sp;
            float4 v1 = *(const float4*)(sp + 4);
            e[0]=v0.x; e[1]=v0.y; e[2]=v0.z; e[3]=v0.w;
            e[4]=v1.x; e[5]=v1.y; e[6]=v1.z; e[7]=v1.w;
        } else {
            #pragma unroll
            for (int j = 0; j < 8; ++j) e[j] = (k0 + j < kreal) ? sp[j] : 0.f;
        }
        short hv[8], lv[8];
        #pragma unroll
        for (int j = 0; j < 8; ++j) split2(e[j], hv[j], lv[j]);
        *(short8*)(dst + q)        = (short8){hv[0],hv[1],hv[2],hv[3],hv[4],hv[5],hv[6],hv[7]};
        *(short8*)(dst + 8192 + q) = (short8){lv[0],lv[1],lv[2],lv[3],lv[4],lv[5],lv[6],lv[7]};
    }
}

// ---------------------------------------------------------------------------
// 4-wave kernel: PREPACK path for G1, reg-staged path for G3.
// AHL=false: A used as SINGLE bf16 plane -> 2-product d = a_bf*(wh+wl);
// error ~2^-9 relative, re-normalized by the next BN.
// ---------------------------------------------------------------------------
template<int BM, int K, bool PREPACK, bool AHL, bool FUSE_BN, bool WRITE_STATS>
__global__ __launch_bounds__(256, 2)
void gemm4w_kernel(const float* __restrict__ A, const char* __restrict__ Apk,
                   const char* __restrict__ Wpk, const float* __restrict__ bias,
                   const float* __restrict__ psumIn, const float* __restrict__ psqIn,
                   const float* __restrict__ gIn, const float* __restrict__ beIn,
                   float* __restrict__ Out,
                   float* __restrict__ psumOut, float* __restrict__ psqOut,
                   const int Fout, const int nbtIn)
{
    constexpr int KS    = (K + 31) / 32;
    constexpr int PLANE = BM * 64;
    constexpr int WOFF  = AHL ? 16384 : 8192;                  // W base in PREPACK buf
    constexpr int BUFSZ = PREPACK ? (AHL ? 32768 : 24576) : (AHL ? 2 * PLANE : PLANE);
    static_assert(PREPACK || (K % 32 == 0), "");
    static_assert(PREPACK || (KS % 2 == 0) || (KS == 1), "");

    __shared__ __align__(16) char sm[2 * BUFSZ + (FUSE_BN ? 8 * K : 16)];
    float* scs = (float*)(sm + 2 * BUFSZ);
    float* shs = scs + (FUSE_BN ? K : 0);

    const int tid   = threadIdx.x;
    const int btile = blockIdx.x, otile = blockIdx.y, c = blockIdx.z;

    if (FUSE_BN) {
        for (int f = tid; f < K; f += 256) {
            const float* ps = psumIn + ((size_t)c * K + f) * nbtIn;
            const float* pq = psqIn  + ((size_t)c * K + f) * nbtIn;
            float s = 0.f, q = 0.f;
            for (int t = 0; t < nbtIn; t += 4) {
                float4 a4 = *(const float4*)(ps + t);
                float4 b4 = *(const float4*)(pq + t);
                s += (a4.x + a4.y) + (a4.z + a4.w);
                q += (b4.x + b4.y) + (b4.z + b4.w);
            }
            const float mean = s * (1.f / BB);
            const float var  = q * (1.f / BB) - mean * mean;
            const float rstd = rsqrtf(var + 1e-5f);
            const float scv  = gIn[(size_t)c * K + f] * rstd;
            scs[f] = scv;
            shs[f] = fmaf(-mean, scv, beIn[(size_t)c * K + f]);
        }
        __syncthreads();
    }

    const int b0 = btile * BM, o0 = otile * 128;
    const int OT = Fout >> 7;
    const char* wbase = Wpk + (size_t)((c * OT + otile) * KS) * 16384;
    const char* abase = PREPACK ? (Apk + (size_t)((c * gridDim.x + btile) * KS) * 16384) : nullptr;

    const int lane = tid & 63, wv = tid >> 6;
    const int fr = lane & 15, fkc = lane >> 4;
    const int wrow = (BM == 128) ? ((wv >> 1) << 6) : ((wv >> 1) << 5);
    const int wcol = (wv & 1) << 6;
    const int wrg = wrow >> 4, wcg = wcol >> 4;
    constexpr int MI = BM / 32;

    f32x4 acc[MI][4];
    #pragma unroll
    for (int mi = 0; mi < MI; ++mi)
        #pragma unroll
        for (int ni = 0; ni < 4; ++ni)
            acc[mi][ni] = (f32x4){0.f, 0.f, 0.f, 0.f};

    if constexpr (PREPACK) {
        auto stageTile = [&](int nb, int ks) {
            const char* at = abase + (size_t)ks * 16384;
            const char* wt = wbase + (size_t)ks * 16384;
            char* dst = sm + nb;
            if constexpr (AHL) {
                #pragma unroll
                for (int i = 0; i < 4; ++i) {
                    const int rg = ((wv << 2) + i) << 10;
                    gll16(at + rg + (lane << 4), dst + rg);
                    gll16(wt + rg + (lane << 4), dst + WOFF + rg);
                }
            } else {
                #pragma unroll
                for (int i = 0; i < 2; ++i) {            // A hi plane: 8 chunks
                    const int rg = ((wv << 1) + i) << 10;
                    gll16(at + rg + (lane << 4), dst + rg);
                }
                #pragma unroll
                for (int i = 0; i < 4; ++i) {            // W hi+lo: 16 chunks
                    const int rg = ((wv << 2) + i) << 10;
                    gll16(wt + rg + (lane << 4), dst + WOFF + rg);
                }
            }
        };
        stageTile(0, 0);
        __syncthreads();
        for (int ks = 0; ks < KS; ++ks) {
            const int cb = (ks & 1) ? BUFSZ : 0;
            if (ks + 1 < KS) stageTile(cb ^ BUFSZ, ks + 1);
            bf16x8 ah[MI], al[MI], wh[4], wl[4];
            #pragma unroll
            for (int i = 0; i < 4; ++i) {
                const int wo = ((wcg + i) << 10) | (fkc << 8) | (fr << 4);
                wh[i] = *(const bf16x8*)(sm + cb + WOFF + wo);
                wl[i] = *(const bf16x8*)(sm + cb + WOFF + 8192 + wo);
            }
            #pragma unroll
            for (int i = 0; i < MI; ++i) {
                const int ao = ((wrg + i) << 10) | (fkc << 8) | (fr << 4);
                ah[i] = *(const bf16x8*)(sm + cb + ao);
                if constexpr (AHL) al[i] = *(const bf16x8*)(sm + cb + 8192 + ao);
            }
            #pragma unroll
            for (int mi = 0; mi < MI; ++mi)
                #pragma unroll
                for (int ni = 0; ni < 4; ++ni) {
                    acc[mi][ni] = __builtin_amdgcn_mfma_f32_16x16x32_bf16(ah[mi], wh[ni], acc[mi][ni], 0, 0, 0);
                    acc[mi][ni] = __builtin_amdgcn_mfma_f32_16x16x32_bf16(ah[mi], wl[ni], acc[mi][ni], 0, 0, 0);
                    if constexpr (AHL)
                        acc[mi][ni] = __builtin_amdgcn_mfma_f32_16x16x32_bf16(al[mi], wh[ni], acc[mi][ni], 0, 0, 0);
                }
            __syncthreads();
        }
    } else {
        constexpr int NV = BM / 32;
        const int arow = (BM == 128) ? (tid >> 1) : (tid >> 2);
        const int asub = (BM == 128) ? (tid & 1)  : (tid & 3);
        const int ak0  = (BM == 128) ? (asub << 4) : (asub << 3);
        const int kch  = (BM == 128) ? (asub << 1) : asub;
        const int awr  = ((arow >> 4) << 10) | (kch << 8) | ((arow & 15) << 4);
        const float* Arow = A + ((size_t)c * BB + b0 + arow) * K;

        auto loadA = [&](float4 (&av)[NV], int gk0) {
            #pragma unroll
            for (int i = 0; i < NV; ++i)
                av[i] = *(const float4*)(Arow + gk0 + (i << 2));
        };
        auto loadW = [&](bf16x8 (&w)[8], int ks) {
            const char* wt = wbase + (size_t)ks * 16384;
            #pragma unroll
            for (int i = 0; i < 4; ++i) {
                const int wo = ((wcg + i) << 10) | (fkc << 8) | (fr << 4);
                w[i]     = *(const bf16x8*)(wt + wo);
                w[4 + i] = *(const bf16x8*)(wt + 8192 + wo);
            }
        };
        auto cvtStore = [&](char* dstbase, const float4 (&a)[NV], int gk0) {
            float e[NV * 4];
            #pragma unroll
            for (int i = 0; i < NV; ++i) {
                e[i*4+0] = a[i].x; e[i*4+1] = a[i].y; e[i*4+2] = a[i].z; e[i*4+3] = a[i].w;
            }
            if constexpr (FUSE_BN) {
                #pragma unroll
                for (int i = 0; i < NV; ++i) {
                    const float4 sc = *(const float4*)(scs + gk0 + (i << 2));
                    const float4 sh = *(const float4*)(shs + gk0 + (i << 2));
                    e[i*4+0] = fmaxf(0.f, fmaf(e[i*4+0], sc.x, sh.x));
                    e[i*4+1] = fmaxf(0.f, fmaf(e[i*4+1], sc.y, sh.y));
                    e[i*4+2] = fmaxf(0.f, fmaf(e[i*4+2], sc.z, sh.z));
                    e[i*4+3] = fmaxf(0.f, fmaf(e[i*4+3], sc.w, sh.w));
                }
            }
            if constexpr (AHL) {
                short h[NV*4], l[NV*4];
                #pragma unroll
                for (int j = 0; j < NV*4; ++j) split2(e[j], h[j], l[j]);
                *(short8*)(dstbase + awr)         = (short8){h[0],h[1],h[2],h[3],h[4],h[5],h[6],h[7]};
                *(short8*)(dstbase + PLANE + awr) = (short8){l[0],l[1],l[2],l[3],l[4],l[5],l[6],l[7]};
                if constexpr (NV == 4) {
                    *(short8*)(dstbase + awr + 256)         = (short8){h[8],h[9],h[10],h[11],h[12],h[13],h[14],h[15]};
                    *(short8*)(dstbase + PLANE + awr + 256) = (short8){l[8],l[9],l[10],l[11],l[12],l[13],l[14],l[15]};
                }
            } else {
                short h[NV*4];
                #pragma unroll
                for (int j = 0; j < NV*4; ++j) h[j] = f2b(e[j]);
                *(short8*)(dstbase + awr) = (short8){h[0],h[1],h[2],h[3],h[4],h[5],h[6],h[7]};
                if constexpr (NV == 4)
                    *(short8*)(dstbase + awr + 256) = (short8){h[8],h[9],h[10],h[11],h[12],h[13],h[14],h[15]};
            }
        };

        bf16x8 wcA[8], wcB[8];
        float4 avP[NV], avQ[NV];

        auto step = [&](int ks, char* cbp, char* nbp,
                        float4 (&avUse)[NV], float4 (&avLoad)[NV],
                        bf16x8 (&wUse)[8], bf16x8 (&wLoad)[8]) {
            const bool hn  = (ks + 1) < KS;
            const bool hn2 = (ks + 2) < KS;
            if (hn2) loadA(avLoad, ((ks + 2) << 5) + ak0);
            if (hn)  loadW(wLoad, ks + 1);
            bf16x8 ah[MI], al[MI];
            #pragma unroll
            for (int i = 0; i < MI; ++i) {
                const int ao = ((wrg + i) << 10) | (fkc << 8) | (fr << 4);
                ah[i] = *(const bf16x8*)(cbp + ao);
                if constexpr (AHL) al[i] = *(const bf16x8*)(cbp + PLANE + ao);
            }
            #pragma unroll
            for (int mi = 0; mi < MI; ++mi)
                #pragma unroll
                for (int ni = 0; ni < 4; ++ni) {
                    acc[mi][ni] = __builtin_amdgcn_mfma_f32_16x16x32_bf16(ah[mi], wUse[ni],     acc[mi][ni], 0, 0, 0);
                    acc[mi][ni] = __builtin_amdgcn_mfma_f32_16x16x32_bf16(ah[mi], wUse[4 + ni], acc[mi][ni], 0, 0, 0);
                    if constexpr (AHL)
                        acc[mi][ni] = __builtin_amdgcn_mfma_f32_16x16x32_bf16(al[mi], wUse[ni], acc[mi][ni], 0, 0, 0);
                }
            if (hn) cvtStore(nbp, avUse, ((ks + 1) << 5) + ak0);
            soft_barrier();
        };

        {
            float4 av0[NV];
            loadA(av0, ak0);
            loadW(wcA, 0);
            if (KS > 1) loadA(avP, 32 + ak0);
            cvtStore(sm, av0, ak0);
        }
        soft_barrier();

        for (int ks = 0; ks < KS; ks += 2) {
            step(ks,     sm,         sm + BUFSZ, avP, avQ, wcA, wcB);
            step(ks + 1, sm + BUFSZ, sm,         avQ, avP, wcB, wcA);
        }
    }

    // ---- epilogue ----
    float bv[4];
    #pragma unroll
    for (int ni = 0; ni < 4; ++ni)
        bv[ni] = bias[(size_t)c * Fout + o0 + wcol + (ni << 4) + fr];

    float p[4] = {}, q[4] = {};
    const int rsub = (lane >> 4) << 2;
    #pragma unroll
    for (int mi = 0; mi < MI; ++mi) {
        #pragma unroll
        for (int j = 0; j < 4; ++j) {
            const int row = b0 + wrow + (mi << 4) + rsub + j;
            float* op = Out + ((size_t)c * BB + row) * Fout + o0 + wcol;
            #pragma unroll
            for (int ni = 0; ni < 4; ++ni) {
                const float v = acc[mi][ni][j] + bv[ni];
                op[(ni << 4) + fr] = v;
                if (WRITE_STATS) { p[ni] += v; q[ni] += v * v; }
            }
        }
    }

    if (WRITE_STATS) {
        #pragma unroll
        for (int ni = 0; ni < 4; ++ni) {
            p[ni] += __shfl_xor(p[ni], 16); p[ni] += __shfl_xor(p[ni], 32);
            q[ni] += __shfl_xor(q[ni], 16); q[ni] += __shfl_xor(q[ni], 32);
        }
        __syncthreads();
        float* redp = (float*)sm;
        float* redq = (float*)(sm + 1024);
        if (lane < 16) {
            const int base = (wv >> 1) * 128 + wcol;
            #pragma unroll
            for (int ni = 0; ni < 4; ++ni) {
                redp[base + (ni << 4) + fr] = p[ni];
                redq[base + (ni << 4) + fr] = q[ni];
            }
        }
        __syncthreads();
        if (tid < 128) {
            const float sp = redp[tid] + redp[128 + tid];
            const float sq = redq[tid] + redq[128 + tid];
            const size_t o = ((size_t)c * Fout + o0 + tid) * gridDim.x + btile;
            psumOut[o] = sp;
            psqOut[o]  = sq;
        }
    }
}

// ---------------------------------------------------------------------------
// 8-wave (512-thread) 128x256 tile kernel, TWO K-steps per barrier (4 LDS
// A-buffers, steps mod 4). AHL=false: single-plane A (2-product); true: full
// hi/lo (3-product). XCD class-cluster remap for W L2 locality.
// ---------------------------------------------------------------------------
template<int K, bool AHL, bool WRITE_STATS>
__global__ __launch_bounds__(512, 2)
void gemm8w_kernel(const float* __restrict__ A, const char* __restrict__ Wpk,
                   const float* __restrict__ bias,
                   const float* __restrict__ psumIn, const float* __restrict__ psqIn,
                   const float* __restrict__ gIn, const float* __restrict__ beIn,
                   float* __restrict__ Out,
                   float* __restrict__ psumOut, float* __restrict__ psqOut,
                   const int Fout, const int nbtIn)
{
    constexpr int KS    = K / 32;
    constexpr int PLANE = 8192;                      // 128x32 bf16 plane
    constexpr int BUFSZ = AHL ? 16384 : 8192;        // per-step A buffer
    static_assert(K % 128 == 0, "need KS % 4 == 0 for the paired schedule");

    __shared__ __align__(16) char sm[4 * BUFSZ + 8 * K];
    float* scs = (float*)(sm + 4 * BUFSZ);
    float* shs = scs + K;

    const int tid = threadIdx.x;
    XCD_REMAP(btile, otile, c)

    // folded combine: BN scale/shift for INPUT features
    for (int f = tid; f < K; f += 512) {
        const float* ps = psumIn + ((size_t)c * K + f) * nbtIn;
        const float* pq = psqIn  + ((size_t)c * K + f) * nbtIn;
        float s = 0.f, q = 0.f;
        for (int t = 0; t < nbtIn; t += 4) {
            float4 a4 = *(const float4*)(ps + t);
            float4 b4 = *(const float4*)(pq + t);
            s += (a4.x + a4.y) + (a4.z + a4.w);
            q += (b4.x + b4.y) + (b4.z + b4.w);
        }
        const float mean = s * (1.f / BB);
        const float var  = q * (1.f / BB) - mean * mean;
        const float rstd = rsqrtf(var + 1e-5f);
        const float scv  = gIn[(size_t)c * K + f] * rstd;
        scs[f] = scv;
        shs[f] = fmaf(-mean, scv, beIn[(size_t)c * K + f]);
    }
    __syncthreads();

    const int b0 = btile * 128, o0 = otile * 256;
    const int OT128 = Fout >> 7;

    // A staging map: 512 threads, 8 floats each (one 16B frag slot)
    const int arow = tid >> 2, asub = tid & 3;
    const int ak0  = asub << 3;
    const int awr  = ((arow >> 4) << 10) | (asub << 8) | ((arow & 15) << 4);
    const float* Arow = A + ((size_t)c * BB + b0 + arow) * K;

    // wave map: 2(M) x 4(N), each wave 64x64
    const int lane = tid & 63, wv = tid >> 6;
    const int wr = wv >> 2, nc = wv & 3;
    const int wrow = wr << 6, wcol = nc << 6;
    const int fr = lane & 15, fkc = lane >> 4;
    const int wrg = wrow >> 4;
    const int wtile = wcol >> 7;
    const int wcg = (wcol >> 4) & 7;
    const char* wbase = Wpk + (size_t)((c * OT128 + otile * 2 + wtile) * KS) * 16384;

    auto loadA = [&](float4 (&av)[2], int gk0) {
        av[0] = *(const float4*)(Arow + gk0);
        av[1] = *(const float4*)(Arow + gk0 + 4);
    };
    auto loadW = [&](bf16x8 (&w)[8], int ks) {
        const char* wt = wbase + (size_t)ks * 16384;
        #pragma unroll
        for (int i = 0; i < 4; ++i) {
            const int wo = ((wcg + i) << 10) | (fkc << 8) | (fr << 4);
            w[i]     = *(const bf16x8*)(wt + wo);
            w[4 + i] = *(const bf16x8*)(wt + 8192 + wo);
        }
    };
    auto cvtStore = [&](char* dstbase, const float4 (&a)[2], int gk0) {
        float e[8] = {a[0].x, a[0].y, a[0].z, a[0].w, a[1].x, a[1].y, a[1].z, a[1].w};
        const float4 sc0 = *(const float4*)(scs + gk0);
        const float4 sc1 = *(const float4*)(scs + gk0 + 4);
        const float4 sh0 = *(const float4*)(shs + gk0);
        const float4 sh1 = *(const float4*)(shs + gk0 + 4);
        e[0] = fmaxf(0.f, fmaf(e[0], sc0.x, sh0.x));
        e[1] = fmaxf(0.f, fmaf(e[1], sc0.y, sh0.y));
        e[2] = fmaxf(0.f, fmaf(e[2], sc0.z, sh0.z));
        e[3] = fmaxf(0.f, fmaf(e[3], sc0.w, sh0.w));
        e[4] = fmaxf(0.f, fmaf(e[4], sc1.x, sh1.x));
        e[5] = fmaxf(0.f, fmaf(e[5], sc1.y, sh1.y));
        e[6] = fmaxf(0.f, fmaf(e[6], sc1.z, sh1.z));
        e[7] = fmaxf(0.f, fmaf(e[7], sc1.w, sh1.w));
        if constexpr (AHL) {
            short h[8], l[8];
            #pragma unroll
            for (int j = 0; j < 8; ++j) split2(e[j], h[j], l[j]);
            *(short8*)(dstbase + awr)         = (short8){h[0],h[1],h[2],h[3],h[4],h[5],h[6],h[7]};
            *(short8*)(dstbase + PLANE + awr) = (short8){l[0],l[1],l[2],l[3],l[4],l[5],l[6],l[7]};
        } else {
            short h[8];
            #pragma unroll
            for (int j = 0; j < 8; ++j) h[j] = f2b(e[j]);
            *(short8*)(dstbase + awr) = (short8){h[0],h[1],h[2],h[3],h[4],h[5],h[6],h[7]};
        }
    };

    f32x4 acc[4][4];
    #pragma unroll
    for (int mi = 0; mi < 4; ++mi)
        #pragma unroll
        for (int ni = 0; ni < 4; ++ni)
            acc[mi][ni] = (f32x4){0.f, 0.f, 0.f, 0.f};

    bf16x8 wc[8], wn[8];
    float4 avA[2], avB[2], avC[2], avD[2];

    auto mfmaStep = [&](char* cbp, bf16x8 (&wUse)[8]) {
        bf16x8 ah[4], al[4];
        #pragma unroll
        for (int i = 0; i < 4; ++i) {
            const int ao = ((wrg + i) << 10) | (fkc << 8) | (fr << 4);
            ah[i] = *(const bf16x8*)(cbp + ao);
            if constexpr (AHL) al[i] = *(const bf16x8*)(cbp + PLANE + ao);
        }
        #pragma unroll
        for (int mi = 0; mi < 4; ++mi)
            #pragma unroll
            for (int ni = 0; ni < 4; ++ni) {
                acc[mi][ni] = __builtin_amdgcn_mfma_f32_16x16x32_bf16(ah[mi], wUse[ni],     acc[mi][ni], 0, 0, 0);
                acc[mi][ni] = __builtin_amdgcn_mfma_f32_16x16x32_bf16(ah[mi], wUse[4 + ni], acc[mi][ni], 0, 0, 0);
                if constexpr (AHL)
                    acc[mi][ni] = __builtin_amdgcn_mfma_f32_16x16x32_bf16(al[mi], wUse[ni], acc[mi][ni], 0, 0, 0);
            }
    };

    auto group = [&](int ks, char* bR0, char* bR1, char* bW0, char* bW1,
                     float4 (&aU0)[2], float4 (&aU1)[2],
                     float4 (&aL0)[2], float4 (&aL1)[2]) {
        if (ks + 4 < KS) loadA(aL0, ((ks + 4) << 5) + ak0);
        if (ks + 1 < KS) loadW(wn, ks + 1);
        mfmaStep(bR0, wc);
        if (ks + 2 < KS) cvtStore(bW0, aU0, ((ks + 2) << 5) + ak0);
        if (ks + 5 < KS) loadA(aL1, ((ks + 5) << 5) + ak0);
        if (ks + 2 < KS) loadW(wc, ks + 2);
        mfmaStep(bR1, wn);
        if (ks + 3 < KS) cvtStore(bW1, aU1, ((ks + 3) << 5) + ak0);
        soft_barrier();
    };

    {
        float4 a0[2], a1[2];
        loadA(a0, ak0);
        loadA(a1, 32 + ak0);
        loadW(wc, 0);
        loadA(avA, 64 + ak0);
        loadA(avB, 96 + ak0);
        cvtStore(sm,         a0, ak0);
        cvtStore(sm + BUFSZ, a1, 32 + ak0);
    }
    soft_barrier();

    for (int ks = 0; ks < KS; ks += 4) {
        group(ks,     sm,             sm + BUFSZ,     sm + 2 * BUFSZ, sm + 3 * BUFSZ,
              avA, avB, avC, avD);
        group(ks + 2, sm + 2 * BUFSZ, sm + 3 * BUFSZ, sm,             sm + BUFSZ,
              avC, avD, avA, avB);
    }

    // ---- epilogue: bias, store, deterministic partial BN stats ----
    float bv[4];
    #pragma unroll
    for (int ni = 0; ni < 4; ++ni)
        bv[ni] = bias[(size_t)c * Fout + o0 + wcol + (ni << 4) + fr];

    float p[4] = {}, q[4] = {};
    const int rsub = (lane >> 4) << 2;
    #pragma unroll
    for (int mi = 0; mi < 4; ++mi) {
        #pragma unroll
        for (int j = 0; j < 4; ++j) {
            const int row = b0 + wrow + (mi << 4) + rsub + j;
            float* op = Out + ((size_t)c * BB + row) * Fout + o0 + wcol;
            #pragma unroll
            for (int ni = 0; ni < 4; ++ni) {
                const float v = acc[mi][ni][j] + bv[ni];
                op[(ni << 4) + fr] = v;
                if (WRITE_STATS) { p[ni] += v; q[ni] += v * v; }
            }
        }
    }

    if (WRITE_STATS) {
        #pragma unroll
        for (int ni = 0; ni < 4; ++ni) {
            p[ni] += __shfl_xor(p[ni], 16); p[ni] += __shfl_xor(p[ni], 32);
            q[ni] += __shfl_xor(q[ni], 16); q[ni] += __shfl_xor(q[ni], 32);
        }
        __syncthreads();
        float* redp = (float*)sm;           // [2][256]
        float* redq = (float*)(sm + 2048);
        if (lane < 16) {
            const int base = wr * 256 + wcol;
            #pragma unroll
            for (int ni = 0; ni < 4; ++ni) {
                redp[base + (ni << 4) + fr] = p[ni];
                redq[base + (ni << 4) + fr] = q[ni];
            }
        }
        __syncthreads();
        if (tid < 256) {
            const float sp = redp[tid] + redp[256 + tid];
            const float sq = redq[tid] + redq[256 + tid];
            const size_t o = ((size_t)c * Fout + o0 + tid) * gridDim.x + btile;
            psumOut[o] = sp;
            psqOut[o]  = sq;
        }
    }
}

__global__ __launch_bounds__(256)
void label_kernel(float* __restrict__ out)
{
    const int i = blockIdx.x * 256 + threadIdx.x;
    out[i] = (float)(i >> 11);   // i / 2048
}

// ---------------------------------------------------------------------------
extern "C" void kernel_launch(void* const* d_in, const int* in_sizes, int n_in,
                              void* d_out, int out_size, void* d_ws, size_t ws_size,
                              hipStream_t stream)
{
    const float* x = (const float*)d_in[0];
    const float* W[5];  const float* bs[5];
    for (int l = 0; l < 5; ++l) { W[l] = (const float*)d_in[1 + 2 * l]; bs[l] = (const float*)d_in[2 + 2 * l]; }
    const float* g[4];  const float* be[4];
    for (int l = 0; l < 4; ++l) { g[l] = (const float*)d_in[11 + 2 * l]; be[l] = (const float*)d_in[12 + 2 * l]; }

    float* out     = (float*)d_out;
    float* gendata = out;                              // [C*BB, 512] — doubles as h1
    float* label   = out + (size_t)CCLS * BB * 512;

    float* ws  = (float*)d_ws;
    float* h2  = ws;                                   // 32MB
    float* h3  = h2 + 8388608;                         // 16MB
    float* h4  = h2;                                   // alias: h2 dead after G3
    float* ps1 = h3 + 4194304;
    float* pq1 = ps1 + 131072;
    float* ps2 = pq1 + 131072;
    float* pq2 = ps2 + 65536;
    float* ps3 = pq2 + 65536;
    float* pq3 = ps3 + 65536;
    float* ps4 = pq3 + 65536;
    float* pq4 = ps4 + 65536;
    char*  pack = (char*)(pq4 + 65536);                // 2560 x 16KB = 40MB

    const char* xpk  = pack;
    const char* wpk1 = pack + (size_t)1024 * 16384;
    const char* wpk2 = pack + (size_t)1280 * 16384;
    const char* wpk3 = pack + (size_t)1792 * 16384;
    const char* wpk4 = pack + (size_t)1920 * 16384;
    const char* wpk5 = pack + (size_t)2048 * 16384;

    const dim3 blk(256);

    PackDesc pd;
    pd.src[0] = x;    pd.src[1] = W[0]; pd.src[2] = W[1];
    pd.src[3] = W[2]; pd.src[4] = W[3]; pd.src[5] = W[4];
    const int nrt[6]   = {16, 4, 2, 1, 2, 4};
    const int ksn[6]   = {4, 4, 16, 8, 4, 8};
    const int kreal[6] = {100, 100, 512, 256, 128, 256};
    const int beg[7]   = {0, 1024, 1280, 1792, 1920, 2048, 2560};
    for (int i = 0; i < 6; ++i) { pd.nrt[i] = nrt[i]; pd.ksn[i] = ksn[i]; pd.kreal[i] = kreal[i]; }
    for (int i = 0; i < 7; ++i) pd.beg[i] = beg[i];
    pack_kernel<<<dim3(2560), blk, 0, stream>>>(pd, pack);

    // G1: x[K=100->128] -> h1(=gendata)[512], stats (PREPACK, 2-product: A-hi only)
    gemm4w_kernel<128, 128, true, false, false, true><<<dim3(16, 4, CCLS), blk, 0, stream>>>(
        nullptr, xpk, wpk1, bs[0], nullptr, nullptr, nullptr, nullptr,
        gendata, ps1, pq1, 512, 0);

    // G2: bn1(h1)->relu -> h2[256], stats (8w paired, 2-product)
    gemm8w_kernel<512, false, true><<<dim3(16, 1, CCLS), dim3(512), 0, stream>>>(
        gendata, wpk2, bs[1], ps1, pq1, g[0], be[0],
        h2, ps2, pq2, 256, 16);

    // G3: bn2(h2)->relu -> h3[128], stats (4w BM=64, 2-product)
    gemm4w_kernel<64, 256, false, false, true, true><<<dim3(32, 1, CCLS), blk, 0, stream>>>(
        h2, nullptr, wpk3, bs[2], ps2, pq2, g[1], be[1],
        h3, ps3, pq3, 128, 16);

    // G4: bn3(h3)->relu -> h4[256], stats (8w paired, 2-product)
    gemm8w_kernel<128, false, true><<<dim3(16, 1, CCLS), dim3(512), 0, stream>>>(
        h3, wpk4, bs[3], ps3, pq3, g[2], be[2],
        h4, ps4, pq4, 256, 32);

    // G5: bn4(h4)->relu -> gendata[512] (8w paired, 2-product — tolerance test;
    // pre-commit: if validation fails, revert THIS layer to 3-product)
    gemm8w_kernel<256, false, false><<<dim3(16, 2, CCLS), dim3(512), 0, stream>>>(
        h4, wpk5, bs[4], ps4, pq4, g[3], be[3],
        gendata, nullptr, nullptr, 512, 16);

    label_kernel<<<dim3(CCLS * BB / 256), blk, 0, stream>>>(label);
}

// Round 18
// 125.498 us; speedup vs baseline: 1.8910x; 1.1062x over previous
//
#include <hip/hip_runtime.h>
#include <hip/hip_bf16.h>
#include <math.h>

#define CCLS 16
#define BB   2048

using bf16x8  = __attribute__((ext_vector_type(8))) short;
using short8  = __attribute__((ext_vector_type(8))) short;
using f32x4   = __attribute__((ext_vector_type(4))) float;

// fp32 -> (hi, lo) bf16 split (RNE)
__device__ __forceinline__ void split2(float e, short& hi, short& lo) {
    __hip_bfloat16 h = __float2bfloat16(e);
    hi = __builtin_bit_cast(short, h);
    lo = __builtin_bit_cast(short, __float2bfloat16(e - __bfloat162float(h)));
}
__device__ __forceinline__ short f2b(float e) {
    return __builtin_bit_cast(short, __float2bfloat16(e));
}
__device__ __forceinline__ float b2f(short s) {
    unsigned u = ((unsigned)(unsigned short)s) << 16;
    return __builtin_bit_cast(float, u);
}

// LDS-visibility barrier that does NOT drain vmcnt.
__device__ __forceinline__ void soft_barrier() {
    asm volatile("s_waitcnt lgkmcnt(0)" ::: "memory");
    __builtin_amdgcn_s_barrier();
    asm volatile("" ::: "memory");
}

// global -> LDS direct copy, 16B/lane; lds dest is wave-uniform base
__device__ __forceinline__ void gll16(const void* g, void* l) {
    __builtin_amdgcn_global_load_lds(
        (const __attribute__((address_space(1))) unsigned*)g,
        (__attribute__((address_space(3))) unsigned*)l, 16, 0, 0);
}

// XCD class-clustering remap (perf-only, bijective): XCD k gets classes
// {2k, 2k+1} so its W-panel working set fits the 4MB per-XCD L2.
#define XCD_REMAP(btile, otile, c)                                             \
    int btile, otile, c;                                                       \
    {                                                                          \
        const int bpcls = gridDim.x * gridDim.y;                               \
        const int id = blockIdx.x + gridDim.x * (blockIdx.y + gridDim.y * blockIdx.z); \
        const int j = id >> 3;                                                 \
        c = 2 * (id & 7) + j / bpcls;                                          \
        const int r = j % bpcls;                                               \
        btile = r % gridDim.x;                                                 \
        otile = r / gridDim.x;                                                 \
    }

// Fragment-major layout for a 128-row x 32-k bf16 tile (8 KB/plane):
//   L(row, kchunk) = (row>>4)<<10 | kchunk<<8 | (row&15)<<4   (kchunk = k/8)

// ---------------------------------------------------------------------------
// One-time pack: x and W1..W5 -> [hi 8KB][lo 8KB] fragment-major 128x32 tiles.
// ---------------------------------------------------------------------------
struct PackDesc {
    const float* src[6];
    int nrt[6];
    int ksn[6];
    int kreal[6];
    int beg[7];
};

__global__ __launch_bounds__(256)
void pack_kernel(PackDesc d, char* __restrict__ base)
{
    const int bid = blockIdx.x;
    int s = 0;
    #pragma unroll
    for (int i = 0; i < 5; ++i) s += (bid >= d.beg[i + 1]);
    const int t    = bid - d.beg[s];
    const int ksn  = d.ksn[s], nrt = d.nrt[s], kreal = d.kreal[s];
    const int perc = nrt * ksn;
    const int c  = t / perc;
    const int r  = t - c * perc;
    const int rt = r / ksn;
    const int ks = r - rt * ksn;
    const float* src = d.src[s] + ((size_t)(c * nrt + rt) * 128) * kreal;
    char* dst = base + (size_t)bid * 16384;
    const int tid = threadIdx.x;

    #pragma unroll
    for (int it = 0; it < 2; ++it) {
        const int row = (tid >> 2) + (it << 6);
        const int cc  = tid & 3;
        const int q   = ((row >> 4) << 10) | (cc << 8) | ((row & 15) << 4);
        const int k0  = ks * 32 + cc * 8;
        const float* sp = src + (size_t)row * kreal + k0;
        float e[8];
        if (k0 + 8 <= kreal) {
            float4 v0 = *(const float4*)sp;
            float4 v1 = *(const float4*)(sp + 4);
            e[0]=v0.x; e[1]=v0.y; e[2]=v0.z; e[3]=v0.w;
            e[4]=v1.x; e[5]=v1.y; e[6]=v1.z; e[7]=v1.w;
        } else {
            #pragma unroll
            for (int j = 0; j < 8; ++j) e[j] = (k0 + j < kreal) ? sp[j] : 0.f;
        }
        short hv[8], lv[8];
        #pragma unroll
        for (int j = 0; j < 8; ++j) split2(e[j], hv[j], lv[j]);
        *(short8*)(dst + q)        = (short8){hv[0],hv[1],hv[2],hv[3],hv[4],hv[5],hv[6],hv[7]};
        *(short8*)(dst + 8192 + q) = (short8){lv[0],lv[1],lv[2],lv[3],lv[4],lv[5],lv[6],lv[7]};
    }
}

// ---------------------------------------------------------------------------
// 4-wave kernel. PREPACK path (G1): A-hi + W hi/lo staged via global_load_lds,
// 2-product. Reg path (G3, BM=64): bf16 activations in, 2-product.
// OUTBF16: write bf16 activations (stats still computed from fp32 acc).
// ---------------------------------------------------------------------------
template<int BM, int K, bool PREPACK, bool OUTBF16, bool FUSE_BN, bool WRITE_STATS>
__global__ __launch_bounds__(256, 2)
void gemm4w_kernel(const unsigned short* __restrict__ A,   // bf16 (reg path)
                   const char* __restrict__ Apk, const char* __restrict__ Wpk,
                   const float* __restrict__ bias,
                   const float* __restrict__ psumIn, const float* __restrict__ psqIn,
                   const float* __restrict__ gIn, const float* __restrict__ beIn,
                   void* __restrict__ OutV,
                   float* __restrict__ psumOut, float* __restrict__ psqOut,
                   const int Fout, const int nbtIn)
{
    constexpr int KS    = (K + 31) / 32;
    constexpr int PLANE = BM * 64;
    constexpr int WOFF  = 8192;                          // W base in PREPACK buf (A-hi only)
    constexpr int BUFSZ = PREPACK ? 24576 : PLANE;       // prepack: Ahi+Whi+Wlo; reg: Ahi
    static_assert(PREPACK || (K % 32 == 0), "");
    static_assert(PREPACK || (KS % 2 == 0) || (KS == 1), "");
    static_assert(PREPACK || BM == 64, "reg path supports BM=64 only");

    __shared__ __align__(16) char sm[2 * BUFSZ + (FUSE_BN ? 8 * K : 16)];
    float* scs = (float*)(sm + 2 * BUFSZ);
    float* shs = scs + (FUSE_BN ? K : 0);

    const int tid   = threadIdx.x;
    const int btile = blockIdx.x, otile = blockIdx.y, c = blockIdx.z;

    if (FUSE_BN) {
        for (int f = tid; f < K; f += 256) {
            const float* ps = psumIn + ((size_t)c * K + f) * nbtIn;
            const float* pq = psqIn  + ((size_t)c * K + f) * nbtIn;
            float s = 0.f, q = 0.f;
            for (int t = 0; t < nbtIn; t += 4) {
                float4 a4 = *(const float4*)(ps + t);
                float4 b4 = *(const float4*)(pq + t);
                s += (a4.x + a4.y) + (a4.z + a4.w);
                q += (b4.x + b4.y) + (b4.z + b4.w);
            }
            const float mean = s * (1.f / BB);
            const float var  = q * (1.f / BB) - mean * mean;
            const float rstd = rsqrtf(var + 1e-5f);
            const float scv  = gIn[(size_t)c * K + f] * rstd;
            scs[f] = scv;
            shs[f] = fmaf(-mean, scv, beIn[(size_t)c * K + f]);
        }
        __syncthreads();
    }

    const int b0 = btile * BM, o0 = otile * 128;
    const int OT = Fout >> 7;
    const char* wbase = Wpk + (size_t)((c * OT + otile) * KS) * 16384;
    const char* abase = PREPACK ? (Apk + (size_t)((c * gridDim.x + btile) * KS) * 16384) : nullptr;

    const int lane = tid & 63, wv = tid >> 6;
    const int fr = lane & 15, fkc = lane >> 4;
    const int wrow = (BM == 128) ? ((wv >> 1) << 6) : ((wv >> 1) << 5);
    const int wcol = (wv & 1) << 6;
    const int wrg = wrow >> 4, wcg = wcol >> 4;
    constexpr int MI = BM / 32;

    f32x4 acc[MI][4];
    #pragma unroll
    for (int mi = 0; mi < MI; ++mi)
        #pragma unroll
        for (int ni = 0; ni < 4; ++ni)
            acc[mi][ni] = (f32x4){0.f, 0.f, 0.f, 0.f};

    if constexpr (PREPACK) {
        auto stageTile = [&](int nb, int ks) {
            const char* at = abase + (size_t)ks * 16384;
            const char* wt = wbase + (size_t)ks * 16384;
            char* dst = sm + nb;
            #pragma unroll
            for (int i = 0; i < 2; ++i) {                 // A hi plane: 8 chunks
                const int rg = ((wv << 1) + i) << 10;
                gll16(at + rg + (lane << 4), dst + rg);
            }
            #pragma unroll
            for (int i = 0; i < 4; ++i) {                 // W hi+lo: 16 chunks
                const int rg = ((wv << 2) + i) << 10;
                gll16(wt + rg + (lane << 4), dst + WOFF + rg);
            }
        };
        stageTile(0, 0);
        __syncthreads();
        for (int ks = 0; ks < KS; ++ks) {
            const int cb = (ks & 1) ? BUFSZ : 0;
            if (ks + 1 < KS) stageTile(cb ^ BUFSZ, ks + 1);
            bf16x8 ah[MI], wh[4], wl[4];
            #pragma unroll
            for (int i = 0; i < 4; ++i) {
                const int wo = ((wcg + i) << 10) | (fkc << 8) | (fr << 4);
                wh[i] = *(const bf16x8*)(sm + cb + WOFF + wo);
                wl[i] = *(const bf16x8*)(sm + cb + WOFF + 8192 + wo);
            }
            #pragma unroll
            for (int i = 0; i < MI; ++i) {
                const int ao = ((wrg + i) << 10) | (fkc << 8) | (fr << 4);
                ah[i] = *(const bf16x8*)(sm + cb + ao);
            }
            #pragma unroll
            for (int mi = 0; mi < MI; ++mi)
                #pragma unroll
                for (int ni = 0; ni < 4; ++ni) {
                    acc[mi][ni] = __builtin_amdgcn_mfma_f32_16x16x32_bf16(ah[mi], wh[ni], acc[mi][ni], 0, 0, 0);
                    acc[mi][ni] = __builtin_amdgcn_mfma_f32_16x16x32_bf16(ah[mi], wl[ni], acc[mi][ni], 0, 0, 0);
                }
            __syncthreads();
        }
    } else {
        // reg path: bf16 A in, one short8 load per thread per step
        const int arow = tid >> 2, asub = tid & 3;
        const int ak0  = asub << 3;
        const int awr  = ((arow >> 4) << 10) | (asub << 8) | ((arow & 15) << 4);
        const unsigned short* Arow = A + ((size_t)c * BB + b0 + arow) * K;

        auto loadA = [&](short8& av, int gk0) {
            av = *(const short8*)(Arow + gk0);
        };
        auto loadW = [&](bf16x8 (&w)[8], int ks) {
            const char* wt = wbase + (size_t)ks * 16384;
            #pragma unroll
            for (int i = 0; i < 4; ++i) {
                const int wo = ((wcg + i) << 10) | (fkc << 8) | (fr << 4);
                w[i]     = *(const bf16x8*)(wt + wo);
                w[4 + i] = *(const bf16x8*)(wt + 8192 + wo);
            }
        };
        auto cvtStore = [&](char* dstbase, const short8& a, int gk0) {
            float e[8];
            #pragma unroll
            for (int j = 0; j < 8; ++j) e[j] = b2f(a[j]);
            if constexpr (FUSE_BN) {
                const float4 sc0 = *(const float4*)(scs + gk0);
                const float4 sc1 = *(const float4*)(scs + gk0 + 4);
                const float4 sh0 = *(const float4*)(shs + gk0);
                const float4 sh1 = *(const float4*)(shs + gk0 + 4);
                e[0] = fmaxf(0.f, fmaf(e[0], sc0.x, sh0.x));
                e[1] = fmaxf(0.f, fmaf(e[1], sc0.y, sh0.y));
                e[2] = fmaxf(0.f, fmaf(e[2], sc0.z, sh0.z));
                e[3] = fmaxf(0.f, fmaf(e[3], sc0.w, sh0.w));
                e[4] = fmaxf(0.f, fmaf(e[4], sc1.x, sh1.x));
                e[5] = fmaxf(0.f, fmaf(e[5], sc1.y, sh1.y));
                e[6] = fmaxf(0.f, fmaf(e[6], sc1.z, sh1.z));
                e[7] = fmaxf(0.f, fmaf(e[7], sc1.w, sh1.w));
            }
            short h[8];
            #pragma unroll
            for (int j = 0; j < 8; ++j) h[j] = f2b(e[j]);
            *(short8*)(dstbase + awr) = (short8){h[0],h[1],h[2],h[3],h[4],h[5],h[6],h[7]};
        };

        bf16x8 wcA[8], wcB[8];
        short8 avP, avQ;

        auto step = [&](int ks, char* cbp, char* nbp,
                        short8& avUse, short8& avLoad,
                        bf16x8 (&wUse)[8], bf16x8 (&wLoad)[8]) {
            const bool hn  = (ks + 1) < KS;
            const bool hn2 = (ks + 2) < KS;
            if (hn2) loadA(avLoad, ((ks + 2) << 5) + ak0);
            if (hn)  loadW(wLoad, ks + 1);
            bf16x8 ah[MI];
            #pragma unroll
            for (int i = 0; i < MI; ++i) {
                const int ao = ((wrg + i) << 10) | (fkc << 8) | (fr << 4);
                ah[i] = *(const bf16x8*)(cbp + ao);
            }
            #pragma unroll
            for (int mi = 0; mi < MI; ++mi)
                #pragma unroll
                for (int ni = 0; ni < 4; ++ni) {
                    acc[mi][ni] = __builtin_amdgcn_mfma_f32_16x16x32_bf16(ah[mi], wUse[ni],     acc[mi][ni], 0, 0, 0);
                    acc[mi][ni] = __builtin_amdgcn_mfma_f32_16x16x32_bf16(ah[mi], wUse[4 + ni], acc[mi][ni], 0, 0, 0);
                }
            if (hn) cvtStore(nbp, avUse, ((ks + 1) << 5) + ak0);
            soft_barrier();
        };

        {
            short8 av0;
            loadA(av0, ak0);
            loadW(wcA, 0);
            if (KS > 1) loadA(avP, 32 + ak0);
            cvtStore(sm, av0, ak0);
        }
        soft_barrier();

        for (int ks = 0; ks < KS; ks += 2) {
            step(ks,     sm,         sm + BUFSZ, avP, avQ, wcA, wcB);
            step(ks + 1, sm + BUFSZ, sm,         avQ, avP, wcB, wcA);
        }
    }

    // ---- epilogue: bias, store (fp32 or bf16), stats from fp32 acc ----
    float bv[4];
    #pragma unroll
    for (int ni = 0; ni < 4; ++ni)
        bv[ni] = bias[(size_t)c * Fout + o0 + wcol + (ni << 4) + fr];

    float p[4] = {}, q[4] = {};
    const int rsub = (lane >> 4) << 2;
    #pragma unroll
    for (int mi = 0; mi < MI; ++mi) {
        #pragma unroll
        for (int j = 0; j < 4; ++j) {
            const int row = b0 + wrow + (mi << 4) + rsub + j;
            const size_t ob = ((size_t)c * BB + row) * Fout + o0 + wcol;
            #pragma unroll
            for (int ni = 0; ni < 4; ++ni) {
                const float v = acc[mi][ni][j] + bv[ni];
                if constexpr (OUTBF16)
                    ((unsigned short*)OutV)[ob + (ni << 4) + fr] = (unsigned short)f2b(v);
                else
                    ((float*)OutV)[ob + (ni << 4) + fr] = v;
                if (WRITE_STATS) { p[ni] += v; q[ni] += v * v; }
            }
        }
    }

    if (WRITE_STATS) {
        #pragma unroll
        for (int ni = 0; ni < 4; ++ni) {
            p[ni] += __shfl_xor(p[ni], 16); p[ni] += __shfl_xor(p[ni], 32);
            q[ni] += __shfl_xor(q[ni], 16); q[ni] += __shfl_xor(q[ni], 32);
        }
        __syncthreads();
        float* redp = (float*)sm;
        float* redq = (float*)(sm + 1024);
        if (lane < 16) {
            const int base = (wv >> 1) * 128 + wcol;
            #pragma unroll
            for (int ni = 0; ni < 4; ++ni) {
                redp[base + (ni << 4) + fr] = p[ni];
                redq[base + (ni << 4) + fr] = q[ni];
            }
        }
        __syncthreads();
        if (tid < 128) {
            const float sp = redp[tid] + redp[128 + tid];
            const float sq = redq[tid] + redq[128 + tid];
            const size_t o = ((size_t)c * Fout + o0 + tid) * gridDim.x + btile;
            psumOut[o] = sp;
            psqOut[o]  = sq;
        }
    }
}

// ---------------------------------------------------------------------------
// 8-wave (512-thread) 128x256 tile, TWO K-steps per barrier, bf16 A in
// (single-plane 2-product). OUTBF16: bf16 activations out (stats from fp32).
// ---------------------------------------------------------------------------
template<int K, bool OUTBF16, bool WRITE_STATS>
__global__ __launch_bounds__(512, 2)
void gemm8w_kernel(const unsigned short* __restrict__ A, const char* __restrict__ Wpk,
                   const float* __restrict__ bias,
                   const float* __restrict__ psumIn, const float* __restrict__ psqIn,
                   const float* __restrict__ gIn, const float* __restrict__ beIn,
                   void* __restrict__ OutV,
                   float* __restrict__ psumOut, float* __restrict__ psqOut,
                   const int Fout, const int nbtIn)
{
    constexpr int KS    = K / 32;
    constexpr int PLANE = 8192;
    constexpr int BUFSZ = 8192;          // single-plane A buffer
    static_assert(K % 128 == 0, "need KS % 4 == 0 for the paired schedule");

    __shared__ __align__(16) char sm[4 * BUFSZ + 8 * K];
    float* scs = (float*)(sm + 4 * BUFSZ);
    float* shs = scs + K;

    const int tid = threadIdx.x;
    XCD_REMAP(btile, otile, c)

    // folded combine: BN scale/shift for INPUT features
    for (int f = tid; f < K; f += 512) {
        const float* ps = psumIn + ((size_t)c * K + f) * nbtIn;
        const float* pq = psqIn  + ((size_t)c * K + f) * nbtIn;
        float s = 0.f, q = 0.f;
        for (int t = 0; t < nbtIn; t += 4) {
            float4 a4 = *(const float4*)(ps + t);
            float4 b4 = *(const float4*)(pq + t);
            s += (a4.x + a4.y) + (a4.z + a4.w);
            q += (b4.x + b4.y) + (b4.z + b4.w);
        }
        const float mean = s * (1.f / BB);
        const float var  = q * (1.f / BB) - mean * mean;
        const float rstd = rsqrtf(var + 1e-5f);
        const float scv  = gIn[(size_t)c * K + f] * rstd;
        scs[f] = scv;
        shs[f] = fmaf(-mean, scv, beIn[(size_t)c * K + f]);
    }
    __syncthreads();

    const int b0 = btile * 128, o0 = otile * 256;
    const int OT128 = Fout >> 7;

    // A staging map: 512 threads x 8 bf16 elems (one 16B slot)
    const int arow = tid >> 2, asub = tid & 3;
    const int ak0  = asub << 3;
    const int awr  = ((arow >> 4) << 10) | (asub << 8) | ((arow & 15) << 4);
    const unsigned short* Arow = A + ((size_t)c * BB + b0 + arow) * K;

    // wave map: 2(M) x 4(N), each wave 64x64
    const int lane = tid & 63, wv = tid >> 6;
    const int wr = wv >> 2, nc = wv & 3;
    const int wrow = wr << 6, wcol = nc << 6;
    const int fr = lane & 15, fkc = lane >> 4;
    const int wrg = wrow >> 4;
    const int wtile = wcol >> 7;
    const int wcg = (wcol >> 4) & 7;
    const char* wbase = Wpk + (size_t)((c * OT128 + otile * 2 + wtile) * KS) * 16384;

    auto loadA = [&](short8& av, int gk0) {
        av = *(const short8*)(Arow + gk0);
    };
    auto loadW = [&](bf16x8 (&w)[8], int ks) {
        const char* wt = wbase + (size_t)ks * 16384;
        #pragma unroll
        for (int i = 0; i < 4; ++i) {
            const int wo = ((wcg + i) << 10) | (fkc << 8) | (fr << 4);
            w[i]     = *(const bf16x8*)(wt + wo);
            w[4 + i] = *(const bf16x8*)(wt + 8192 + wo);
        }
    };
    auto cvtStore = [&](char* dstbase, const short8& a, int gk0) {
        float e[8];
        #pragma unroll
        for (int j = 0; j < 8; ++j) e[j] = b2f(a[j]);
        const float4 sc0 = *(const float4*)(scs + gk0);
        const float4 sc1 = *(const float4*)(scs + gk0 + 4);
        const float4 sh0 = *(const float4*)(shs + gk0);
        const float4 sh1 = *(const float4*)(shs + gk0 + 4);
        e[0] = fmaxf(0.f, fmaf(e[0], sc0.x, sh0.x));
        e[1] = fmaxf(0.f, fmaf(e[1], sc0.y, sh0.y));
        e[2] = fmaxf(0.f, fmaf(e[2], sc0.z, sh0.z));
        e[3] = fmaxf(0.f, fmaf(e[3], sc0.w, sh0.w));
        e[4] = fmaxf(0.f, fmaf(e[4], sc1.x, sh1.x));
        e[5] = fmaxf(0.f, fmaf(e[5], sc1.y, sh1.y));
        e[6] = fmaxf(0.f, fmaf(e[6], sc1.z, sh1.z));
        e[7] = fmaxf(0.f, fmaf(e[7], sc1.w, sh1.w));
        short h[8];
        #pragma unroll
        for (int j = 0; j < 8; ++j) h[j] = f2b(e[j]);
        *(short8*)(dstbase + awr) = (short8){h[0],h[1],h[2],h[3],h[4],h[5],h[6],h[7]};
    };

    f32x4 acc[4][4];
    #pragma unroll
    for (int mi = 0; mi < 4; ++mi)
        #pragma unroll
        for (int ni = 0; ni < 4; ++ni)
            acc[mi][ni] = (f32x4){0.f, 0.f, 0.f, 0.f};

    bf16x8 wc[8], wn[8];
    short8 avA, avB, avC, avD;

    auto mfmaStep = [&](char* cbp, bf16x8 (&wUse)[8]) {
        bf16x8 ah[4];
        #pragma unroll
        for (int i = 0; i < 4; ++i) {
            const int ao = ((wrg + i) << 10) | (fkc << 8) | (fr << 4);
            ah[i] = *(const bf16x8*)(cbp + ao);
        }
        #pragma unroll
        for (int mi = 0; mi < 4; ++mi)
            #pragma unroll
            for (int ni = 0; ni < 4; ++ni) {
                acc[mi][ni] = __builtin_amdgcn_mfma_f32_16x16x32_bf16(ah[mi], wUse[ni],     acc[mi][ni], 0, 0, 0);
                acc[mi][ni] = __builtin_amdgcn_mfma_f32_16x16x32_bf16(ah[mi], wUse[4 + ni], acc[mi][ni], 0, 0, 0);
            }
    };

    auto group = [&](int ks, char* bR0, char* bR1, char* bW0, char* bW1,
                     short8& aU0, short8& aU1, short8& aL0, short8& aL1) {
        if (ks + 4 < KS) loadA(aL0, ((ks + 4) << 5) + ak0);
        if (ks + 1 < KS) loadW(wn, ks + 1);
        mfmaStep(bR0, wc);
        if (ks + 2 < KS) cvtStore(bW0, aU0, ((ks + 2) << 5) + ak0);
        if (ks + 5 < KS) loadA(aL1, ((ks + 5) << 5) + ak0);
        if (ks + 2 < KS) loadW(wc, ks + 2);
        mfmaStep(bR1, wn);
        if (ks + 3 < KS) cvtStore(bW1, aU1, ((ks + 3) << 5) + ak0);
        soft_barrier();
    };

    {
        short8 a0, a1;
        loadA(a0, ak0);
        loadA(a1, 32 + ak0);
        loadW(wc, 0);
        loadA(avA, 64 + ak0);
        loadA(avB, 96 + ak0);
        cvtStore(sm,         a0, ak0);
        cvtStore(sm + BUFSZ, a1, 32 + ak0);
    }
    soft_barrier();

    for (int ks = 0; ks < KS; ks += 4) {
        group(ks,     sm,             sm + BUFSZ,     sm + 2 * BUFSZ, sm + 3 * BUFSZ,
              avA, avB, avC, avD);
        group(ks + 2, sm + 2 * BUFSZ, sm + 3 * BUFSZ, sm,             sm + BUFSZ,
              avC, avD, avA, avB);
    }

    // ---- epilogue: bias, store (fp32 or bf16), stats from fp32 acc ----
    float bv[4];
    #pragma unroll
    for (int ni = 0; ni < 4; ++ni)
        bv[ni] = bias[(size_t)c * Fout + o0 + wcol + (ni << 4) + fr];

    float p[4] = {}, q[4] = {};
    const int rsub = (lane >> 4) << 2;
    #pragma unroll
    for (int mi = 0; mi < 4; ++mi) {
        #pragma unroll
        for (int j = 0; j < 4; ++j) {
            const int row = b0 + wrow + (mi << 4) + rsub + j;
            const size_t ob = ((size_t)c * BB + row) * Fout + o0 + wcol;
            #pragma unroll
            for (int ni = 0; ni < 4; ++ni) {
                const float v = acc[mi][ni][j] + bv[ni];
                if constexpr (OUTBF16)
                    ((unsigned short*)OutV)[ob + (ni << 4) + fr] = (unsigned short)f2b(v);
                else
                    ((float*)OutV)[ob + (ni << 4) + fr] = v;
                if (WRITE_STATS) { p[ni] += v; q[ni] += v * v; }
            }
        }
    }

    if (WRITE_STATS) {
        #pragma unroll
        for (int ni = 0; ni < 4; ++ni) {
            p[ni] += __shfl_xor(p[ni], 16); p[ni] += __shfl_xor(p[ni], 32);
            q[ni] += __shfl_xor(q[ni], 16); q[ni] += __shfl_xor(q[ni], 32);
        }
        __syncthreads();
        float* redp = (float*)sm;           // [2][256]
        float* redq = (float*)(sm + 2048);
        if (lane < 16) {
            const int base = wr * 256 + wcol;
            #pragma unroll
            for (int ni = 0; ni < 4; ++ni) {
                redp[base + (ni << 4) + fr] = p[ni];
                redq[base + (ni << 4) + fr] = q[ni];
            }
        }
        __syncthreads();
        if (tid < 256) {
            const float sp = redp[tid] + redp[256 + tid];
            const float sq = redq[tid] + redq[256 + tid];
            const size_t o = ((size_t)c * Fout + o0 + tid) * gridDim.x + btile;
            psumOut[o] = sp;
            psqOut[o]  = sq;
        }
    }
}

__global__ __launch_bounds__(256)
void label_kernel(float* __restrict__ out)
{
    const int i = blockIdx.x * 256 + threadIdx.x;
    out[i] = (float)(i >> 11);   // i / 2048
}

// ---------------------------------------------------------------------------
extern "C" void kernel_launch(void* const* d_in, const int* in_sizes, int n_in,
                              void* d_out, int out_size, void* d_ws, size_t ws_size,
                              hipStream_t stream)
{
    const float* x = (const float*)d_in[0];
    const float* W[5];  const float* bs[5];
    for (int l = 0; l < 5; ++l) { W[l] = (const float*)d_in[1 + 2 * l]; bs[l] = (const float*)d_in[2 + 2 * l]; }
    const float* g[4];  const float* be[4];
    for (int l = 0; l < 4; ++l) { g[l] = (const float*)d_in[11 + 2 * l]; be[l] = (const float*)d_in[12 + 2 * l]; }

    float* out     = (float*)d_out;
    float* gendata = out;                               // final fp32 output
    float* label   = out + (size_t)CCLS * BB * 512;
    unsigned short* h1b = (unsigned short*)d_out;       // bf16 h1 lives in gendata
                                                        // region (dead before G5 writes)

    char* wsb = (char*)d_ws;
    unsigned short* h2b = (unsigned short*)wsb;                    // 16.8 MB
    unsigned short* h3b = (unsigned short*)(wsb + 16777216);       // 8.4 MB
    unsigned short* h4b = h2b;                                     // alias (h2 dead after G3)
    float* ps1 = (float*)(wsb + 16777216 + 8388608);
    float* pq1 = ps1 + 131072;
    float* ps2 = pq1 + 131072;
    float* pq2 = ps2 + 65536;
    float* ps3 = pq2 + 65536;
    float* pq3 = ps3 + 65536;
    float* ps4 = pq3 + 65536;
    float* pq4 = ps4 + 65536;
    char*  pack = (char*)(pq4 + 65536);                 // 2560 x 16KB = 40MB

    const char* xpk  = pack;
    const char* wpk1 = pack + (size_t)1024 * 16384;
    const char* wpk2 = pack + (size_t)1280 * 16384;
    const char* wpk3 = pack + (size_t)1792 * 16384;
    const char* wpk4 = pack + (size_t)1920 * 16384;
    const char* wpk5 = pack + (size_t)2048 * 16384;

    const dim3 blk(256);

    PackDesc pd;
    pd.src[0] = x;    pd.src[1] = W[0]; pd.src[2] = W[1];
    pd.src[3] = W[2]; pd.src[4] = W[3]; pd.src[5] = W[4];
    const int nrt[6]   = {16, 4, 2, 1, 2, 4};
    const int ksn[6]   = {4, 4, 16, 8, 4, 8};
    const int kreal[6] = {100, 100, 512, 256, 128, 256};
    const int beg[7]   = {0, 1024, 1280, 1792, 1920, 2048, 2560};
    for (int i = 0; i < 6; ++i) { pd.nrt[i] = nrt[i]; pd.ksn[i] = ksn[i]; pd.kreal[i] = kreal[i]; }
    for (int i = 0; i < 7; ++i) pd.beg[i] = beg[i];
    pack_kernel<<<dim3(2560), blk, 0, stream>>>(pd, pack);

    // G1: x[K=100->128] -> h1b (bf16), stats -> ps1 (PREPACK, 2-product). 16 btiles.
    gemm4w_kernel<128, 128, true, true, false, true><<<dim3(16, 4, CCLS), blk, 0, stream>>>(
        nullptr, xpk, wpk1, bs[0], nullptr, nullptr, nullptr, nullptr,
        h1b, ps1, pq1, 512, 0);

    // G2: bn1(h1b)->relu -> h2b (bf16), stats (8w paired). nbtIn=16 (G1 grid.x).
    gemm8w_kernel<512, true, true><<<dim3(16, 1, CCLS), dim3(512), 0, stream>>>(
        h1b, wpk2, bs[1], ps1, pq1, g[0], be[0],
        h2b, ps2, pq2, 256, 16);

    // G3: bn2(h2b)->relu -> h3b (bf16), stats (4w BM=64). nbtIn=16 (G2 grid.x).
    gemm4w_kernel<64, 256, false, true, true, true><<<dim3(32, 1, CCLS), blk, 0, stream>>>(
        h2b, nullptr, wpk3, bs[2], ps2, pq2, g[1], be[1],
        h3b, ps3, pq3, 128, 16);

    // G4: bn3(h3b)->relu -> h4b (bf16), stats (8w paired). nbtIn=32 (G3 grid.x).
    gemm8w_kernel<128, true, true><<<dim3(16, 1, CCLS), dim3(512), 0, stream>>>(
        h3b, wpk4, bs[3], ps3, pq3, g[2], be[2],
        h4b, ps4, pq4, 256, 32);

    // G5: bn4(h4b)->relu -> gendata (fp32). nbtIn=16 (G4 grid.x) — R17 bug fixed.
    gemm8w_kernel<256, false, false><<<dim3(16, 2, CCLS), dim3(512), 0, stream>>>(
        h4b, wpk5, bs[4], ps4, pq4, g[3], be[3],
        gendata, nullptr, nullptr, 512, 16);

    label_kernel<<<dim3(CCLS * BB / 256), blk, 0, stream>>>(label);
}